// Round 1
// 557.063 us; speedup vs baseline: 1.0152x; 1.0152x over previous
//
#include <hip/hip_runtime.h>
#include <math.h>

#define B_ 64
#define L_ 512
#define C_ 256
#define H_ 4
#define LAY 3
#define NEGV -1e9f

#define GF_BIAS  1
#define GF_RELU  2
#define GF_OBF16 4

typedef __attribute__((ext_vector_type(8))) short short8;
typedef __attribute__((ext_vector_type(4))) short short4v;
typedef __attribute__((ext_vector_type(4))) float floatx4;

static __device__ __forceinline__ float rcp_(float x) { return __builtin_amdgcn_rcpf(x); }
static __device__ __forceinline__ float sig_(float x) { return rcp_(1.f + __expf(-x)); }
static __device__ __forceinline__ float tanh_(float x) {
    float e = __expf(2.f * x);
    return 1.f - 2.f * rcp_(e + 1.f);
}

static __device__ __forceinline__ short f2bf(float f) {
    unsigned x = __float_as_uint(f);
    x += 0x7fffu + ((x >> 16) & 1u);       // round-to-nearest-even to bf16
    return (short)(x >> 16);
}
static __device__ __forceinline__ float bf2f(short s) {
    return __uint_as_float(((unsigned)(unsigned short)s) << 16);
}

// XCD-aligned token swizzle for elementwise consumers (matches GEMM rb%8 = XCD).
static __device__ __forceinline__ int tok_swizzle(int blk) {
    int c8 = blk & 7, i = blk >> 3;
    return (c8 + 8 * (i >> 5)) * 128 + (i & 31) * 4;
}

static __device__ __forceinline__ void gl_lds16(const short* g, short* l) {
    __builtin_amdgcn_global_load_lds(
        (const __attribute__((address_space(1))) unsigned int*)g,
        (__attribute__((address_space(3))) unsigned int*)l, 16, 0, 0);
}

// ---------------- mask / logical-position scan + pos_of_logical ----------------
__global__ void scan_kernel(const int* __restrict__ x, int* __restrict__ mask,
                            int* __restrict__ logical, int* __restrict__ pol,
                            int* __restrict__ nvalid) {
    int b = blockIdx.x, t = threadIdx.x;
    __shared__ int s[L_];
    int m = (x[b * L_ + t] != 0) ? 1 : 0;
    s[t] = m;
    __syncthreads();
    for (int off = 1; off < L_; off <<= 1) {
        int v = (t >= off) ? s[t - off] : 0;
        __syncthreads();
        s[t] += v;
        __syncthreads();
    }
    int cum = s[t];
    int lg = cum - 1; if (lg < 0) lg = 0;
    mask[b * L_ + t] = m;
    logical[b * L_ + t] = lg;
    if (m) pol[b * L_ + lg] = t;
    if (t == L_ - 1) nvalid[b] = cum;
}

// ---------------- hb = bf16((emb[x] + pos*mf)*mf) ----------------
__global__ void embed_kernel(const int* __restrict__ x, const float* __restrict__ emb,
                             const float* __restrict__ pos, short* __restrict__ hb) {
    int t = threadIdx.x;
    int bl = tok_swizzle(blockIdx.x) + (t >> 6);
    int lane = t & 63;
    int xv = x[bl];
    float mf = (xv != 0) ? 1.f : 0.f;
    int l = bl & (L_ - 1);
    float4 e = *(const float4*)&emb[(size_t)xv * C_ + lane * 4];
    float4 p = *(const float4*)&pos[(size_t)l * C_ + lane * 4];
    short4v hv4;
    hv4.x = f2bf((e.x + p.x * mf) * mf);
    hv4.y = f2bf((e.y + p.y * mf) * mf);
    hv4.z = f2bf((e.z + p.z * mf) * mf);
    hv4.w = f2bf((e.w + p.w * mf) * mf);
    *(short4v*)&hb[(size_t)bl * C_ + lane * 4] = hv4;
}

// ---------------- weight prep ----------------
__global__ void f2bf_kernel(const float* __restrict__ s, short* __restrict__ d, int n) {
    int i = blockIdx.x * 256 + threadIdx.x;
    if (i < n) d[i] = f2bf(s[i]);
}

// Wcomb[l][640][256]: rows 0..255 = gpW[l], 256..511 = gfW[l],
// rows 512..527 = AsdW (n = type*8+dir*4+head -> a_vec @ W_dir), rest 0.
__global__ void prep_wcomb(const float* __restrict__ gpW, const float* __restrict__ gfW,
                           const float* __restrict__ gpas, const float* __restrict__ gpad,
                           const float* __restrict__ gfas, const float* __restrict__ gfad,
                           short* __restrict__ Wc) {
    int i = blockIdx.x * 256 + threadIdx.x;
    if (i >= 3 * 640 * 256) return;
    int k = i & 255;
    int r = (i >> 8) % 640;
    int l = i / (640 * 256);
    float v = 0.f;
    if (r < 256) {
        v = gpW[((size_t)l * 256 + r) * 256 + k];
    } else if (r < 512) {
        v = gfW[((size_t)l * 256 + (r - 256)) * 256 + k];
    } else {
        int n = r - 512;
        if (n < 16) {
            int type = n >> 3, dir = (n >> 2) & 1, hh = n & 3;
            const float* a = type ? (dir ? gfad : gpad) : (dir ? gfas : gpas);
            const float* W = dir ? gfW : gpW;
            for (int j = 0; j < 64; j++) {
                float av = a[l * 256 + hh * 64 + j];
                float wv = W[((size_t)l * 256 + hh * 64 + j) * 256 + k];
                v = fmaf(av, wv, v);
            }
        }
    }
    Wc[i] = f2bf(v);
}

// Interleaved GRU weights: Bc[l][n'][512], n' = 4*ch + g, g in {0:r,1:z,2:i,3:n}.
__global__ void prep_gru_i(const float* __restrict__ Wih, const float* __restrict__ Whh,
                           short* __restrict__ Bc) {
    int i = blockIdx.x * 256 + threadIdx.x;
    if (i >= 3 * 1024 * 512) return;
    int k = i & 511, np = (i >> 9) & 1023, l = i >> 19;
    int ch = np >> 2, g = np & 3;
    float v = 0.f;
    if (g < 2) {
        v = (k < 256) ? Wih[((size_t)l * 768 + g * 256 + ch) * 256 + k]
                      : Whh[((size_t)l * 768 + g * 256 + ch) * 256 + (k - 256)];
    } else if (g == 2) {
        if (k < 256) v = Wih[((size_t)l * 768 + 512 + ch) * 256 + k];
    } else {
        if (k >= 256) v = Whh[((size_t)l * 768 + 512 + ch) * 256 + (k - 256)];
    }
    Bc[i] = f2bf(v);
}

// bias4[l][4*ch+g]
__global__ void prep_bias4(const float* __restrict__ bih, const float* __restrict__ bhh,
                           float* __restrict__ bc) {
    int i = blockIdx.x * 256 + threadIdx.x;
    if (i >= 3 * 1024) return;
    int np = i & 1023, l = i >> 10;
    int ch = np >> 2, g = np & 3;
    float v;
    if (g < 2)       v = bih[l * 768 + g * 256 + ch] + bhh[l * 768 + g * 256 + ch];
    else if (g == 2) v = bih[l * 768 + 512 + ch];
    else             v = bhh[l * 768 + 512 + ch];
    bc[i] = v;
}

// ---------------- plain bf16 MFMA GEMM (msg): C[M,N] = A[M,K] * B[N,K]^T ----------------
__global__ __launch_bounds__(256) void bgemm(const short* __restrict__ A0,
                                             const short* __restrict__ Bw,
                                             void* __restrict__ Cout,
                                             const float* __restrict__ bias,
                                             int K, int lda, int ldc, int nstore,
                                             int cbBits, int flags) {
    __shared__ short As[128 * 32];
    __shared__ short Bs[128 * 32];
    const int id = blockIdx.x;
    const int cb = (id >> 3) & ((1 << cbBits) - 1);
    const int rb = (id & 7) + ((id >> (3 + cbBits)) << 3);
    const int tid = threadIdx.x;
    const int wave = tid >> 6, lane = tid & 63;
    const int wm = wave >> 1, wn = wave & 1;
    const size_t arow0 = (size_t)rb * 128;
    const short* Bb = Bw + (size_t)cb * 128 * K;
    floatx4 acc[4][4];   // [nf][mf]
#pragma unroll
    for (int i = 0; i < 4; i++)
#pragma unroll
        for (int j = 0; j < 4; j++) acc[i][j] = (floatx4)0.f;

    const int srow = lane >> 2;
    const int sq = (lane & 3) * 8;
    const int q = lane >> 4, t16 = lane & 15;

    for (int k0 = 0; k0 < K; k0 += 32) {
        const short* Abase = A0 + arow0 * (size_t)lda + k0;
#pragma unroll
        for (int t = 0; t < 2; ++t) {
            int r = (wave * 2 + t) * 16 + srow;
            gl_lds16(Abase + (size_t)r * lda + sq, &As[r * 32 + sq]);
            gl_lds16(Bb + (size_t)r * K + k0 + sq, &Bs[r * 32 + sq]);
        }
        __syncthreads();
        short8 af[4], bfr[4];
#pragma unroll
        for (int mf = 0; mf < 4; mf++)
            af[mf] = *(const short8*)&As[(wm * 64 + mf * 16 + t16) * 32 + q * 8];
#pragma unroll
        for (int nf = 0; nf < 4; nf++)
            bfr[nf] = *(const short8*)&Bs[(wn * 64 + nf * 16 + t16) * 32 + q * 8];
#pragma unroll
        for (int mf = 0; mf < 4; mf++)
#pragma unroll
            for (int nf = 0; nf < 4; nf++)
                acc[nf][mf] = __builtin_amdgcn_mfma_f32_16x16x32_bf16(
                    bfr[nf], af[mf], acc[nf][mf], 0, 0, 0);
        __syncthreads();
    }

    const int rowbase = rb * 128 + wm * 64;
    const int colbase = cb * 128 + wn * 64;
#pragma unroll
    for (int nf = 0; nf < 4; nf++) {
        int col0 = colbase + nf * 16 + q * 4;
        if (col0 >= nstore) continue;
        float4 bv4 = make_float4(0.f, 0.f, 0.f, 0.f);
        if (flags & GF_BIAS) bv4 = *(const float4*)&bias[col0];
#pragma unroll
        for (int mf = 0; mf < 4; mf++) {
            int row = rowbase + mf * 16 + t16;
            float v0 = acc[nf][mf][0] + bv4.x;
            float v1 = acc[nf][mf][1] + bv4.y;
            float v2 = acc[nf][mf][2] + bv4.z;
            float v3 = acc[nf][mf][3] + bv4.w;
            if (flags & GF_RELU) {
                v0 = fmaxf(v0, 0.f); v1 = fmaxf(v1, 0.f);
                v2 = fmaxf(v2, 0.f); v3 = fmaxf(v3, 0.f);
            }
            size_t base = (size_t)row * ldc + col0;
            if (flags & GF_OBF16) {
                short4v pk;
                pk.x = f2bf(v0); pk.y = f2bf(v1); pk.z = f2bf(v2); pk.w = f2bf(v3);
                *(short4v*)&((short*)Cout)[base] = pk;
            } else {
                float4 pk = make_float4(v0, v1, v2, v3);
                *(float4*)&((float*)Cout)[base] = pk;
            }
        }
    }
}

// ---------------- projection + Ssd combined GEMM ----------------
// A = hb [32768,256] (K=256), B = Wcomb [640,256]; cb 0..3 -> hpb2 bf16 (ldc 512),
// cb 4 -> Ssd fp32 (ldc 16, 16 real cols). Grid 1280 = 256 rb x 5 cb, XCD-seq.
__global__ __launch_bounds__(256) void projssd_bgemm(const short* __restrict__ A0,
                                                     const short* __restrict__ Bw,
                                                     short* __restrict__ hpb2,
                                                     float* __restrict__ Ssd) {
    __shared__ short As[128 * 32];
    __shared__ short Bs[128 * 32];
    const int id = blockIdx.x;
    const int grp = id >> 3;
    const int cb = grp % 5;
    const int rb = (id & 7) + (grp / 5) * 8;
    const int tid = threadIdx.x;
    const int wave = tid >> 6, lane = tid & 63;
    const int wm = wave >> 1, wn = wave & 1;
    const size_t arow0 = (size_t)rb * 128;
    const short* Bb = Bw + (size_t)cb * 128 * 256;
    floatx4 acc[4][4];
#pragma unroll
    for (int i = 0; i < 4; i++)
#pragma unroll
        for (int j = 0; j < 4; j++) acc[i][j] = (floatx4)0.f;

    const int srow = lane >> 2;
    const int sq = (lane & 3) * 8;
    const int q = lane >> 4, t16 = lane & 15;

    for (int k0 = 0; k0 < 256; k0 += 32) {
        const short* Abase = A0 + arow0 * 256 + k0;
#pragma unroll
        for (int t = 0; t < 2; ++t) {
            int r = (wave * 2 + t) * 16 + srow;
            gl_lds16(Abase + (size_t)r * 256 + sq, &As[r * 32 + sq]);
            gl_lds16(Bb + (size_t)r * 256 + k0 + sq, &Bs[r * 32 + sq]);
        }
        __syncthreads();
        short8 af[4], bfr[4];
#pragma unroll
        for (int mf = 0; mf < 4; mf++)
            af[mf] = *(const short8*)&As[(wm * 64 + mf * 16 + t16) * 32 + q * 8];
#pragma unroll
        for (int nf = 0; nf < 4; nf++)
            bfr[nf] = *(const short8*)&Bs[(wn * 64 + nf * 16 + t16) * 32 + q * 8];
#pragma unroll
        for (int mf = 0; mf < 4; mf++)
#pragma unroll
            for (int nf = 0; nf < 4; nf++)
                acc[nf][mf] = __builtin_amdgcn_mfma_f32_16x16x32_bf16(
                    bfr[nf], af[mf], acc[nf][mf], 0, 0, 0);
        __syncthreads();
    }

    const int rowbase = rb * 128 + wm * 64;
    if (cb < 4) {
        const int colbase = cb * 128 + wn * 64;
#pragma unroll
        for (int nf = 0; nf < 4; nf++) {
            int col0 = colbase + nf * 16 + q * 4;
#pragma unroll
            for (int mf = 0; mf < 4; mf++) {
                int row = rowbase + mf * 16 + t16;
                short4v pk;
                pk.x = f2bf(acc[nf][mf][0]);
                pk.y = f2bf(acc[nf][mf][1]);
                pk.z = f2bf(acc[nf][mf][2]);
                pk.w = f2bf(acc[nf][mf][3]);
                *(short4v*)&hpb2[(size_t)row * 512 + col0] = pk;
            }
        }
    } else {
        // Ssd: cols 512..639 map to 0..127; only first 16 real (wn=0, nf=0)
        if (wn == 0) {
            int col0 = q * 4;   // nf = 0
            if (col0 < 16) {
#pragma unroll
                for (int mf = 0; mf < 4; mf++) {
                    int row = rowbase + mf * 16 + t16;
                    float4 pk = make_float4(acc[0][mf][0], acc[0][mf][1],
                                            acc[0][mf][2], acc[0][mf][3]);
                    *(float4*)&Ssd[(size_t)row * 16 + col0] = pk;
                }
            }
        }
    }
}

// ---------------- dedicated GRU GEMM, 256x256 tile, counted-vmcnt pipeline ----------------
// A = [mmb | hb] K=512, B = Bcat interleaved (N=1024, n'=4ch+g).
// 8 waves (2M x 4N), BK=64, double-buffered 128 KiB LDS, global_load_lds staging
// with XOR-swizzled source (involution cs^=row&7) + swizzled ds_read (2-way banks).
// Raw s_barrier + counted s_waitcnt vmcnt(8): loads stay in flight across barriers.
// Grid 512 = 128 rb x 4 cb, XCD-bijective chunks (64 consecutive rb per XCD).
__global__ __launch_bounds__(512, 2) void gru_bgemm(const short* __restrict__ mmb,
                                                    const short* __restrict__ hb_in,
                                                    const short* __restrict__ Bw,
                                                    short* __restrict__ hn2b,
                                                    const float* __restrict__ bias4) {
    __shared__ short lds[2][32768];   // per buf: A[256][64] @0, B[256][64] @16384
    const int id = blockIdx.x;
    const int swz = (id & 7) * 64 + (id >> 3);   // 512 % 8 == 0: bijective
    const int rb = swz & 127;
    const int cb = swz >> 7;
    const int tid = threadIdx.x;
    const int wave = tid >> 6, lane = tid & 63;
    const int wm = wave >> 2, wn = wave & 3;
    const int q = lane >> 4, t16 = lane & 15;
    const size_t arow0 = (size_t)rb * 256;
    const short* Bb = Bw + (size_t)cb * 256 * 512;

    floatx4 acc[4][8];   // [nf][mf]
#pragma unroll
    for (int i = 0; i < 4; i++)
#pragma unroll
        for (int j = 0; j < 8; j++) acc[i][j] = (floatx4)0.f;

    // stage K-tile t (8 gl_lds16 per thread: 4 A + 4 B). Linear LDS dest,
    // inverse-swizzled global source (rule 21: dest linear + src perm + read perm).
    auto stage = [&](int t) {
        const short* Asrc = (t < 4) ? (mmb + t * 64) : (hb_in + (t * 64 - 256));
        short* bufA = lds[t & 1];
        short* bufB = lds[t & 1] + 16384;
#pragma unroll
        for (int i = 0; i < 4; ++i) {
            int unit = i * 512 + tid;
            int row = unit >> 3;
            int csw = (unit & 7) ^ (row & 7);
            gl_lds16(Asrc + (arow0 + (size_t)row) * 256 + csw * 8, bufA + unit * 8);
        }
#pragma unroll
        for (int i = 0; i < 4; ++i) {
            int unit = i * 512 + tid;
            int row = unit >> 3;
            int csw = (unit & 7) ^ (row & 7);
            gl_lds16(Bb + (size_t)row * 512 + t * 64 + csw * 8, bufB + unit * 8);
        }
    };

    auto compute = [&](int t) {
        const short* bufA = lds[t & 1];
        const short* bufB = lds[t & 1] + 16384;
#pragma unroll
        for (int ks = 0; ks < 2; ++ks) {
            short8 af[8], bfr[4];
#pragma unroll
            for (int mf = 0; mf < 8; mf++) {
                int row = wm * 128 + mf * 16 + t16;
                int cg = (ks * 4 + q) ^ (row & 7);
                af[mf] = *(const short8*)&bufA[row * 64 + cg * 8];
            }
#pragma unroll
            for (int nf = 0; nf < 4; nf++) {
                int row = wn * 64 + nf * 16 + t16;
                int cg = (ks * 4 + q) ^ (row & 7);
                bfr[nf] = *(const short8*)&bufB[row * 64 + cg * 8];
            }
            __builtin_amdgcn_s_setprio(1);
#pragma unroll
            for (int mf = 0; mf < 8; mf++)
#pragma unroll
                for (int nf = 0; nf < 4; nf++)
                    acc[nf][mf] = __builtin_amdgcn_mfma_f32_16x16x32_bf16(
                        bfr[nf], af[mf], acc[nf][mf], 0, 0, 0);
            __builtin_amdgcn_s_setprio(0);
        }
    };

    // prologue: tiles 0,1 in flight (16 outstanding loads/wave)
    stage(0);
    stage(1);

    for (int t = 0; t < 7; ++t) {
        // oldest 8 (= tile t's loads) complete; tile t+1 stays in flight
        asm volatile("s_waitcnt vmcnt(8)" ::: "memory");
        __builtin_amdgcn_s_barrier();          // all waves' portions of tile t visible
        asm volatile("" ::: "memory");
        compute(t);
        asm volatile("" ::: "memory");
        __builtin_amdgcn_s_barrier();          // all waves done reading buf[t&1]
        asm volatile("" ::: "memory");
        if (t < 6) stage(t + 2);               // refill the buffer just freed
    }
    // last tile: only its own 8 loads outstanding
    asm volatile("s_waitcnt vmcnt(0)" ::: "memory");
    __builtin_amdgcn_s_barrier();
    asm volatile("" ::: "memory");
    compute(7);

    // epilogue: h_prev (L2-hot), gates, LDS-staged coalesced bf16 write.
    // acc[nf][mf] lanes j = gates (r,z,i,n) of channel ch = col0/4 (interleaved B).
    short* sO = lds[0];                        // [256][72] bf16 (pad: align + banks)
#pragma unroll
    for (int nf = 0; nf < 4; nf++) {
        int chl = wn * 16 + nf * 4 + q;        // 0..63 within block
        int col0 = cb * 256 + wn * 64 + nf * 16 + q * 4;
        float4 bv4 = *(const float4*)&bias4[col0];
#pragma unroll
        for (int mf = 0; mf < 8; mf++) {
            int rowl = wm * 128 + mf * 16 + t16;
            size_t grow = arow0 + rowl;
            float hp = bf2f(hb_in[grow * 256 + cb * 64 + chl]);
            float r = sig_(acc[nf][mf][0] + bv4.x);
            float z = sig_(acc[nf][mf][1] + bv4.y);
            float nv = tanh_((acc[nf][mf][2] + bv4.z) + r * (acc[nf][mf][3] + bv4.w));
            sO[rowl * 72 + chl] = f2bf((1.f - z) * nv + z * hp);
        }
    }
    __syncthreads();
    // coalesced write: 256 rows x 64 ch, short8 chunks
#pragma unroll
    for (int it = 0; it < 4; ++it) {
        int unit = it * 512 + tid;
        int rowl = unit >> 3, ck = unit & 7;
        *(short8*)&hn2b[(arow0 + rowl) * 256 + cb * 64 + ck * 8] =
            *(const short8*)&sO[rowl * 72 + ck * 8];
    }
}

// ---------------- LayerNorm over hn2 (bf16) + mask -> hb ----------------
__global__ __launch_bounds__(256) void ln_kernel(
    const short* __restrict__ hn2b, short* __restrict__ hb,
    const int* __restrict__ mask,
    const float* __restrict__ lng, const float* __restrict__ lnb) {
    int t = threadIdx.x;
    int bl = tok_swizzle(blockIdx.x) + (t >> 6);
    int lane = t & 63;
    short4v v4 = *(const short4v*)&hn2b[(size_t)bl * C_ + lane * 4];
    float v[4] = {bf2f(v4.x), bf2f(v4.y), bf2f(v4.z), bf2f(v4.w)};
    float s = (v[0] + v[1]) + (v[2] + v[3]);
    float ss = (v[0] * v[0] + v[1] * v[1]) + (v[2] * v[2] + v[3] * v[3]);
#pragma unroll
    for (int off = 32; off; off >>= 1) {
        s += __shfl_xor(s, off);
        ss += __shfl_xor(ss, off);
    }
    float mu = s * (1.f / 256.f);
    float var = ss * (1.f / 256.f) - mu * mu;
    float rstd = rsqrtf(fmaxf(var, 0.f) + 1e-5f);
    float4 lg = *(const float4*)&lng[lane * 4];
    float4 lb = *(const float4*)&lnb[lane * 4];
    float mfv = mask[bl] ? 1.f : 0.f;
    short4v yb;
    yb.x = f2bf(((v[0] - mu) * rstd * lg.x + lb.x) * mfv);
    yb.y = f2bf(((v[1] - mu) * rstd * lg.y + lb.y) * mfv);
    yb.z = f2bf(((v[2] - mu) * rstd * lg.z + lb.z) * mfv);
    yb.w = f2bf(((v[3] - mu) * rstd * lg.w + lb.w) * mfv);
    *(short4v*)&hb[(size_t)bl * C_ + lane * 4] = yb;
}

// ---------------- sparse GAT aggregation, vectorized short8, both dirs ----------------
__global__ __launch_bounds__(256) void agg_fused(
    const short* __restrict__ hpb2, const float* __restrict__ S,
    const int* __restrict__ mask, const int* __restrict__ logical,
    const int* __restrict__ pol, const int* __restrict__ nvalid,
    short* __restrict__ m, int dil) {
    int t = threadIdx.x;
    int bl = tok_swizzle(blockIdx.x) + (t >> 6);
    int sub = t & 63;
    int dir = sub >> 5;
    int slot = sub & 31;
    int cb = slot * 8;
    int head = slot >> 3;
    int b = bl >> 9;

    int mi = mask[bl];
    int li = logical[bl];
    int nv = nvalid[b];
    int js[3]; int nn = 0;
    if (mi) {
#pragma unroll
        for (int k = 1; k <= 3; k++) {
            int lj = dir ? (li - k * dil) : (li + k * dil);
            if (lj >= 0 && lj < nv) js[nn++] = pol[b * L_ + lj];
        }
    }
    int sn = dir * 4 + head, dn = 8 + sn;
    float si = S[(size_t)bl * 16 + sn];
    float di = S[(size_t)bl * 16 + dn];
    float e0 = si + di; e0 = e0 > 0.f ? e0 : 0.2f * e0;
    float emax = e0, ev[3];
    for (int k = 0; k < nn; k++) {
        float djv = S[((size_t)(b * L_ + js[k])) * 16 + dn];
        float e = si + djv; e = e > 0.f ? e : 0.2f * e;
        ev[k] = e; emax = fmaxf(emax, e);
    }
    float w0 = __expf(e0 - emax), den = w0;
    float wv[3];
    for (int k = 0; k < nn; k++) { wv[k] = __expf(ev[k] - emax); den += wv[k]; }
    float rden = rcp_(den);

    size_t base = (size_t)bl * 512 + dir * 256 + cb;
    short8 vself = *(const short8*)&hpb2[base];
    float o[8];
#pragma unroll
    for (int j = 0; j < 8; j++) o[j] = w0 * bf2f(vself[j]);
    for (int k = 0; k < nn; k++) {
        short8 vn = *(const short8*)&hpb2[((size_t)(b * L_ + js[k])) * 512 + dir * 256 + cb];
#pragma unroll
        for (int j = 0; j < 8; j++) o[j] = fmaf(wv[k], bf2f(vn[j]), o[j]);
    }
    short8 ov;
#pragma unroll
    for (int j = 0; j < 8; j++) ov[j] = f2bf(o[j] * rden);
    *(short8*)&m[base] = ov;
}

// ---------------- masked softmax pooling + both heads (bf16 h) ----------------
__global__ __launch_bounds__(1024) void pool_head_kernel(
    const short* __restrict__ hb, const int* __restrict__ mask,
    const float* __restrict__ pw, const float* __restrict__ pb,
    const float* __restrict__ h0W, const float* __restrict__ h0b,
    const float* __restrict__ h1W, const float* __restrict__ h1b,
    float* __restrict__ out) {
    int b = blockIdx.x;
    int t = threadIdx.x;
    int lane = t & 63, wave = t >> 6;
    __shared__ float sc[L_];
    __shared__ float red[20];
    __shared__ float part[4][C_];
    __shared__ float pooled[C_];

    float4 wv = *(const float4*)&pw[lane * 4];
    for (int l = wave; l < L_; l += 16) {
        short4v hv = *(const short4v*)&hb[((size_t)b * L_ + l) * C_ + lane * 4];
        float p = bf2f(hv.x) * wv.x + bf2f(hv.y) * wv.y
                + bf2f(hv.z) * wv.z + bf2f(hv.w) * wv.w;
#pragma unroll
        for (int off = 32; off; off >>= 1) p += __shfl_down(p, off);
        if (lane == 0) sc[l] = mask[b * L_ + l] ? (p + pb[0]) : NEGV;
    }
    __syncthreads();

    float v = (t < L_) ? sc[t] : NEGV;
    float mx = v;
#pragma unroll
    for (int off = 32; off; off >>= 1) mx = fmaxf(mx, __shfl_down(mx, off));
    if (lane == 0) red[wave] = mx;
    __syncthreads();
    if (t == 0) {
        float g = red[0];
        for (int i = 1; i < 16; i++) g = fmaxf(g, red[i]);
        red[16] = g;
    }
    __syncthreads();
    float gmax = red[16];
    float e = (t < L_) ? __expf(v - gmax) : 0.f;
    float ssum = e;
#pragma unroll
    for (int off = 32; off; off >>= 1) ssum += __shfl_down(ssum, off);
    if (lane == 0) red[wave] = ssum;
    __syncthreads();
    if (t == 0) {
        float g = 0.f;
        for (int i = 0; i < 16; i++) g += red[i];
        red[17] = 1.f / g;
    }
    __syncthreads();
    if (t < L_) sc[t] = e * red[17];
    __syncthreads();

    int g = t >> 8, c = t & 255;
    const short* hrow = &hb[((size_t)b * L_ + g * 128) * C_ + c];
    const float* scg = &sc[g * 128];
    float a0 = 0.f, a1 = 0.f, a2 = 0.f, a3 = 0.f;
    for (int l = 0; l < 128; l += 4) {
        a0 = fmaf(scg[l + 0], bf2f(hrow[(size_t)(l + 0) * C_]), a0);
        a1 = fmaf(scg[l + 1], bf2f(hrow[(size_t)(l + 1) * C_]), a1);
        a2 = fmaf(scg[l + 2], bf2f(hrow[(size_t)(l + 2) * C_]), a2);
        a3 = fmaf(scg[l + 3], bf2f(hrow[(size_t)(l + 3) * C_]), a3);
    }
    part[g][c] = (a0 + a1) + (a2 + a3);
    __syncthreads();
    if (t < C_) pooled[t] = (part[0][t] + part[1][t]) + (part[2][t] + part[3][t]);
    __syncthreads();

    for (int o = wave; o < 70; o += 16) {
        const float* W = (o < 50) ? (h0W + (size_t)o * C_) : (h1W + (size_t)(o - 50) * C_);
        float bb = (o < 50) ? h0b[o] : h1b[o - 50];
        float4 w4 = *(const float4*)&W[lane * 4];
        float4 p4 = *(const float4*)&pooled[lane * 4];
        float s = p4.x * w4.x + p4.y * w4.y + p4.z * w4.z + p4.w * w4.w;
#pragma unroll
        for (int off = 32; off; off >>= 1) s += __shfl_down(s, off);
        if (lane == 0) out[b * 70 + o] = s + bb;
    }
}

extern "C" void kernel_launch(void* const* d_in, const int* in_sizes, int n_in,
                              void* d_out, int out_size, void* d_ws, size_t ws_size,
                              hipStream_t stream) {
    const int*   x    = (const int*)d_in[0];
    const float* emb  = (const float*)d_in[1];
    const float* pos  = (const float*)d_in[2];
    const float* gpW  = (const float*)d_in[3];
    const float* gpas = (const float*)d_in[4];
    const float* gpad = (const float*)d_in[5];
    const float* gfW  = (const float*)d_in[6];
    const float* gfas = (const float*)d_in[7];
    const float* gfad = (const float*)d_in[8];
    const float* msgW = (const float*)d_in[9];
    const float* msgb = (const float*)d_in[10];
    const float* Wih  = (const float*)d_in[11];
    const float* bih  = (const float*)d_in[12];
    const float* Whh  = (const float*)d_in[13];
    const float* bhh  = (const float*)d_in[14];
    const float* lng  = (const float*)d_in[15];
    const float* lnb  = (const float*)d_in[16];
    const float* pw   = (const float*)d_in[17];
    const float* pb   = (const float*)d_in[18];
    const float* h0W  = (const float*)d_in[19];
    const float* h0b  = (const float*)d_in[20];
    const float* h1W  = (const float*)d_in[21];
    const float* h1b  = (const float*)d_in[22];
    float* out = (float*)d_out;

    // Workspace layout, units MW = 1Mi floats = 4 MiB:
    //   hn2b bf16 [32768, 256] =  4 MW   -> [ 0,  4)
    //   hb   bf16 [32768, 256] =  4 MW   -> [ 8, 12)
    //   mmb  bf16 [32768, 256] =  4 MW   -> [12, 16)   (also Ssd fp32 [32768,16])
    //   hpb2 bf16 [32768, 512] =  8 MW   -> [16, 24)
    //   mb   bf16 [32768, 512] =  8 MW   -> [24, 32)
    //   weights/bias/masks               -> [32, ~33.3)
    const size_t MW = 1024 * 1024;
    float* ws = (float*)d_ws;
    short* hn2b = (short*)ws;
    short* hb   = (short*)(ws + 8 * MW);
    short* mmb  = (short*)(ws + 12 * MW);
    float* Ssd  = ws + 12 * MW;                          // aliases mmb (timeshared)
    short* hpb2 = (short*)(ws + 16 * MW);
    short* mb   = (short*)(ws + 24 * MW);
    short* Wcomb = (short*)(ws + 32 * MW);               // 3*640*256 shorts
    short* msgWb = Wcomb + 3 * 640 * 256;                // 3*256*512 shorts
    short* Bcat  = msgWb + 3 * 256 * 512;                // 3*1024*512 shorts (interleaved)
    float* bias4 = (float*)(Bcat + 3 * 1024 * 512);      // 3*1024 floats
    int* mask    = (int*)(bias4 + 3 * 1024);
    int* logical = mask + B_ * L_;
    int* pol     = logical + B_ * L_;
    int* nvalid  = pol + B_ * L_;

    // weight prep
    prep_wcomb<<<(3 * 640 * 256 + 255) / 256, 256, 0, stream>>>(gpW, gfW, gpas, gpad,
                                                                gfas, gfad, Wcomb);
    f2bf_kernel<<<(3 * 256 * 512 + 255) / 256, 256, 0, stream>>>(msgW, msgWb, 3 * 256 * 512);
    prep_gru_i<<<(3 * 1024 * 512 + 255) / 256, 256, 0, stream>>>(Wih, Whh, Bcat);
    prep_bias4<<<12, 256, 0, stream>>>(bih, bhh, bias4);

    scan_kernel<<<B_, L_, 0, stream>>>(x, mask, logical, pol, nvalid);
    embed_kernel<<<B_ * L_ / 4, 256, 0, stream>>>(x, emb, pos, hb);

    const int DILS[LAY] = {1, 2, 4};

    for (int l = 0; l < LAY; l++) {
        int dil = DILS[l];
        // hpb2 (N=512 bf16) + Ssd (16 fp32 cols) in one dispatch
        projssd_bgemm<<<256 * 5, 256, 0, stream>>>(hb, Wcomb + (size_t)l * 640 * 256,
                                                   hpb2, Ssd);
        // sparse GAT aggregation, both dirs in one wave, short8-vectorized
        agg_fused<<<8192, 256, 0, stream>>>(hpb2, Ssd, mask, logical, pol, nvalid, mb, dil);
        // mm = relu(m @ msgW^T + msgb) -> bf16  (CB=2, overwrites Ssd region)
        bgemm<<<256 * 2, 256, 0, stream>>>(mb, msgWb + (size_t)l * 256 * 512,
                                           mmb, msgb + l * C_, 512, 512, 256, 256, 1,
                                           GF_BIAS | GF_RELU | GF_OBF16);
        // 256x256-tile pipelined GRU GEMM + fast-gate epilogue -> hn2b bf16 [32768,256]
        gru_bgemm<<<512, 512, 0, stream>>>(mmb, hb, Bcat + (size_t)l * 1024 * 512,
                                           hn2b, bias4 + l * 1024);
        // LayerNorm + mask -> hb
        ln_kernel<<<8192, 256, 0, stream>>>(hn2b, hb, mask, lng + l * C_, lnb + l * C_);
    }

    pool_head_kernel<<<B_, 1024, 0, stream>>>(hb, mask, pw, pb, h0W, h0b, h1W, h1b, out);
}

// Round 2
// 539.623 us; speedup vs baseline: 1.0480x; 1.0323x over previous
//
#include <hip/hip_runtime.h>
#include <math.h>

#define B_ 64
#define L_ 512
#define C_ 256
#define H_ 4
#define LAY 3
#define NEGV -1e9f

#define GF_BIAS  1
#define GF_RELU  2
#define GF_OBF16 4

typedef __attribute__((ext_vector_type(8))) short short8;
typedef __attribute__((ext_vector_type(4))) short short4v;
typedef __attribute__((ext_vector_type(4))) float floatx4;

static __device__ __forceinline__ float rcp_(float x) { return __builtin_amdgcn_rcpf(x); }
static __device__ __forceinline__ float sig_(float x) { return rcp_(1.f + __expf(-x)); }
static __device__ __forceinline__ float tanh_(float x) {
    float e = __expf(2.f * x);
    return 1.f - 2.f * rcp_(e + 1.f);
}

static __device__ __forceinline__ short f2bf(float f) {
    unsigned x = __float_as_uint(f);
    x += 0x7fffu + ((x >> 16) & 1u);       // round-to-nearest-even to bf16
    return (short)(x >> 16);
}
static __device__ __forceinline__ float bf2f(short s) {
    return __uint_as_float(((unsigned)(unsigned short)s) << 16);
}

// XCD-aligned token swizzle for elementwise consumers (matches GEMM rb%8 = XCD).
static __device__ __forceinline__ int tok_swizzle(int blk) {
    int c8 = blk & 7, i = blk >> 3;
    return (c8 + 8 * (i >> 5)) * 128 + (i & 31) * 4;
}

static __device__ __forceinline__ void gl_lds16(const short* g, short* l) {
    __builtin_amdgcn_global_load_lds(
        (const __attribute__((address_space(1))) unsigned int*)g,
        (__attribute__((address_space(3))) unsigned int*)l, 16, 0, 0);
}

#define CF() asm volatile("" ::: "memory")

// ---------------- mask / logical-position scan + pos_of_logical ----------------
__global__ void scan_kernel(const int* __restrict__ x, int* __restrict__ mask,
                            int* __restrict__ logical, int* __restrict__ pol,
                            int* __restrict__ nvalid) {
    int b = blockIdx.x, t = threadIdx.x;
    __shared__ int s[L_];
    int m = (x[b * L_ + t] != 0) ? 1 : 0;
    s[t] = m;
    __syncthreads();
    for (int off = 1; off < L_; off <<= 1) {
        int v = (t >= off) ? s[t - off] : 0;
        __syncthreads();
        s[t] += v;
        __syncthreads();
    }
    int cum = s[t];
    int lg = cum - 1; if (lg < 0) lg = 0;
    mask[b * L_ + t] = m;
    logical[b * L_ + t] = lg;
    if (m) pol[b * L_ + lg] = t;
    if (t == L_ - 1) nvalid[b] = cum;
}

// ---------------- hb = bf16((emb[x] + pos*mf)*mf) ----------------
__global__ void embed_kernel(const int* __restrict__ x, const float* __restrict__ emb,
                             const float* __restrict__ pos, short* __restrict__ hb) {
    int t = threadIdx.x;
    int bl = tok_swizzle(blockIdx.x) + (t >> 6);
    int lane = t & 63;
    int xv = x[bl];
    float mf = (xv != 0) ? 1.f : 0.f;
    int l = bl & (L_ - 1);
    float4 e = *(const float4*)&emb[(size_t)xv * C_ + lane * 4];
    float4 p = *(const float4*)&pos[(size_t)l * C_ + lane * 4];
    short4v hv4;
    hv4.x = f2bf((e.x + p.x * mf) * mf);
    hv4.y = f2bf((e.y + p.y * mf) * mf);
    hv4.z = f2bf((e.z + p.z * mf) * mf);
    hv4.w = f2bf((e.w + p.w * mf) * mf);
    *(short4v*)&hb[(size_t)bl * C_ + lane * 4] = hv4;
}

// ---------------- weight prep ----------------
__global__ void f2bf_kernel(const float* __restrict__ s, short* __restrict__ d, int n) {
    int i = blockIdx.x * 256 + threadIdx.x;
    if (i < n) d[i] = f2bf(s[i]);
}

// Wcomb[l][640][256]: rows 0..255 = gpW[l], 256..511 = gfW[l],
// rows 512..527 = AsdW (n = type*8+dir*4+head -> a_vec @ W_dir), rest 0.
__global__ void prep_wcomb(const float* __restrict__ gpW, const float* __restrict__ gfW,
                           const float* __restrict__ gpas, const float* __restrict__ gpad,
                           const float* __restrict__ gfas, const float* __restrict__ gfad,
                           short* __restrict__ Wc) {
    int i = blockIdx.x * 256 + threadIdx.x;
    if (i >= 3 * 640 * 256) return;
    int k = i & 255;
    int r = (i >> 8) % 640;
    int l = i / (640 * 256);
    float v = 0.f;
    if (r < 256) {
        v = gpW[((size_t)l * 256 + r) * 256 + k];
    } else if (r < 512) {
        v = gfW[((size_t)l * 256 + (r - 256)) * 256 + k];
    } else {
        int n = r - 512;
        if (n < 16) {
            int type = n >> 3, dir = (n >> 2) & 1, hh = n & 3;
            const float* a = type ? (dir ? gfad : gpad) : (dir ? gfas : gpas);
            const float* W = dir ? gfW : gpW;
            for (int j = 0; j < 64; j++) {
                float av = a[l * 256 + hh * 64 + j];
                float wv = W[((size_t)l * 256 + hh * 64 + j) * 256 + k];
                v = fmaf(av, wv, v);
            }
        }
    }
    Wc[i] = f2bf(v);
}

// Interleaved GRU weights: Bc[l][n'][512], n' = 4*ch + g, g in {0:r,1:z,2:i,3:n}.
__global__ void prep_gru_i(const float* __restrict__ Wih, const float* __restrict__ Whh,
                           short* __restrict__ Bc) {
    int i = blockIdx.x * 256 + threadIdx.x;
    if (i >= 3 * 1024 * 512) return;
    int k = i & 511, np = (i >> 9) & 1023, l = i >> 19;
    int ch = np >> 2, g = np & 3;
    float v = 0.f;
    if (g < 2) {
        v = (k < 256) ? Wih[((size_t)l * 768 + g * 256 + ch) * 256 + k]
                      : Whh[((size_t)l * 768 + g * 256 + ch) * 256 + (k - 256)];
    } else if (g == 2) {
        if (k < 256) v = Wih[((size_t)l * 768 + 512 + ch) * 256 + k];
    } else {
        if (k >= 256) v = Whh[((size_t)l * 768 + 512 + ch) * 256 + (k - 256)];
    }
    Bc[i] = f2bf(v);
}

// bias4[l][4*ch+g]
__global__ void prep_bias4(const float* __restrict__ bih, const float* __restrict__ bhh,
                           float* __restrict__ bc) {
    int i = blockIdx.x * 256 + threadIdx.x;
    if (i >= 3 * 1024) return;
    int np = i & 1023, l = i >> 10;
    int ch = np >> 2, g = np & 3;
    float v;
    if (g < 2)       v = bih[l * 768 + g * 256 + ch] + bhh[l * 768 + g * 256 + ch];
    else if (g == 2) v = bih[l * 768 + 512 + ch];
    else             v = bhh[l * 768 + 512 + ch];
    bc[i] = v;
}

// ---------------- plain bf16 MFMA GEMM (msg): C[M,N] = A[M,K] * B[N,K]^T ----------------
__global__ __launch_bounds__(256) void bgemm(const short* __restrict__ A0,
                                             const short* __restrict__ Bw,
                                             void* __restrict__ Cout,
                                             const float* __restrict__ bias,
                                             int K, int lda, int ldc, int nstore,
                                             int cbBits, int flags) {
    __shared__ short As[128 * 32];
    __shared__ short Bs[128 * 32];
    const int id = blockIdx.x;
    const int cb = (id >> 3) & ((1 << cbBits) - 1);
    const int rb = (id & 7) + ((id >> (3 + cbBits)) << 3);
    const int tid = threadIdx.x;
    const int wave = tid >> 6, lane = tid & 63;
    const int wm = wave >> 1, wn = wave & 1;
    const size_t arow0 = (size_t)rb * 128;
    const short* Bb = Bw + (size_t)cb * 128 * K;
    floatx4 acc[4][4];   // [nf][mf]
#pragma unroll
    for (int i = 0; i < 4; i++)
#pragma unroll
        for (int j = 0; j < 4; j++) acc[i][j] = (floatx4)0.f;

    const int srow = lane >> 2;
    const int sq = (lane & 3) * 8;
    const int q = lane >> 4, t16 = lane & 15;

    for (int k0 = 0; k0 < K; k0 += 32) {
        const short* Abase = A0 + arow0 * (size_t)lda + k0;
#pragma unroll
        for (int t = 0; t < 2; ++t) {
            int r = (wave * 2 + t) * 16 + srow;
            gl_lds16(Abase + (size_t)r * lda + sq, &As[r * 32 + sq]);
            gl_lds16(Bb + (size_t)r * K + k0 + sq, &Bs[r * 32 + sq]);
        }
        __syncthreads();
        short8 af[4], bfr[4];
#pragma unroll
        for (int mf = 0; mf < 4; mf++)
            af[mf] = *(const short8*)&As[(wm * 64 + mf * 16 + t16) * 32 + q * 8];
#pragma unroll
        for (int nf = 0; nf < 4; nf++)
            bfr[nf] = *(const short8*)&Bs[(wn * 64 + nf * 16 + t16) * 32 + q * 8];
#pragma unroll
        for (int mf = 0; mf < 4; mf++)
#pragma unroll
            for (int nf = 0; nf < 4; nf++)
                acc[nf][mf] = __builtin_amdgcn_mfma_f32_16x16x32_bf16(
                    bfr[nf], af[mf], acc[nf][mf], 0, 0, 0);
        __syncthreads();
    }

    const int rowbase = rb * 128 + wm * 64;
    const int colbase = cb * 128 + wn * 64;
#pragma unroll
    for (int nf = 0; nf < 4; nf++) {
        int col0 = colbase + nf * 16 + q * 4;
        if (col0 >= nstore) continue;
        float4 bv4 = make_float4(0.f, 0.f, 0.f, 0.f);
        if (flags & GF_BIAS) bv4 = *(const float4*)&bias[col0];
#pragma unroll
        for (int mf = 0; mf < 4; mf++) {
            int row = rowbase + mf * 16 + t16;
            float v0 = acc[nf][mf][0] + bv4.x;
            float v1 = acc[nf][mf][1] + bv4.y;
            float v2 = acc[nf][mf][2] + bv4.z;
            float v3 = acc[nf][mf][3] + bv4.w;
            if (flags & GF_RELU) {
                v0 = fmaxf(v0, 0.f); v1 = fmaxf(v1, 0.f);
                v2 = fmaxf(v2, 0.f); v3 = fmaxf(v3, 0.f);
            }
            size_t base = (size_t)row * ldc + col0;
            if (flags & GF_OBF16) {
                short4v pk;
                pk.x = f2bf(v0); pk.y = f2bf(v1); pk.z = f2bf(v2); pk.w = f2bf(v3);
                *(short4v*)&((short*)Cout)[base] = pk;
            } else {
                float4 pk = make_float4(v0, v1, v2, v3);
                *(float4*)&((float*)Cout)[base] = pk;
            }
        }
    }
}

// ---------------- projection + Ssd combined GEMM ----------------
// A = hb [32768,256] (K=256), B = Wcomb [640,256]; cb 0..3 -> hpb2 bf16 (ldc 512),
// cb 4 -> Ssd fp32 (ldc 16, 16 real cols). Grid 1280 = 256 rb x 5 cb, XCD-seq.
__global__ __launch_bounds__(256) void projssd_bgemm(const short* __restrict__ A0,
                                                     const short* __restrict__ Bw,
                                                     short* __restrict__ hpb2,
                                                     float* __restrict__ Ssd) {
    __shared__ short As[128 * 32];
    __shared__ short Bs[128 * 32];
    const int id = blockIdx.x;
    const int grp = id >> 3;
    const int cb = grp % 5;
    const int rb = (id & 7) + (grp / 5) * 8;
    const int tid = threadIdx.x;
    const int wave = tid >> 6, lane = tid & 63;
    const int wm = wave >> 1, wn = wave & 1;
    const size_t arow0 = (size_t)rb * 128;
    const short* Bb = Bw + (size_t)cb * 128 * 256;
    floatx4 acc[4][4];
#pragma unroll
    for (int i = 0; i < 4; i++)
#pragma unroll
        for (int j = 0; j < 4; j++) acc[i][j] = (floatx4)0.f;

    const int srow = lane >> 2;
    const int sq = (lane & 3) * 8;
    const int q = lane >> 4, t16 = lane & 15;

    for (int k0 = 0; k0 < 256; k0 += 32) {
        const short* Abase = A0 + arow0 * 256 + k0;
#pragma unroll
        for (int t = 0; t < 2; ++t) {
            int r = (wave * 2 + t) * 16 + srow;
            gl_lds16(Abase + (size_t)r * 256 + sq, &As[r * 32 + sq]);
            gl_lds16(Bb + (size_t)r * 256 + k0 + sq, &Bs[r * 32 + sq]);
        }
        __syncthreads();
        short8 af[4], bfr[4];
#pragma unroll
        for (int mf = 0; mf < 4; mf++)
            af[mf] = *(const short8*)&As[(wm * 64 + mf * 16 + t16) * 32 + q * 8];
#pragma unroll
        for (int nf = 0; nf < 4; nf++)
            bfr[nf] = *(const short8*)&Bs[(wn * 64 + nf * 16 + t16) * 32 + q * 8];
#pragma unroll
        for (int mf = 0; mf < 4; mf++)
#pragma unroll
            for (int nf = 0; nf < 4; nf++)
                acc[nf][mf] = __builtin_amdgcn_mfma_f32_16x16x32_bf16(
                    bfr[nf], af[mf], acc[nf][mf], 0, 0, 0);
        __syncthreads();
    }

    const int rowbase = rb * 128 + wm * 64;
    if (cb < 4) {
        const int colbase = cb * 128 + wn * 64;
#pragma unroll
        for (int nf = 0; nf < 4; nf++) {
            int col0 = colbase + nf * 16 + q * 4;
#pragma unroll
            for (int mf = 0; mf < 4; mf++) {
                int row = rowbase + mf * 16 + t16;
                short4v pk;
                pk.x = f2bf(acc[nf][mf][0]);
                pk.y = f2bf(acc[nf][mf][1]);
                pk.z = f2bf(acc[nf][mf][2]);
                pk.w = f2bf(acc[nf][mf][3]);
                *(short4v*)&hpb2[(size_t)row * 512 + col0] = pk;
            }
        }
    } else {
        // Ssd: cols 512..639 map to 0..127; only first 16 real (wn=0, nf=0)
        if (wn == 0) {
            int col0 = q * 4;   // nf = 0
            if (col0 < 16) {
#pragma unroll
                for (int mf = 0; mf < 4; mf++) {
                    int row = rowbase + mf * 16 + t16;
                    float4 pk = make_float4(acc[0][mf][0], acc[0][mf][1],
                                            acc[0][mf][2], acc[0][mf][3]);
                    *(float4*)&Ssd[(size_t)row * 16 + col0] = pk;
                }
            }
        }
    }
}

// ---------------- GRU GEMM fragment helpers (256x256 tile, 8-phase schedule) ----
static __device__ __forceinline__ short8 lds_rd8(const short* p) {
    return *(const short8*)p;
}

template <int MH>
static __device__ __forceinline__ void ld_af(const short* bufA, int wm, int q, int t16,
                                             short8 af[4][2]) {
#pragma unroll
    for (int mfl = 0; mfl < 4; ++mfl) {
        int row = wm * 128 + (MH * 4 + mfl) * 16 + t16;
#pragma unroll
        for (int ks = 0; ks < 2; ++ks) {
            int cg = (ks * 4 + q) ^ (row & 7);
            af[mfl][ks] = lds_rd8(&bufA[row * 64 + cg * 8]);
        }
    }
}

template <int NH>
static __device__ __forceinline__ void ld_bf(const short* bufB, int wn, int q, int t16,
                                             short8 bf[2][2]) {
#pragma unroll
    for (int nfl = 0; nfl < 2; ++nfl) {
        int row = wn * 64 + (NH * 2 + nfl) * 16 + t16;
#pragma unroll
        for (int ks = 0; ks < 2; ++ks) {
            int cg = (ks * 4 + q) ^ (row & 7);
            bf[nfl][ks] = lds_rd8(&bufB[row * 64 + cg * 8]);
        }
    }
}

template <int MH, int NH>
static __device__ __forceinline__ void mfma_q(const short8 af[4][2], const short8 bf[2][2],
                                              floatx4 acc[4][8]) {
    __builtin_amdgcn_s_setprio(1);
#pragma unroll
    for (int ks = 0; ks < 2; ++ks)
#pragma unroll
        for (int mfl = 0; mfl < 4; ++mfl)
#pragma unroll
            for (int nfl = 0; nfl < 2; ++nfl)
                acc[NH * 2 + nfl][MH * 4 + mfl] = __builtin_amdgcn_mfma_f32_16x16x32_bf16(
                    bf[nfl][ks], af[mfl][ks], acc[NH * 2 + nfl][MH * 4 + mfl], 0, 0, 0);
    __builtin_amdgcn_s_setprio(0);
}

// ---------------- dedicated GRU GEMM, 256x256 tile, 8-phase counted-vmcnt ----------
// A = [mmb | hb] K=512, B = Bcat interleaved (N=1024, n'=4ch+g).
// 8 waves (2M x 4N), BK=64, dbuf 128 KiB LDS, XOR-swizzle (src-perm + read-perm).
// Per K-tile: 4 quadrant phases {ds_read frag subtile; issue 1 half-tile stage;
// s_barrier; lgkmcnt(0); setprio(1); 16 MFMA; setprio(0); s_barrier}.
// Half-tile units issued at [t-1.P3, t.P0, t.P1, t.P2]; boundary wait vmcnt(2)
// (next tile's A-half0 stays in flight) - loads cross all intra-tile barriers.
// XCD swizzle: rb = 16*(id&7) + (id>>5), cb = (id>>3)&3 -> each XCD gets 16
// contiguous A panels x all 4 cb; the 4 cb-blocks of one panel run concurrently
// on adjacent CUs of the same XCD (A fetched once into that XCD's L2).
__global__ __launch_bounds__(512, 2) void gru_bgemm(const short* __restrict__ mmb,
                                                    const short* __restrict__ hb_in,
                                                    const short* __restrict__ Bw,
                                                    short* __restrict__ hn2b,
                                                    const float* __restrict__ bias4) {
    __shared__ short lds[2][32768];   // per buf: A[256][64] @0, B[256][64] @16384
    const int id = blockIdx.x;
    const int rb = 16 * (id & 7) + (id >> 5);
    const int cb = (id >> 3) & 3;
    const int tid = threadIdx.x;
    const int wave = tid >> 6, lane = tid & 63;
    const int wm = wave >> 2, wn = wave & 3;
    const int q = lane >> 4, t16 = lane & 15;
    const size_t arow0 = (size_t)rb * 256;
    const short* Bb = Bw + (size_t)cb * 256 * 512;

    floatx4 acc[4][8];   // [nf][mf]
#pragma unroll
    for (int i = 0; i < 4; i++)
#pragma unroll
        for (int j = 0; j < 8; j++) acc[i][j] = (floatx4)0.f;

    // half-tile stage units: 2 x gl_lds16 per thread each. Linear LDS dest,
    // inverse-swizzled global source (involution cs = c ^ (row&7)).
    auto stageA = [&](int tt, int Hh) {
        const short* Asrc = (tt < 4) ? (mmb + tt * 64) : (hb_in + (tt - 4) * 64);
        short* bufA = lds[tt & 1];
#pragma unroll
        for (int i = 0; i < 2; ++i) {
            int unit = i * 512 + tid;              // 0..1023
            int row = Hh * 128 + (unit >> 3);
            int cs = (unit & 7) ^ (row & 7);
            gl_lds16(Asrc + (arow0 + (size_t)row) * 256 + cs * 8,
                     bufA + Hh * 8192 + unit * 8);
        }
    };
    auto stageB = [&](int tt, int Hh) {
        short* bufB = lds[tt & 1] + 16384;
#pragma unroll
        for (int i = 0; i < 2; ++i) {
            int unit = i * 512 + tid;
            int row = Hh * 128 + (unit >> 3);
            int cs = (unit & 7) ^ (row & 7);
            gl_lds16(Bb + (size_t)row * 512 + tt * 64 + cs * 8,
                     bufB + Hh * 8192 + unit * 8);
        }
    };

    // prologue: tiles 0 and 1 fully issued; wait tile 0 (8 newest = tile 1 in flight)
    stageA(0, 0); stageB(0, 0); stageA(0, 1); stageB(0, 1);
    stageA(1, 0); stageB(1, 0); stageA(1, 1); stageB(1, 1);
    asm volatile("s_waitcnt vmcnt(8)" ::: "memory");
    CF(); __builtin_amdgcn_s_barrier(); CF();

    short8 af[4][2], b0[2][2], b1[2][2];

#pragma unroll
    for (int t = 0; t < 8; ++t) {
        const short* bufA = lds[t & 1];
        const short* bufB = lds[t & 1] + 16384;

        // ---- P0: quadrant (0,0) ----
        ld_af<0>(bufA, wm, q, t16, af);
        ld_bf<0>(bufB, wn, q, t16, b0);
        if (t > 0 && t < 7) stageB(t + 1, 0);
        CF(); __builtin_amdgcn_s_barrier();
        asm volatile("s_waitcnt lgkmcnt(0)" ::: "memory");
        mfma_q<0, 0>(af, b0, acc);
        CF(); __builtin_amdgcn_s_barrier(); CF();

        // ---- P1: quadrant (0,1) ----
        ld_bf<1>(bufB, wn, q, t16, b1);
        if (t > 0 && t < 7) stageA(t + 1, 1);
        CF(); __builtin_amdgcn_s_barrier();
        asm volatile("s_waitcnt lgkmcnt(0)" ::: "memory");
        mfma_q<0, 1>(af, b1, acc);
        CF(); __builtin_amdgcn_s_barrier(); CF();

        // ---- P2: quadrant (1,1) ----
        ld_af<1>(bufA, wm, q, t16, af);
        if (t > 0 && t < 7) stageB(t + 1, 1);
        CF(); __builtin_amdgcn_s_barrier();
        asm volatile("s_waitcnt lgkmcnt(0)" ::: "memory");
        mfma_q<1, 1>(af, b1, acc);
        CF(); __builtin_amdgcn_s_barrier(); CF();

        // ---- P3: quadrant (1,0) ---- (no frag reads; bufA[t&1] free after P2)
        if (t < 6) stageA(t + 2, 0);
        CF(); __builtin_amdgcn_s_barrier();
        mfma_q<1, 0>(af, b0, acc);
        // tile boundary: all su(t+1) complete; su(t+2).A0 (2 instr) stays in flight
        if (t < 6)       asm volatile("s_waitcnt vmcnt(2)" ::: "memory");
        else if (t == 6) asm volatile("s_waitcnt vmcnt(0)" ::: "memory");
        CF(); __builtin_amdgcn_s_barrier(); CF();
    }

    // epilogue: load h_prev (L2-hot), compute gates, stage hn2 tile in LDS.
    // acc[nf][mf] lanes j = gates (r,z,i,n) of channel ch (interleaved B).
    short* sO = (short*)lds;                   // [256][72] bf16 (pad: align + banks)
#pragma unroll
    for (int nf = 0; nf < 4; nf++) {
        int chl = wn * 16 + nf * 4 + q;        // 0..63 within block
        int col0 = cb * 256 + wn * 64 + nf * 16 + q * 4;
        float4 bv4 = *(const float4*)&bias4[col0];
#pragma unroll
        for (int mf = 0; mf < 8; mf++) {
            int rowl = wm * 128 + mf * 16 + t16;
            size_t grow = arow0 + rowl;
            float r = sig_(acc[nf][mf][0] + bv4.x);
            float z = sig_(acc[nf][mf][1] + bv4.y);
            float nv = tanh_((acc[nf][mf][2] + bv4.z) + r * (acc[nf][mf][3] + bv4.w));
            float hp = bf2f(hb_in[grow * 256 + cb * 64 + chl]);
            sO[rowl * 72 + chl] = f2bf((1.f - z) * nv + z * hp);
        }
    }
    __syncthreads();
    // coalesced write: 256 rows x 64 ch, short8 chunks
#pragma unroll
    for (int it = 0; it < 4; ++it) {
        int unit = it * 512 + tid;
        int rowl = unit >> 3, ck = unit & 7;
        *(short8*)&hn2b[(arow0 + rowl) * 256 + cb * 64 + ck * 8] =
            *(const short8*)&sO[rowl * 72 + ck * 8];
    }
}

// ---------------- LayerNorm over hn2 (bf16) + mask -> hb ----------------
__global__ __launch_bounds__(256) void ln_kernel(
    const short* __restrict__ hn2b, short* __restrict__ hb,
    const int* __restrict__ mask,
    const float* __restrict__ lng, const float* __restrict__ lnb) {
    int t = threadIdx.x;
    int bl = tok_swizzle(blockIdx.x) + (t >> 6);
    int lane = t & 63;
    short4v v4 = *(const short4v*)&hn2b[(size_t)bl * C_ + lane * 4];
    float v[4] = {bf2f(v4.x), bf2f(v4.y), bf2f(v4.z), bf2f(v4.w)};
    float s = (v[0] + v[1]) + (v[2] + v[3]);
    float ss = (v[0] * v[0] + v[1] * v[1]) + (v[2] * v[2] + v[3] * v[3]);
#pragma unroll
    for (int off = 32; off; off >>= 1) {
        s += __shfl_xor(s, off);
        ss += __shfl_xor(ss, off);
    }
    float mu = s * (1.f / 256.f);
    float var = ss * (1.f / 256.f) - mu * mu;
    float rstd = rsqrtf(fmaxf(var, 0.f) + 1e-5f);
    float4 lg = *(const float4*)&lng[lane * 4];
    float4 lb = *(const float4*)&lnb[lane * 4];
    float mfv = mask[bl] ? 1.f : 0.f;
    short4v yb;
    yb.x = f2bf(((v[0] - mu) * rstd * lg.x + lb.x) * mfv);
    yb.y = f2bf(((v[1] - mu) * rstd * lg.y + lb.y) * mfv);
    yb.z = f2bf(((v[2] - mu) * rstd * lg.z + lb.z) * mfv);
    yb.w = f2bf(((v[3] - mu) * rstd * lg.w + lb.w) * mfv);
    *(short4v*)&hb[(size_t)bl * C_ + lane * 4] = yb;
}

// ---------------- sparse GAT aggregation, vectorized short8, both dirs ----------------
__global__ __launch_bounds__(256) void agg_fused(
    const short* __restrict__ hpb2, const float* __restrict__ S,
    const int* __restrict__ mask, const int* __restrict__ logical,
    const int* __restrict__ pol, const int* __restrict__ nvalid,
    short* __restrict__ m, int dil) {
    int t = threadIdx.x;
    int bl = tok_swizzle(blockIdx.x) + (t >> 6);
    int sub = t & 63;
    int dir = sub >> 5;
    int slot = sub & 31;
    int cb = slot * 8;
    int head = slot >> 3;
    int b = bl >> 9;

    int mi = mask[bl];
    int li = logical[bl];
    int nv = nvalid[b];
    int js[3]; int nn = 0;
    if (mi) {
#pragma unroll
        for (int k = 1; k <= 3; k++) {
            int lj = dir ? (li - k * dil) : (li + k * dil);
            if (lj >= 0 && lj < nv) js[nn++] = pol[b * L_ + lj];
        }
    }
    int sn = dir * 4 + head, dn = 8 + sn;
    float si = S[(size_t)bl * 16 + sn];
    float di = S[(size_t)bl * 16 + dn];
    float e0 = si + di; e0 = e0 > 0.f ? e0 : 0.2f * e0;
    float emax = e0, ev[3];
    for (int k = 0; k < nn; k++) {
        float djv = S[((size_t)(b * L_ + js[k])) * 16 + dn];
        float e = si + djv; e = e > 0.f ? e : 0.2f * e;
        ev[k] = e; emax = fmaxf(emax, e);
    }
    float w0 = __expf(e0 - emax), den = w0;
    float wv[3];
    for (int k = 0; k < nn; k++) { wv[k] = __expf(ev[k] - emax); den += wv[k]; }
    float rden = rcp_(den);

    size_t base = (size_t)bl * 512 + dir * 256 + cb;
    short8 vself = *(const short8*)&hpb2[base];
    float o[8];
#pragma unroll
    for (int j = 0; j < 8; j++) o[j] = w0 * bf2f(vself[j]);
    for (int k = 0; k < nn; k++) {
        short8 vn = *(const short8*)&hpb2[((size_t)(b * L_ + js[k])) * 512 + dir * 256 + cb];
#pragma unroll
        for (int j = 0; j < 8; j++) o[j] = fmaf(wv[k], bf2f(vn[j]), o[j]);
    }
    short8 ov;
#pragma unroll
    for (int j = 0; j < 8; j++) ov[j] = f2bf(o[j] * rden);
    *(short8*)&m[base] = ov;
}

// ---------------- masked softmax pooling + both heads (bf16 h) ----------------
__global__ __launch_bounds__(1024) void pool_head_kernel(
    const short* __restrict__ hb, const int* __restrict__ mask,
    const float* __restrict__ pw, const float* __restrict__ pb,
    const float* __restrict__ h0W, const float* __restrict__ h0b,
    const float* __restrict__ h1W, const float* __restrict__ h1b,
    float* __restrict__ out) {
    int b = blockIdx.x;
    int t = threadIdx.x;
    int lane = t & 63, wave = t >> 6;
    __shared__ float sc[L_];
    __shared__ float red[20];
    __shared__ float part[4][C_];
    __shared__ float pooled[C_];

    float4 wv = *(const float4*)&pw[lane * 4];
    for (int l = wave; l < L_; l += 16) {
        short4v hv = *(const short4v*)&hb[((size_t)b * L_ + l) * C_ + lane * 4];
        float p = bf2f(hv.x) * wv.x + bf2f(hv.y) * wv.y
                + bf2f(hv.z) * wv.z + bf2f(hv.w) * wv.w;
#pragma unroll
        for (int off = 32; off; off >>= 1) p += __shfl_down(p, off);
        if (lane == 0) sc[l] = mask[b * L_ + l] ? (p + pb[0]) : NEGV;
    }
    __syncthreads();

    float v = (t < L_) ? sc[t] : NEGV;
    float mx = v;
#pragma unroll
    for (int off = 32; off; off >>= 1) mx = fmaxf(mx, __shfl_down(mx, off));
    if (lane == 0) red[wave] = mx;
    __syncthreads();
    if (t == 0) {
        float g = red[0];
        for (int i = 1; i < 16; i++) g = fmaxf(g, red[i]);
        red[16] = g;
    }
    __syncthreads();
    float gmax = red[16];
    float e = (t < L_) ? __expf(v - gmax) : 0.f;
    float ssum = e;
#pragma unroll
    for (int off = 32; off; off >>= 1) ssum += __shfl_down(ssum, off);
    if (lane == 0) red[wave] = ssum;
    __syncthreads();
    if (t == 0) {
        float g = 0.f;
        for (int i = 0; i < 16; i++) g += red[i];
        red[17] = 1.f / g;
    }
    __syncthreads();
    if (t < L_) sc[t] = e * red[17];
    __syncthreads();

    int g = t >> 8, c = t & 255;
    const short* hrow = &hb[((size_t)b * L_ + g * 128) * C_ + c];
    const float* scg = &sc[g * 128];
    float a0 = 0.f, a1 = 0.f, a2 = 0.f, a3 = 0.f;
    for (int l = 0; l < 128; l += 4) {
        a0 = fmaf(scg[l + 0], bf2f(hrow[(size_t)(l + 0) * C_]), a0);
        a1 = fmaf(scg[l + 1], bf2f(hrow[(size_t)(l + 1) * C_]), a1);
        a2 = fmaf(scg[l + 2], bf2f(hrow[(size_t)(l + 2) * C_]), a2);
        a3 = fmaf(scg[l + 3], bf2f(hrow[(size_t)(l + 3) * C_]), a3);
    }
    part[g][c] = (a0 + a1) + (a2 + a3);
    __syncthreads();
    if (t < C_) pooled[t] = (part[0][t] + part[1][t]) + (part[2][t] + part[3][t]);
    __syncthreads();

    for (int o = wave; o < 70; o += 16) {
        const float* W = (o < 50) ? (h0W + (size_t)o * C_) : (h1W + (size_t)(o - 50) * C_);
        float bb = (o < 50) ? h0b[o] : h1b[o - 50];
        float4 w4 = *(const float4*)&W[lane * 4];
        float4 p4 = *(const float4*)&pooled[lane * 4];
        float s = p4.x * w4.x + p4.y * w4.y + p4.z * w4.z + p4.w * w4.w;
#pragma unroll
        for (int off = 32; off; off >>= 1) s += __shfl_down(s, off);
        if (lane == 0) out[b * 70 + o] = s + bb;
    }
}

extern "C" void kernel_launch(void* const* d_in, const int* in_sizes, int n_in,
                              void* d_out, int out_size, void* d_ws, size_t ws_size,
                              hipStream_t stream) {
    const int*   x    = (const int*)d_in[0];
    const float* emb  = (const float*)d_in[1];
    const float* pos  = (const float*)d_in[2];
    const float* gpW  = (const float*)d_in[3];
    const float* gpas = (const float*)d_in[4];
    const float* gpad = (const float*)d_in[5];
    const float* gfW  = (const float*)d_in[6];
    const float* gfas = (const float*)d_in[7];
    const float* gfad = (const float*)d_in[8];
    const float* msgW = (const float*)d_in[9];
    const float* msgb = (const float*)d_in[10];
    const float* Wih  = (const float*)d_in[11];
    const float* bih  = (const float*)d_in[12];
    const float* Whh  = (const float*)d_in[13];
    const float* bhh  = (const float*)d_in[14];
    const float* lng  = (const float*)d_in[15];
    const float* lnb  = (const float*)d_in[16];
    const float* pw   = (const float*)d_in[17];
    const float* pb   = (const float*)d_in[18];
    const float* h0W  = (const float*)d_in[19];
    const float* h0b  = (const float*)d_in[20];
    const float* h1W  = (const float*)d_in[21];
    const float* h1b  = (const float*)d_in[22];
    float* out = (float*)d_out;

    // Workspace layout, units MW = 1Mi floats = 4 MiB:
    //   hn2b bf16 [32768, 256] =  4 MW   -> [ 0,  4)
    //   hb   bf16 [32768, 256] =  4 MW   -> [ 8, 12)
    //   mmb  bf16 [32768, 256] =  4 MW   -> [12, 16)   (also Ssd fp32 [32768,16])
    //   hpb2 bf16 [32768, 512] =  8 MW   -> [16, 24)
    //   mb   bf16 [32768, 512] =  8 MW   -> [24, 32)
    //   weights/bias/masks               -> [32, ~33.3)
    const size_t MW = 1024 * 1024;
    float* ws = (float*)d_ws;
    short* hn2b = (short*)ws;
    short* hb   = (short*)(ws + 8 * MW);
    short* mmb  = (short*)(ws + 12 * MW);
    float* Ssd  = ws + 12 * MW;                          // aliases mmb (timeshared)
    short* hpb2 = (short*)(ws + 16 * MW);
    short* mb   = (short*)(ws + 24 * MW);
    short* Wcomb = (short*)(ws + 32 * MW);               // 3*640*256 shorts
    short* msgWb = Wcomb + 3 * 640 * 256;                // 3*256*512 shorts
    short* Bcat  = msgWb + 3 * 256 * 512;                // 3*1024*512 shorts (interleaved)
    float* bias4 = (float*)(Bcat + 3 * 1024 * 512);      // 3*1024 floats
    int* mask    = (int*)(bias4 + 3 * 1024);
    int* logical = mask + B_ * L_;
    int* pol     = logical + B_ * L_;
    int* nvalid  = pol + B_ * L_;

    // weight prep
    prep_wcomb<<<(3 * 640 * 256 + 255) / 256, 256, 0, stream>>>(gpW, gfW, gpas, gpad,
                                                                gfas, gfad, Wcomb);
    f2bf_kernel<<<(3 * 256 * 512 + 255) / 256, 256, 0, stream>>>(msgW, msgWb, 3 * 256 * 512);
    prep_gru_i<<<(3 * 1024 * 512 + 255) / 256, 256, 0, stream>>>(Wih, Whh, Bcat);
    prep_bias4<<<12, 256, 0, stream>>>(bih, bhh, bias4);

    scan_kernel<<<B_, L_, 0, stream>>>(x, mask, logical, pol, nvalid);
    embed_kernel<<<B_ * L_ / 4, 256, 0, stream>>>(x, emb, pos, hb);

    const int DILS[LAY] = {1, 2, 4};

    for (int l = 0; l < LAY; l++) {
        int dil = DILS[l];
        // hpb2 (N=512 bf16) + Ssd (16 fp32 cols) in one dispatch
        projssd_bgemm<<<256 * 5, 256, 0, stream>>>(hb, Wcomb + (size_t)l * 640 * 256,
                                                   hpb2, Ssd);
        // sparse GAT aggregation, both dirs in one wave, short8-vectorized
        agg_fused<<<8192, 256, 0, stream>>>(hpb2, Ssd, mask, logical, pol, nvalid, mb, dil);
        // mm = relu(m @ msgW^T + msgb) -> bf16  (CB=2, overwrites Ssd region)
        bgemm<<<256 * 2, 256, 0, stream>>>(mb, msgWb + (size_t)l * 256 * 512,
                                           mmb, msgb + l * C_, 512, 512, 256, 256, 1,
                                           GF_BIAS | GF_RELU | GF_OBF16);
        // 256x256-tile 8-phase GRU GEMM + fast-gate epilogue -> hn2b bf16 [32768,256]
        gru_bgemm<<<512, 512, 0, stream>>>(mmb, hb, Bcat + (size_t)l * 1024 * 512,
                                           hn2b, bias4 + l * 1024);
        // LayerNorm + mask -> hb
        ln_kernel<<<8192, 256, 0, stream>>>(hn2b, hb, mask, lng + l * C_, lnb + l * C_);
    }

    pool_head_kernel<<<B_, 1024, 0, stream>>>(hb, mask, pw, pb, h0W, h0b, h1W, h1b, out);
}

// Round 3
// 513.353 us; speedup vs baseline: 1.1017x; 1.0512x over previous
//
#include <hip/hip_runtime.h>
#include <math.h>

#define B_ 64
#define L_ 512
#define C_ 256
#define H_ 4
#define LAY 3
#define NEGV -1e9f

#define GF_BIAS  1
#define GF_RELU  2
#define GF_OBF16 4

typedef __attribute__((ext_vector_type(8))) short short8;
typedef __attribute__((ext_vector_type(4))) short short4v;
typedef __attribute__((ext_vector_type(4))) float floatx4;

static __device__ __forceinline__ float rcp_(float x) { return __builtin_amdgcn_rcpf(x); }
static __device__ __forceinline__ float sig_(float x) { return rcp_(1.f + __expf(-x)); }
static __device__ __forceinline__ float tanh_(float x) {
    float e = __expf(2.f * x);
    return 1.f - 2.f * rcp_(e + 1.f);
}

static __device__ __forceinline__ short f2bf(float f) {
    unsigned x = __float_as_uint(f);
    x += 0x7fffu + ((x >> 16) & 1u);       // round-to-nearest-even to bf16
    return (short)(x >> 16);
}
static __device__ __forceinline__ float bf2f(short s) {
    return __uint_as_float(((unsigned)(unsigned short)s) << 16);
}

// XCD-aligned token swizzle for elementwise consumers (matches GEMM rb%8 = XCD).
static __device__ __forceinline__ int tok_swizzle(int blk) {
    int c8 = blk & 7, i = blk >> 3;
    return (c8 + 8 * (i >> 5)) * 128 + (i & 31) * 4;
}

static __device__ __forceinline__ void gl_lds16(const short* g, short* l) {
    __builtin_amdgcn_global_load_lds(
        (const __attribute__((address_space(1))) unsigned int*)g,
        (__attribute__((address_space(3))) unsigned int*)l, 16, 0, 0);
}

#define CF() asm volatile("" ::: "memory")

// ---------------- mask / logical-position scan + pos_of_logical ----------------
__global__ void scan_kernel(const int* __restrict__ x, int* __restrict__ mask,
                            int* __restrict__ logical, int* __restrict__ pol,
                            int* __restrict__ nvalid) {
    int b = blockIdx.x, t = threadIdx.x;
    __shared__ int s[L_];
    int m = (x[b * L_ + t] != 0) ? 1 : 0;
    s[t] = m;
    __syncthreads();
    for (int off = 1; off < L_; off <<= 1) {
        int v = (t >= off) ? s[t - off] : 0;
        __syncthreads();
        s[t] += v;
        __syncthreads();
    }
    int cum = s[t];
    int lg = cum - 1; if (lg < 0) lg = 0;
    mask[b * L_ + t] = m;
    logical[b * L_ + t] = lg;
    if (m) pol[b * L_ + lg] = t;
    if (t == L_ - 1) nvalid[b] = cum;
}

// ---------------- hb = bf16((emb[x] + pos*mf)*mf) ----------------
__global__ void embed_kernel(const int* __restrict__ x, const float* __restrict__ emb,
                             const float* __restrict__ pos, short* __restrict__ hb) {
    int t = threadIdx.x;
    int bl = tok_swizzle(blockIdx.x) + (t >> 6);
    int lane = t & 63;
    int xv = x[bl];
    float mf = (xv != 0) ? 1.f : 0.f;
    int l = bl & (L_ - 1);
    float4 e = *(const float4*)&emb[(size_t)xv * C_ + lane * 4];
    float4 p = *(const float4*)&pos[(size_t)l * C_ + lane * 4];
    short4v hv4;
    hv4.x = f2bf((e.x + p.x * mf) * mf);
    hv4.y = f2bf((e.y + p.y * mf) * mf);
    hv4.z = f2bf((e.z + p.z * mf) * mf);
    hv4.w = f2bf((e.w + p.w * mf) * mf);
    *(short4v*)&hb[(size_t)bl * C_ + lane * 4] = hv4;
}

// ---------------- weight prep ----------------
__global__ void f2bf_kernel(const float* __restrict__ s, short* __restrict__ d, int n) {
    int i = blockIdx.x * 256 + threadIdx.x;
    if (i < n) d[i] = f2bf(s[i]);
}

// Wcomb[l][640][256]: rows 0..255 = gpW[l], 256..511 = gfW[l],
// rows 512..527 = AsdW (n = type*8+dir*4+head -> a_vec @ W_dir), rest 0.
__global__ void prep_wcomb(const float* __restrict__ gpW, const float* __restrict__ gfW,
                           const float* __restrict__ gpas, const float* __restrict__ gpad,
                           const float* __restrict__ gfas, const float* __restrict__ gfad,
                           short* __restrict__ Wc) {
    int i = blockIdx.x * 256 + threadIdx.x;
    if (i >= 3 * 640 * 256) return;
    int k = i & 255;
    int r = (i >> 8) % 640;
    int l = i / (640 * 256);
    float v = 0.f;
    if (r < 256) {
        v = gpW[((size_t)l * 256 + r) * 256 + k];
    } else if (r < 512) {
        v = gfW[((size_t)l * 256 + (r - 256)) * 256 + k];
    } else {
        int n = r - 512;
        if (n < 16) {
            int type = n >> 3, dir = (n >> 2) & 1, hh = n & 3;
            const float* a = type ? (dir ? gfad : gpad) : (dir ? gfas : gpas);
            const float* W = dir ? gfW : gpW;
            for (int j = 0; j < 64; j++) {
                float av = a[l * 256 + hh * 64 + j];
                float wv = W[((size_t)l * 256 + hh * 64 + j) * 256 + k];
                v = fmaf(av, wv, v);
            }
        }
    }
    Wc[i] = f2bf(v);
}

// Interleaved GRU weights: Bc[l][n'][512], n' = 4*ch + g, g in {0:r,1:z,2:i,3:n}.
__global__ void prep_gru_i(const float* __restrict__ Wih, const float* __restrict__ Whh,
                           short* __restrict__ Bc) {
    int i = blockIdx.x * 256 + threadIdx.x;
    if (i >= 3 * 1024 * 512) return;
    int k = i & 511, np = (i >> 9) & 1023, l = i >> 19;
    int ch = np >> 2, g = np & 3;
    float v = 0.f;
    if (g < 2) {
        v = (k < 256) ? Wih[((size_t)l * 768 + g * 256 + ch) * 256 + k]
                      : Whh[((size_t)l * 768 + g * 256 + ch) * 256 + (k - 256)];
    } else if (g == 2) {
        if (k < 256) v = Wih[((size_t)l * 768 + 512 + ch) * 256 + k];
    } else {
        if (k >= 256) v = Whh[((size_t)l * 768 + 512 + ch) * 256 + (k - 256)];
    }
    Bc[i] = f2bf(v);
}

// bias4[l][4*ch+g]
__global__ void prep_bias4(const float* __restrict__ bih, const float* __restrict__ bhh,
                           float* __restrict__ bc) {
    int i = blockIdx.x * 256 + threadIdx.x;
    if (i >= 3 * 1024) return;
    int np = i & 1023, l = i >> 10;
    int ch = np >> 2, g = np & 3;
    float v;
    if (g < 2)       v = bih[l * 768 + g * 256 + ch] + bhh[l * 768 + g * 256 + ch];
    else if (g == 2) v = bih[l * 768 + 512 + ch];
    else             v = bhh[l * 768 + 512 + ch];
    bc[i] = v;
}

// ---------------- plain bf16 MFMA GEMM (msg): C[M,N] = A[M,K] * B[N,K]^T ----------------
// XCD-coherent mapping: id&7 = XCD; each XCD gets nrb/8 contiguous rb x all cb,
// so cb-blocks sharing an A-panel run on the same XCD (A fetched once into its L2).
__global__ __launch_bounds__(256) void bgemm(const short* __restrict__ A0,
                                             const short* __restrict__ Bw,
                                             void* __restrict__ Cout,
                                             const float* __restrict__ bias,
                                             int K, int lda, int ldc, int nstore,
                                             int cbBits, int flags) {
    __shared__ short As[128 * 32];
    __shared__ short Bs[128 * 32];
    const int id = blockIdx.x;
    const int nrb8 = gridDim.x >> (3 + cbBits);
    const int j = id >> 3;
    const int cb = j / nrb8;
    const int rb = (id & 7) * nrb8 + (j % nrb8);
    const int tid = threadIdx.x;
    const int wave = tid >> 6, lane = tid & 63;
    const int wm = wave >> 1, wn = wave & 1;
    const size_t arow0 = (size_t)rb * 128;
    const short* Bb = Bw + (size_t)cb * 128 * K;
    floatx4 acc[4][4];   // [nf][mf]
#pragma unroll
    for (int i = 0; i < 4; i++)
#pragma unroll
        for (int jj = 0; jj < 4; jj++) acc[i][jj] = (floatx4)0.f;

    const int srow = lane >> 2;
    const int sq = (lane & 3) * 8;
    const int q = lane >> 4, t16 = lane & 15;

    for (int k0 = 0; k0 < K; k0 += 32) {
        const short* Abase = A0 + arow0 * (size_t)lda + k0;
#pragma unroll
        for (int t = 0; t < 2; ++t) {
            int r = (wave * 2 + t) * 16 + srow;
            gl_lds16(Abase + (size_t)r * lda + sq, &As[r * 32 + sq]);
            gl_lds16(Bb + (size_t)r * K + k0 + sq, &Bs[r * 32 + sq]);
        }
        __syncthreads();
        short8 af[4], bfr[4];
#pragma unroll
        for (int mf = 0; mf < 4; mf++)
            af[mf] = *(const short8*)&As[(wm * 64 + mf * 16 + t16) * 32 + q * 8];
#pragma unroll
        for (int nf = 0; nf < 4; nf++)
            bfr[nf] = *(const short8*)&Bs[(wn * 64 + nf * 16 + t16) * 32 + q * 8];
#pragma unroll
        for (int mf = 0; mf < 4; mf++)
#pragma unroll
            for (int nf = 0; nf < 4; nf++)
                acc[nf][mf] = __builtin_amdgcn_mfma_f32_16x16x32_bf16(
                    bfr[nf], af[mf], acc[nf][mf], 0, 0, 0);
        __syncthreads();
    }

    const int rowbase = rb * 128 + wm * 64;
    const int colbase = cb * 128 + wn * 64;
#pragma unroll
    for (int nf = 0; nf < 4; nf++) {
        int col0 = colbase + nf * 16 + q * 4;
        if (col0 >= nstore) continue;
        float4 bv4 = make_float4(0.f, 0.f, 0.f, 0.f);
        if (flags & GF_BIAS) bv4 = *(const float4*)&bias[col0];
#pragma unroll
        for (int mf = 0; mf < 4; mf++) {
            int row = rowbase + mf * 16 + t16;
            float v0 = acc[nf][mf][0] + bv4.x;
            float v1 = acc[nf][mf][1] + bv4.y;
            float v2 = acc[nf][mf][2] + bv4.z;
            float v3 = acc[nf][mf][3] + bv4.w;
            if (flags & GF_RELU) {
                v0 = fmaxf(v0, 0.f); v1 = fmaxf(v1, 0.f);
                v2 = fmaxf(v2, 0.f); v3 = fmaxf(v3, 0.f);
            }
            size_t base = (size_t)row * ldc + col0;
            if (flags & GF_OBF16) {
                short4v pk;
                pk.x = f2bf(v0); pk.y = f2bf(v1); pk.z = f2bf(v2); pk.w = f2bf(v3);
                *(short4v*)&((short*)Cout)[base] = pk;
            } else {
                float4 pk = make_float4(v0, v1, v2, v3);
                *(float4*)&((float*)Cout)[base] = pk;
            }
        }
    }
}

// ---------------- projection + Ssd combined GEMM ----------------
// A = hb [32768,256] (K=256), B = Wcomb [640,256]; cb 0..3 -> hpb2 bf16 (ldc 512),
// cb 4 -> Ssd fp32 (ldc 16, 16 real cols). Grid 1280.
// XCD-coherent: id&7 = XCD, 32 contiguous rb x all 5 cb per XCD (A 2MB + B 320KB in L2).
__global__ __launch_bounds__(256) void projssd_bgemm(const short* __restrict__ A0,
                                                     const short* __restrict__ Bw,
                                                     short* __restrict__ hpb2,
                                                     float* __restrict__ Ssd) {
    __shared__ short As[128 * 32];
    __shared__ short Bs[128 * 32];
    const int id = blockIdx.x;
    const int j = id >> 3;                 // 0..159
    const int cb = j >> 5;                 // 0..4
    const int rb = ((id & 7) << 5) + (j & 31);   // 0..255
    const int tid = threadIdx.x;
    const int wave = tid >> 6, lane = tid & 63;
    const int wm = wave >> 1, wn = wave & 1;
    const size_t arow0 = (size_t)rb * 128;
    const short* Bb = Bw + (size_t)cb * 128 * 256;
    floatx4 acc[4][4];
#pragma unroll
    for (int i = 0; i < 4; i++)
#pragma unroll
        for (int jj = 0; jj < 4; jj++) acc[i][jj] = (floatx4)0.f;

    const int srow = lane >> 2;
    const int sq = (lane & 3) * 8;
    const int q = lane >> 4, t16 = lane & 15;

    for (int k0 = 0; k0 < 256; k0 += 32) {
        const short* Abase = A0 + arow0 * 256 + k0;
#pragma unroll
        for (int t = 0; t < 2; ++t) {
            int r = (wave * 2 + t) * 16 + srow;
            gl_lds16(Abase + (size_t)r * 256 + sq, &As[r * 32 + sq]);
            gl_lds16(Bb + (size_t)r * 256 + k0 + sq, &Bs[r * 32 + sq]);
        }
        __syncthreads();
        short8 af[4], bfr[4];
#pragma unroll
        for (int mf = 0; mf < 4; mf++)
            af[mf] = *(const short8*)&As[(wm * 64 + mf * 16 + t16) * 32 + q * 8];
#pragma unroll
        for (int nf = 0; nf < 4; nf++)
            bfr[nf] = *(const short8*)&Bs[(wn * 64 + nf * 16 + t16) * 32 + q * 8];
#pragma unroll
        for (int mf = 0; mf < 4; mf++)
#pragma unroll
            for (int nf = 0; nf < 4; nf++)
                acc[nf][mf] = __builtin_amdgcn_mfma_f32_16x16x32_bf16(
                    bfr[nf], af[mf], acc[nf][mf], 0, 0, 0);
        __syncthreads();
    }

    const int rowbase = rb * 128 + wm * 64;
    if (cb < 4) {
        const int colbase = cb * 128 + wn * 64;
#pragma unroll
        for (int nf = 0; nf < 4; nf++) {
            int col0 = colbase + nf * 16 + q * 4;
#pragma unroll
            for (int mf = 0; mf < 4; mf++) {
                int row = rowbase + mf * 16 + t16;
                short4v pk;
                pk.x = f2bf(acc[nf][mf][0]);
                pk.y = f2bf(acc[nf][mf][1]);
                pk.z = f2bf(acc[nf][mf][2]);
                pk.w = f2bf(acc[nf][mf][3]);
                *(short4v*)&hpb2[(size_t)row * 512 + col0] = pk;
            }
        }
    } else {
        // Ssd: cols 512..639 map to 0..127; only first 16 real (wn=0, nf=0)
        if (wn == 0) {
            int col0 = q * 4;   // nf = 0
            if (col0 < 16) {
#pragma unroll
                for (int mf = 0; mf < 4; mf++) {
                    int row = rowbase + mf * 16 + t16;
                    float4 pk = make_float4(acc[0][mf][0], acc[0][mf][1],
                                            acc[0][mf][2], acc[0][mf][3]);
                    *(float4*)&Ssd[(size_t)row * 16 + col0] = pk;
                }
            }
        }
    }
}

// ---------------- GRU GEMM fragment helpers (256x256 tile, 8-phase schedule) ----
static __device__ __forceinline__ short8 lds_rd8(const short* p) {
    return *(const short8*)p;
}

template <int MH>
static __device__ __forceinline__ void ld_af(const short* bufA, int wm, int q, int t16,
                                             short8 af[4][2]) {
#pragma unroll
    for (int mfl = 0; mfl < 4; ++mfl) {
        int row = wm * 128 + (MH * 4 + mfl) * 16 + t16;
#pragma unroll
        for (int ks = 0; ks < 2; ++ks) {
            int cg = (ks * 4 + q) ^ (row & 7);
            af[mfl][ks] = lds_rd8(&bufA[row * 64 + cg * 8]);
        }
    }
}

template <int NH>
static __device__ __forceinline__ void ld_bf(const short* bufB, int wn, int q, int t16,
                                             short8 bf[2][2]) {
#pragma unroll
    for (int nfl = 0; nfl < 2; ++nfl) {
        int row = wn * 64 + (NH * 2 + nfl) * 16 + t16;
#pragma unroll
        for (int ks = 0; ks < 2; ++ks) {
            int cg = (ks * 4 + q) ^ (row & 7);
            bf[nfl][ks] = lds_rd8(&bufB[row * 64 + cg * 8]);
        }
    }
}

template <int MH, int NH>
static __device__ __forceinline__ void mfma_q(const short8 af[4][2], const short8 bf[2][2],
                                              floatx4 acc[4][8]) {
    __builtin_amdgcn_s_setprio(1);
#pragma unroll
    for (int ks = 0; ks < 2; ++ks)
#pragma unroll
        for (int mfl = 0; mfl < 4; ++mfl)
#pragma unroll
            for (int nfl = 0; nfl < 2; ++nfl)
                acc[NH * 2 + nfl][MH * 4 + mfl] = __builtin_amdgcn_mfma_f32_16x16x32_bf16(
                    bf[nfl][ks], af[mfl][ks], acc[NH * 2 + nfl][MH * 4 + mfl], 0, 0, 0);
    __builtin_amdgcn_s_setprio(0);
}

// ---------------- dedicated GRU GEMM, 256x256 tile, 8-phase deep-vmcnt ----------
// A = [mmb | hb] K=512, B = Bcat interleaved (N=1024, n'=4ch+g).
// 8 waves (2M x 4N), BK=64, dbuf 128 KiB LDS, XOR-swizzle (src-perm + read-perm).
// Per K-tile: 4 quadrant phases {ds_read frag subtile; (stage); s_barrier;
// lgkmcnt(0)+sched_barrier; setprio(1); 16 MFMA; setprio(0); s_barrier}.
// DEEP staging: su(t+2).B issued at t.P2 (bufB free after P1), su(t+2).A at t.P3
// (bufA free after P2); su(t+1) was issued one full tile earlier -> at every tile
// boundary exactly ONE s_waitcnt vmcnt(8): su(t+1) (oldest 8 loads) complete,
// su(t+2) (newest 8) stay in flight across all barriers (T4, m201 depth).
// K-tile processing order rotated so the hb-slice covering this block's cb
// channels is staged LAST -> epilogue reads h_prev from LDS, not global.
// XCD swizzle: rb = 16*(id&7) + (id>>5), cb = (id>>3)&3.
__global__ __launch_bounds__(512, 2) void gru_bgemm(const short* __restrict__ mmb,
                                                    const short* __restrict__ hb_in,
                                                    const short* __restrict__ Bw,
                                                    short* __restrict__ hn2b,
                                                    const float* __restrict__ bias4) {
    __shared__ short lds[2][32768];   // per buf: A[256][64] @0, B[256][64] @16384
    const int id = blockIdx.x;
    const int rb = 16 * (id & 7) + (id >> 5);
    const int cb = (id >> 3) & 3;
    const int tid = threadIdx.x;
    const int wave = tid >> 6, lane = tid & 63;
    const int wm = wave >> 2, wn = wave & 3;
    const int q = lane >> 4, t16 = lane & 15;
    const size_t arow0 = (size_t)rb * 256;
    const short* Bb = Bw + (size_t)cb * 256 * 512;
    // tile order rotation: position i processes K-tile tt = (5+cb+i)&7, so that
    // position 7 = tile 4+cb = hb columns [cb*64, cb*64+64) -> lands in lds[1].
    const int ord0 = (5 + cb) & 7;

    floatx4 acc[4][8];   // [nf][mf]
#pragma unroll
    for (int i = 0; i < 4; i++)
#pragma unroll
        for (int jj = 0; jj < 8; jj++) acc[i][jj] = (floatx4)0.f;

    // half-tile stage units: 2 x gl_lds16 per thread each. Linear LDS dest,
    // inverse-swizzled global source (involution cs = c ^ (row&7)).
    auto stageA = [&](int i, int Hh) {
        int tt = (ord0 + i) & 7;
        const short* Asrc = (tt < 4) ? (mmb + tt * 64) : (hb_in + (tt - 4) * 64);
        short* bufA = lds[i & 1];
#pragma unroll
        for (int u = 0; u < 2; ++u) {
            int unit = u * 512 + tid;              // 0..1023
            int row = Hh * 128 + (unit >> 3);
            int cs = (unit & 7) ^ (row & 7);
            gl_lds16(Asrc + (arow0 + (size_t)row) * 256 + cs * 8,
                     bufA + Hh * 8192 + unit * 8);
        }
    };
    auto stageB = [&](int i, int Hh) {
        int tt = (ord0 + i) & 7;
        short* bufB = lds[i & 1] + 16384;
#pragma unroll
        for (int u = 0; u < 2; ++u) {
            int unit = u * 512 + tid;
            int row = Hh * 128 + (unit >> 3);
            int cs = (unit & 7) ^ (row & 7);
            gl_lds16(Bb + (size_t)row * 512 + tt * 64 + cs * 8,
                     bufB + Hh * 8192 + unit * 8);
        }
    };

    // prologue: tiles 0 and 1 fully issued (16 loads/wave);
    // wait tile 0 complete (vmcnt(8): tile 1's 8 loads stay in flight)
    stageA(0, 0); stageA(0, 1); stageB(0, 0); stageB(0, 1);
    stageA(1, 0); stageA(1, 1); stageB(1, 0); stageB(1, 1);
    asm volatile("s_waitcnt vmcnt(8)" ::: "memory");
    CF(); __builtin_amdgcn_s_barrier(); CF();

    short8 af[4][2], b0[2][2], b1[2][2];

#pragma unroll
    for (int t = 0; t < 8; ++t) {
        const short* bufA = lds[t & 1];
        const short* bufB = lds[t & 1] + 16384;

        // ---- P0: quadrant (0,0) ----
        ld_af<0>(bufA, wm, q, t16, af);
        ld_bf<0>(bufB, wn, q, t16, b0);
        CF(); __builtin_amdgcn_s_barrier();
        asm volatile("s_waitcnt lgkmcnt(0)" ::: "memory");
        __builtin_amdgcn_sched_barrier(0);
        mfma_q<0, 0>(af, b0, acc);
        CF(); __builtin_amdgcn_s_barrier(); CF();

        // ---- P1: quadrant (0,1) ----
        ld_bf<1>(bufB, wn, q, t16, b1);
        CF(); __builtin_amdgcn_s_barrier();
        asm volatile("s_waitcnt lgkmcnt(0)" ::: "memory");
        __builtin_amdgcn_sched_barrier(0);
        mfma_q<0, 1>(af, b1, acc);
        CF(); __builtin_amdgcn_s_barrier(); CF();

        // ---- P2: quadrant (1,1) ----  (bufB[t&1] free after P1's end barrier)
        ld_af<1>(bufA, wm, q, t16, af);
        if (t < 6) { stageB(t + 2, 0); stageB(t + 2, 1); }
        CF(); __builtin_amdgcn_s_barrier();
        asm volatile("s_waitcnt lgkmcnt(0)" ::: "memory");
        __builtin_amdgcn_sched_barrier(0);
        mfma_q<1, 1>(af, b1, acc);
        CF(); __builtin_amdgcn_s_barrier(); CF();

        // ---- P3: quadrant (1,0) ----  (bufA[t&1] free after P2's end barrier)
        if (t < 6) { stageA(t + 2, 0); stageA(t + 2, 1); }
        CF(); __builtin_amdgcn_s_barrier();
        mfma_q<1, 0>(af, b0, acc);
        // tile boundary: su(t+1) (oldest 8) complete; su(t+2) (8) stay in flight
        if (t < 6)       asm volatile("s_waitcnt vmcnt(8)" ::: "memory");
        else if (t == 6) asm volatile("s_waitcnt vmcnt(0)" ::: "memory");
        CF(); __builtin_amdgcn_s_barrier(); CF();
    }

    // epilogue: h_prev from LDS (lds[1] holds A-tile of tt=4+cb = hb cols cb*64..),
    // compute gates, stage hn2 tile in LDS, coalesced bf16 write.
    // acc[nf][mf] lanes j = gates (r,z,i,n) of channel ch (interleaved B).
    const short* hpt = lds[1];
    short* sO = (short*)lds;                   // [256][72] bf16 within lds[0]
#pragma unroll
    for (int nf = 0; nf < 4; nf++) {
        int chl = wn * 16 + nf * 4 + q;        // 0..63 within block
        int col0 = cb * 256 + wn * 64 + nf * 16 + q * 4;
        float4 bv4 = *(const float4*)&bias4[col0];
#pragma unroll
        for (int mf = 0; mf < 8; mf++) {
            int rowl = wm * 128 + mf * 16 + t16;
            float hp = bf2f(hpt[rowl * 64 + (((chl >> 3) ^ (rowl & 7)) << 3) + (chl & 7)]);
            float r = sig_(acc[nf][mf][0] + bv4.x);
            float z = sig_(acc[nf][mf][1] + bv4.y);
            float nv = tanh_((acc[nf][mf][2] + bv4.z) + r * (acc[nf][mf][3] + bv4.w));
            sO[rowl * 72 + chl] = f2bf((1.f - z) * nv + z * hp);
        }
    }
    __syncthreads();
    // coalesced write: 256 rows x 64 ch, short8 chunks
#pragma unroll
    for (int it = 0; it < 4; ++it) {
        int unit = it * 512 + tid;
        int rowl = unit >> 3, ck = unit & 7;
        *(short8*)&hn2b[(arow0 + rowl) * 256 + cb * 64 + ck * 8] =
            *(const short8*)&sO[rowl * 72 + ck * 8];
    }
}

// ---------------- LayerNorm over hn2 (bf16) + mask -> hb ----------------
__global__ __launch_bounds__(256) void ln_kernel(
    const short* __restrict__ hn2b, short* __restrict__ hb,
    const int* __restrict__ mask,
    const float* __restrict__ lng, const float* __restrict__ lnb) {
    int t = threadIdx.x;
    int bl = tok_swizzle(blockIdx.x) + (t >> 6);
    int lane = t & 63;
    short4v v4 = *(const short4v*)&hn2b[(size_t)bl * C_ + lane * 4];
    float v[4] = {bf2f(v4.x), bf2f(v4.y), bf2f(v4.z), bf2f(v4.w)};
    float s = (v[0] + v[1]) + (v[2] + v[3]);
    float ss = (v[0] * v[0] + v[1] * v[1]) + (v[2] * v[2] + v[3] * v[3]);
#pragma unroll
    for (int off = 32; off; off >>= 1) {
        s += __shfl_xor(s, off);
        ss += __shfl_xor(ss, off);
    }
    float mu = s * (1.f / 256.f);
    float var = ss * (1.f / 256.f) - mu * mu;
    float rstd = rsqrtf(fmaxf(var, 0.f) + 1e-5f);
    float4 lg = *(const float4*)&lng[lane * 4];
    float4 lb = *(const float4*)&lnb[lane * 4];
    float mfv = mask[bl] ? 1.f : 0.f;
    short4v yb;
    yb.x = f2bf(((v[0] - mu) * rstd * lg.x + lb.x) * mfv);
    yb.y = f2bf(((v[1] - mu) * rstd * lg.y + lb.y) * mfv);
    yb.z = f2bf(((v[2] - mu) * rstd * lg.z + lb.z) * mfv);
    yb.w = f2bf(((v[3] - mu) * rstd * lg.w + lb.w) * mfv);
    *(short4v*)&hb[(size_t)bl * C_ + lane * 4] = yb;
}

// ---------------- sparse GAT aggregation, vectorized short8, both dirs ----------------
__global__ __launch_bounds__(256) void agg_fused(
    const short* __restrict__ hpb2, const float* __restrict__ S,
    const int* __restrict__ mask, const int* __restrict__ logical,
    const int* __restrict__ pol, const int* __restrict__ nvalid,
    short* __restrict__ m, int dil) {
    int t = threadIdx.x;
    int bl = tok_swizzle(blockIdx.x) + (t >> 6);
    int sub = t & 63;
    int dir = sub >> 5;
    int slot = sub & 31;
    int cb = slot * 8;
    int head = slot >> 3;
    int b = bl >> 9;

    int mi = mask[bl];
    int li = logical[bl];
    int nv = nvalid[b];
    int js[3]; int nn = 0;
    if (mi) {
#pragma unroll
        for (int k = 1; k <= 3; k++) {
            int lj = dir ? (li - k * dil) : (li + k * dil);
            if (lj >= 0 && lj < nv) js[nn++] = pol[b * L_ + lj];
        }
    }
    int sn = dir * 4 + head, dn = 8 + sn;
    float si = S[(size_t)bl * 16 + sn];
    float di = S[(size_t)bl * 16 + dn];
    float e0 = si + di; e0 = e0 > 0.f ? e0 : 0.2f * e0;
    float emax = e0, ev[3];
    for (int k = 0; k < nn; k++) {
        float djv = S[((size_t)(b * L_ + js[k])) * 16 + dn];
        float e = si + djv; e = e > 0.f ? e : 0.2f * e;
        ev[k] = e; emax = fmaxf(emax, e);
    }
    float w0 = __expf(e0 - emax), den = w0;
    float wv[3];
    for (int k = 0; k < nn; k++) { wv[k] = __expf(ev[k] - emax); den += wv[k]; }
    float rden = rcp_(den);

    size_t base = (size_t)bl * 512 + dir * 256 + cb;
    short8 vself = *(const short8*)&hpb2[base];
    float o[8];
#pragma unroll
    for (int j = 0; j < 8; j++) o[j] = w0 * bf2f(vself[j]);
    for (int k = 0; k < nn; k++) {
        short8 vn = *(const short8*)&hpb2[((size_t)(b * L_ + js[k])) * 512 + dir * 256 + cb];
#pragma unroll
        for (int j = 0; j < 8; j++) o[j] = fmaf(wv[k], bf2f(vn[j]), o[j]);
    }
    short8 ov;
#pragma unroll
    for (int j = 0; j < 8; j++) ov[j] = f2bf(o[j] * rden);
    *(short8*)&m[base] = ov;
}

// ---------------- masked softmax pooling + both heads (bf16 h) ----------------
__global__ __launch_bounds__(1024) void pool_head_kernel(
    const short* __restrict__ hb, const int* __restrict__ mask,
    const float* __restrict__ pw, const float* __restrict__ pb,
    const float* __restrict__ h0W, const float* __restrict__ h0b,
    const float* __restrict__ h1W, const float* __restrict__ h1b,
    float* __restrict__ out) {
    int b = blockIdx.x;
    int t = threadIdx.x;
    int lane = t & 63, wave = t >> 6;
    __shared__ float sc[L_];
    __shared__ float red[20];
    __shared__ float part[4][C_];
    __shared__ float pooled[C_];

    float4 wv = *(const float4*)&pw[lane * 4];
    for (int l = wave; l < L_; l += 16) {
        short4v hv = *(const short4v*)&hb[((size_t)b * L_ + l) * C_ + lane * 4];
        float p = bf2f(hv.x) * wv.x + bf2f(hv.y) * wv.y
                + bf2f(hv.z) * wv.z + bf2f(hv.w) * wv.w;
#pragma unroll
        for (int off = 32; off; off >>= 1) p += __shfl_down(p, off);
        if (lane == 0) sc[l] = mask[b * L_ + l] ? (p + pb[0]) : NEGV;
    }
    __syncthreads();

    float v = (t < L_) ? sc[t] : NEGV;
    float mx = v;
#pragma unroll
    for (int off = 32; off; off >>= 1) mx = fmaxf(mx, __shfl_down(mx, off));
    if (lane == 0) red[wave] = mx;
    __syncthreads();
    if (t == 0) {
        float g = red[0];
        for (int i = 1; i < 16; i++) g = fmaxf(g, red[i]);
        red[16] = g;
    }
    __syncthreads();
    float gmax = red[16];
    float e = (t < L_) ? __expf(v - gmax) : 0.f;
    float ssum = e;
#pragma unroll
    for (int off = 32; off; off >>= 1) ssum += __shfl_down(ssum, off);
    if (lane == 0) red[wave] = ssum;
    __syncthreads();
    if (t == 0) {
        float g = 0.f;
        for (int i = 0; i < 16; i++) g += red[i];
        red[17] = 1.f / g;
    }
    __syncthreads();
    if (t < L_) sc[t] = e * red[17];
    __syncthreads();

    int g = t >> 8, c = t & 255;
    const short* hrow = &hb[((size_t)b * L_ + g * 128) * C_ + c];
    const float* scg = &sc[g * 128];
    float a0 = 0.f, a1 = 0.f, a2 = 0.f, a3 = 0.f;
    for (int l = 0; l < 128; l += 4) {
        a0 = fmaf(scg[l + 0], bf2f(hrow[(size_t)(l + 0) * C_]), a0);
        a1 = fmaf(scg[l + 1], bf2f(hrow[(size_t)(l + 1) * C_]), a1);
        a2 = fmaf(scg[l + 2], bf2f(hrow[(size_t)(l + 2) * C_]), a2);
        a3 = fmaf(scg[l + 3], bf2f(hrow[(size_t)(l + 3) * C_]), a3);
    }
    part[g][c] = (a0 + a1) + (a2 + a3);
    __syncthreads();
    if (t < C_) pooled[t] = (part[0][t] + part[1][t]) + (part[2][t] + part[3][t]);
    __syncthreads();

    for (int o = wave; o < 70; o += 16) {
        const float* W = (o < 50) ? (h0W + (size_t)o * C_) : (h1W + (size_t)(o - 50) * C_);
        float bb = (o < 50) ? h0b[o] : h1b[o - 50];
        float4 w4 = *(const float4*)&W[lane * 4];
        float4 p4 = *(const float4*)&pooled[lane * 4];
        float s = p4.x * w4.x + p4.y * w4.y + p4.z * w4.z + p4.w * w4.w;
#pragma unroll
        for (int off = 32; off; off >>= 1) s += __shfl_down(s, off);
        if (lane == 0) out[b * 70 + o] = s + bb;
    }
}

extern "C" void kernel_launch(void* const* d_in, const int* in_sizes, int n_in,
                              void* d_out, int out_size, void* d_ws, size_t ws_size,
                              hipStream_t stream) {
    const int*   x    = (const int*)d_in[0];
    const float* emb  = (const float*)d_in[1];
    const float* pos  = (const float*)d_in[2];
    const float* gpW  = (const float*)d_in[3];
    const float* gpas = (const float*)d_in[4];
    const float* gpad = (const float*)d_in[5];
    const float* gfW  = (const float*)d_in[6];
    const float* gfas = (const float*)d_in[7];
    const float* gfad = (const float*)d_in[8];
    const float* msgW = (const float*)d_in[9];
    const float* msgb = (const float*)d_in[10];
    const float* Wih  = (const float*)d_in[11];
    const float* bih  = (const float*)d_in[12];
    const float* Whh  = (const float*)d_in[13];
    const float* bhh  = (const float*)d_in[14];
    const float* lng  = (const float*)d_in[15];
    const float* lnb  = (const float*)d_in[16];
    const float* pw   = (const float*)d_in[17];
    const float* pb   = (const float*)d_in[18];
    const float* h0W  = (const float*)d_in[19];
    const float* h0b  = (const float*)d_in[20];
    const float* h1W  = (const float*)d_in[21];
    const float* h1b  = (const float*)d_in[22];
    float* out = (float*)d_out;

    // Workspace layout, units MW = 1Mi floats = 4 MiB:
    //   hn2b bf16 [32768, 256] =  4 MW   -> [ 0,  4)
    //   hb   bf16 [32768, 256] =  4 MW   -> [ 8, 12)
    //   mmb  bf16 [32768, 256] =  4 MW   -> [12, 16)   (also Ssd fp32 [32768,16])
    //   hpb2 bf16 [32768, 512] =  8 MW   -> [16, 24)
    //   mb   bf16 [32768, 512] =  8 MW   -> [24, 32)
    //   weights/bias/masks               -> [32, ~33.3)
    const size_t MW = 1024 * 1024;
    float* ws = (float*)d_ws;
    short* hn2b = (short*)ws;
    short* hb   = (short*)(ws + 8 * MW);
    short* mmb  = (short*)(ws + 12 * MW);
    float* Ssd  = ws + 12 * MW;                          // aliases mmb (timeshared)
    short* hpb2 = (short*)(ws + 16 * MW);
    short* mb   = (short*)(ws + 24 * MW);
    short* Wcomb = (short*)(ws + 32 * MW);               // 3*640*256 shorts
    short* msgWb = Wcomb + 3 * 640 * 256;                // 3*256*512 shorts
    short* Bcat  = msgWb + 3 * 256 * 512;                // 3*1024*512 shorts (interleaved)
    float* bias4 = (float*)(Bcat + 3 * 1024 * 512);      // 3*1024 floats
    int* mask    = (int*)(bias4 + 3 * 1024);
    int* logical = mask + B_ * L_;
    int* pol     = logical + B_ * L_;
    int* nvalid  = pol + B_ * L_;

    // weight prep
    prep_wcomb<<<(3 * 640 * 256 + 255) / 256, 256, 0, stream>>>(gpW, gfW, gpas, gpad,
                                                                gfas, gfad, Wcomb);
    f2bf_kernel<<<(3 * 256 * 512 + 255) / 256, 256, 0, stream>>>(msgW, msgWb, 3 * 256 * 512);
    prep_gru_i<<<(3 * 1024 * 512 + 255) / 256, 256, 0, stream>>>(Wih, Whh, Bcat);
    prep_bias4<<<12, 256, 0, stream>>>(bih, bhh, bias4);

    scan_kernel<<<B_, L_, 0, stream>>>(x, mask, logical, pol, nvalid);
    embed_kernel<<<B_ * L_ / 4, 256, 0, stream>>>(x, emb, pos, hb);

    const int DILS[LAY] = {1, 2, 4};

    for (int l = 0; l < LAY; l++) {
        int dil = DILS[l];
        // hpb2 (N=512 bf16) + Ssd (16 fp32 cols) in one dispatch
        projssd_bgemm<<<256 * 5, 256, 0, stream>>>(hb, Wcomb + (size_t)l * 640 * 256,
                                                   hpb2, Ssd);
        // sparse GAT aggregation, both dirs in one wave, short8-vectorized
        agg_fused<<<8192, 256, 0, stream>>>(hpb2, Ssd, mask, logical, pol, nvalid, mb, dil);
        // mm = relu(m @ msgW^T + msgb) -> bf16  (CB=2, overwrites Ssd region)
        bgemm<<<256 * 2, 256, 0, stream>>>(mb, msgWb + (size_t)l * 256 * 512,
                                           mmb, msgb + l * C_, 512, 512, 256, 256, 1,
                                           GF_BIAS | GF_RELU | GF_OBF16);
        // 256x256-tile 8-phase deep-vmcnt GRU GEMM + gate epilogue -> hn2b
        gru_bgemm<<<512, 512, 0, stream>>>(mmb, hb, Bcat + (size_t)l * 1024 * 512,
                                           hn2b, bias4 + l * 1024);
        // LayerNorm + mask -> hb
        ln_kernel<<<8192, 256, 0, stream>>>(hn2b, hb, mask, lng + l * C_, lnb + l * C_);
    }

    pool_head_kernel<<<B_, 1024, 0, stream>>>(hb, mask, pw, pb, h0W, h0b, h1W, h1b, out);
}

// Round 4
// 500.511 us; speedup vs baseline: 1.1299x; 1.0257x over previous
//
#include <hip/hip_runtime.h>
#include <math.h>

#define B_ 64
#define L_ 512
#define C_ 256
#define H_ 4
#define LAY 3
#define NEGV -1e9f

typedef __attribute__((ext_vector_type(8))) short short8;
typedef __attribute__((ext_vector_type(4))) short short4v;
typedef __attribute__((ext_vector_type(4))) float floatx4;

static __device__ __forceinline__ float rcp_(float x) { return __builtin_amdgcn_rcpf(x); }
static __device__ __forceinline__ float sig_(float x) { return rcp_(1.f + __expf(-x)); }
static __device__ __forceinline__ float tanh_(float x) {
    float e = __expf(2.f * x);
    return 1.f - 2.f * rcp_(e + 1.f);
}

static __device__ __forceinline__ short f2bf(float f) {
    unsigned x = __float_as_uint(f);
    x += 0x7fffu + ((x >> 16) & 1u);       // round-to-nearest-even to bf16
    return (short)(x >> 16);
}
static __device__ __forceinline__ float bf2f(short s) {
    return __uint_as_float(((unsigned)(unsigned short)s) << 16);
}

// XCD-aligned token swizzle for elementwise consumers (matches GEMM rb%8 = XCD).
static __device__ __forceinline__ int tok_swizzle(int blk) {
    int c8 = blk & 7, i = blk >> 3;
    return (c8 + 8 * (i >> 5)) * 128 + (i & 31) * 4;
}

static __device__ __forceinline__ void gl_lds16(const short* g, short* l) {
    __builtin_amdgcn_global_load_lds(
        (const __attribute__((address_space(1))) unsigned int*)g,
        (__attribute__((address_space(3))) unsigned int*)l, 16, 0, 0);
}

#define CF() asm volatile("" ::: "memory")

// ---------------- mask / logical-position scan + pos_of_logical ----------------
__global__ void scan_kernel(const int* __restrict__ x, int* __restrict__ mask,
                            int* __restrict__ logical, int* __restrict__ pol,
                            int* __restrict__ nvalid) {
    int b = blockIdx.x, t = threadIdx.x;
    __shared__ int s[L_];
    int m = (x[b * L_ + t] != 0) ? 1 : 0;
    s[t] = m;
    __syncthreads();
    for (int off = 1; off < L_; off <<= 1) {
        int v = (t >= off) ? s[t - off] : 0;
        __syncthreads();
        s[t] += v;
        __syncthreads();
    }
    int cum = s[t];
    int lg = cum - 1; if (lg < 0) lg = 0;
    mask[b * L_ + t] = m;
    logical[b * L_ + t] = lg;
    if (m) pol[b * L_ + lg] = t;
    if (t == L_ - 1) nvalid[b] = cum;
}

// ---------------- hb = bf16((emb[x] + pos*mf)*mf) ----------------
__global__ void embed_kernel(const int* __restrict__ x, const float* __restrict__ emb,
                             const float* __restrict__ pos, short* __restrict__ hb) {
    int t = threadIdx.x;
    int bl = tok_swizzle(blockIdx.x) + (t >> 6);
    int lane = t & 63;
    int xv = x[bl];
    float mf = (xv != 0) ? 1.f : 0.f;
    int l = bl & (L_ - 1);
    float4 e = *(const float4*)&emb[(size_t)xv * C_ + lane * 4];
    float4 p = *(const float4*)&pos[(size_t)l * C_ + lane * 4];
    short4v hv4;
    hv4.x = f2bf((e.x + p.x * mf) * mf);
    hv4.y = f2bf((e.y + p.y * mf) * mf);
    hv4.z = f2bf((e.z + p.z * mf) * mf);
    hv4.w = f2bf((e.w + p.w * mf) * mf);
    *(short4v*)&hb[(size_t)bl * C_ + lane * 4] = hv4;
}

// ---------------- weight prep ----------------
__global__ void f2bf_kernel(const float* __restrict__ s, short* __restrict__ d, int n) {
    int i = blockIdx.x * 256 + threadIdx.x;
    if (i < n) d[i] = f2bf(s[i]);
}

// Wcomb[l][640][256]: rows 0..255 = gpW[l], 256..511 = gfW[l],
// rows 512..527 = AsdW (n = type*8+dir*4+head -> a_vec @ W_dir), rest 0.
__global__ void prep_wcomb(const float* __restrict__ gpW, const float* __restrict__ gfW,
                           const float* __restrict__ gpas, const float* __restrict__ gpad,
                           const float* __restrict__ gfas, const float* __restrict__ gfad,
                           short* __restrict__ Wc) {
    int i = blockIdx.x * 256 + threadIdx.x;
    if (i >= 3 * 640 * 256) return;
    int k = i & 255;
    int r = (i >> 8) % 640;
    int l = i / (640 * 256);
    float v = 0.f;
    if (r < 256) {
        v = gpW[((size_t)l * 256 + r) * 256 + k];
    } else if (r < 512) {
        v = gfW[((size_t)l * 256 + (r - 256)) * 256 + k];
    } else {
        int n = r - 512;
        if (n < 16) {
            int type = n >> 3, dir = (n >> 2) & 1, hh = n & 3;
            const float* a = type ? (dir ? gfad : gpad) : (dir ? gfas : gpas);
            const float* W = dir ? gfW : gpW;
            for (int j = 0; j < 64; j++) {
                float av = a[l * 256 + hh * 64 + j];
                float wv = W[((size_t)l * 256 + hh * 64 + j) * 256 + k];
                v = fmaf(av, wv, v);
            }
        }
    }
    Wc[i] = f2bf(v);
}

// Interleaved GRU weights: Bc[l][n'][512], n' = 4*ch + g, g in {0:r,1:z,2:i,3:n}.
__global__ void prep_gru_i(const float* __restrict__ Wih, const float* __restrict__ Whh,
                           short* __restrict__ Bc) {
    int i = blockIdx.x * 256 + threadIdx.x;
    if (i >= 3 * 1024 * 512) return;
    int k = i & 511, np = (i >> 9) & 1023, l = i >> 19;
    int ch = np >> 2, g = np & 3;
    float v = 0.f;
    if (g < 2) {
        v = (k < 256) ? Wih[((size_t)l * 768 + g * 256 + ch) * 256 + k]
                      : Whh[((size_t)l * 768 + g * 256 + ch) * 256 + (k - 256)];
    } else if (g == 2) {
        if (k < 256) v = Wih[((size_t)l * 768 + 512 + ch) * 256 + k];
    } else {
        if (k >= 256) v = Whh[((size_t)l * 768 + 512 + ch) * 256 + (k - 256)];
    }
    Bc[i] = f2bf(v);
}

// bias4[l][4*ch+g]
__global__ void prep_bias4(const float* __restrict__ bih, const float* __restrict__ bhh,
                           float* __restrict__ bc) {
    int i = blockIdx.x * 256 + threadIdx.x;
    if (i >= 3 * 1024) return;
    int np = i & 1023, l = i >> 10;
    int ch = np >> 2, g = np & 3;
    float v;
    if (g < 2)       v = bih[l * 768 + g * 256 + ch] + bhh[l * 768 + g * 256 + ch];
    else if (g == 2) v = bih[l * 768 + 512 + ch];
    else             v = bhh[l * 768 + 512 + ch];
    bc[i] = v;
}

// ---------------- projection + Ssd combined GEMM ----------------
// A = hb [32768,256] (K=256), B = Wcomb [640,256]; cb 0..3 -> hpb2 bf16 (ldc 512),
// cb 4 -> Ssd fp32 (ldc 16, 16 real cols). Grid 1280.
// XCD-coherent: id&7 = XCD, 32 contiguous rb x all 5 cb per XCD (A 2MB + B 320KB in L2).
__global__ __launch_bounds__(256) void projssd_bgemm(const short* __restrict__ A0,
                                                     const short* __restrict__ Bw,
                                                     short* __restrict__ hpb2,
                                                     float* __restrict__ Ssd) {
    __shared__ short As[128 * 32];
    __shared__ short Bs[128 * 32];
    const int id = blockIdx.x;
    const int j = id >> 3;                 // 0..159
    const int cb = j >> 5;                 // 0..4
    const int rb = ((id & 7) << 5) + (j & 31);   // 0..255
    const int tid = threadIdx.x;
    const int wave = tid >> 6, lane = tid & 63;
    const int wm = wave >> 1, wn = wave & 1;
    const size_t arow0 = (size_t)rb * 128;
    const short* Bb = Bw + (size_t)cb * 128 * 256;
    floatx4 acc[4][4];
#pragma unroll
    for (int i = 0; i < 4; i++)
#pragma unroll
        for (int jj = 0; jj < 4; jj++) acc[i][jj] = (floatx4)0.f;

    const int srow = lane >> 2;
    const int sq = (lane & 3) * 8;
    const int q = lane >> 4, t16 = lane & 15;

    for (int k0 = 0; k0 < 256; k0 += 32) {
        const short* Abase = A0 + arow0 * 256 + k0;
#pragma unroll
        for (int t = 0; t < 2; ++t) {
            int r = (wave * 2 + t) * 16 + srow;
            gl_lds16(Abase + (size_t)r * 256 + sq, &As[r * 32 + sq]);
            gl_lds16(Bb + (size_t)r * 256 + k0 + sq, &Bs[r * 32 + sq]);
        }
        __syncthreads();
        short8 af[4], bfr[4];
#pragma unroll
        for (int mf = 0; mf < 4; mf++)
            af[mf] = *(const short8*)&As[(wm * 64 + mf * 16 + t16) * 32 + q * 8];
#pragma unroll
        for (int nf = 0; nf < 4; nf++)
            bfr[nf] = *(const short8*)&Bs[(wn * 64 + nf * 16 + t16) * 32 + q * 8];
#pragma unroll
        for (int mf = 0; mf < 4; mf++)
#pragma unroll
            for (int nf = 0; nf < 4; nf++)
                acc[nf][mf] = __builtin_amdgcn_mfma_f32_16x16x32_bf16(
                    bfr[nf], af[mf], acc[nf][mf], 0, 0, 0);
        __syncthreads();
    }

    const int rowbase = rb * 128 + wm * 64;
    if (cb < 4) {
        const int colbase = cb * 128 + wn * 64;
#pragma unroll
        for (int nf = 0; nf < 4; nf++) {
            int col0 = colbase + nf * 16 + q * 4;
#pragma unroll
            for (int mf = 0; mf < 4; mf++) {
                int row = rowbase + mf * 16 + t16;
                short4v pk;
                pk.x = f2bf(acc[nf][mf][0]);
                pk.y = f2bf(acc[nf][mf][1]);
                pk.z = f2bf(acc[nf][mf][2]);
                pk.w = f2bf(acc[nf][mf][3]);
                *(short4v*)&hpb2[(size_t)row * 512 + col0] = pk;
            }
        }
    } else {
        // Ssd: cols 512..639 map to 0..127; only first 16 real (wn=0, nf=0)
        if (wn == 0) {
            int col0 = q * 4;   // nf = 0
            if (col0 < 16) {
#pragma unroll
                for (int mf = 0; mf < 4; mf++) {
                    int row = rowbase + mf * 16 + t16;
                    float4 pk = make_float4(acc[0][mf][0], acc[0][mf][1],
                                            acc[0][mf][2], acc[0][mf][3]);
                    *(float4*)&Ssd[(size_t)row * 16 + col0] = pk;
                }
            }
        }
    }
}

// ---------------- deep-GEMM fragment helpers (shared by gru/msg) ----------
static __device__ __forceinline__ short8 lds_rd8(const short* p) {
    return *(const short8*)p;
}

template <int MH>
static __device__ __forceinline__ void ld_af(const short* bufA, int wm, int q, int t16,
                                             short8 af[4][2]) {
#pragma unroll
    for (int mfl = 0; mfl < 4; ++mfl) {
        int row = wm * 128 + (MH * 4 + mfl) * 16 + t16;
#pragma unroll
        for (int ks = 0; ks < 2; ++ks) {
            int cg = (ks * 4 + q) ^ (row & 7);
            af[mfl][ks] = lds_rd8(&bufA[row * 64 + cg * 8]);
        }
    }
}

template <int NH>
static __device__ __forceinline__ void ld_bf(const short* bufB, int wn, int q, int t16,
                                             short8 bf[2][2]) {
#pragma unroll
    for (int nfl = 0; nfl < 2; ++nfl) {
        int row = wn * 64 + (NH * 2 + nfl) * 16 + t16;
#pragma unroll
        for (int ks = 0; ks < 2; ++ks) {
            int cg = (ks * 4 + q) ^ (row & 7);
            bf[nfl][ks] = lds_rd8(&bufB[row * 64 + cg * 8]);
        }
    }
}

// B fragment read for BN=128 (wave covers 32 cols): rows wn*32 + nfl*16 + t16
static __device__ __forceinline__ void ld_bf32(const short* bufB, int wn, int q, int t16,
                                               short8 bf[2][2]) {
#pragma unroll
    for (int nfl = 0; nfl < 2; ++nfl) {
        int row = wn * 32 + nfl * 16 + t16;
#pragma unroll
        for (int ks = 0; ks < 2; ++ks) {
            int cg = (ks * 4 + q) ^ (row & 7);
            bf[nfl][ks] = lds_rd8(&bufB[row * 64 + cg * 8]);
        }
    }
}

template <int MH, int NH>
static __device__ __forceinline__ void mfma_q(const short8 af[4][2], const short8 bf[2][2],
                                              floatx4 acc[4][8]) {
    __builtin_amdgcn_s_setprio(1);
#pragma unroll
    for (int ks = 0; ks < 2; ++ks)
#pragma unroll
        for (int mfl = 0; mfl < 4; ++mfl)
#pragma unroll
            for (int nfl = 0; nfl < 2; ++nfl)
                acc[NH * 2 + nfl][MH * 4 + mfl] = __builtin_amdgcn_mfma_f32_16x16x32_bf16(
                    bf[nfl][ks], af[mfl][ks], acc[NH * 2 + nfl][MH * 4 + mfl], 0, 0, 0);
    __builtin_amdgcn_s_setprio(0);
}

template <int MH>
static __device__ __forceinline__ void mfma_m(const short8 af[4][2], const short8 bf[2][2],
                                              floatx4 acc[2][8]) {
    __builtin_amdgcn_s_setprio(1);
#pragma unroll
    for (int ks = 0; ks < 2; ++ks)
#pragma unroll
        for (int mfl = 0; mfl < 4; ++mfl)
#pragma unroll
            for (int nfl = 0; nfl < 2; ++nfl)
                acc[nfl][MH * 4 + mfl] = __builtin_amdgcn_mfma_f32_16x16x32_bf16(
                    bf[nfl][ks], af[mfl][ks], acc[nfl][MH * 4 + mfl], 0, 0, 0);
    __builtin_amdgcn_s_setprio(0);
}

// ---------------- dedicated GRU GEMM, 256x256 tile, 8-phase deep-vmcnt ----------
// A = [mmb | hb] K=512, B = Bcat interleaved (N=1024, n'=4ch+g).
// 8 waves (2M x 4N), BK=64, dbuf 128 KiB LDS, XOR-swizzle (src-perm + read-perm).
// Rolled K-loop (unroll 2: buffer parity static, ~1/4 code size vs full unroll).
// Deep staging: su(t+2).B issued at t.P2 (bufB free after P1), su(t+2).A at t.P3
// (bufA free after P2); one s_waitcnt vmcnt(8) per tile boundary (su(t+2)'s 8
// loads stay in flight across all barriers).
// K-tile order rotated so the hb-slice covering this block's cb channels is
// staged LAST -> epilogue reads h_prev from LDS. XCD: rb=16*(id&7)+(id>>5).
__global__ __launch_bounds__(512, 2) void gru_bgemm(const short* __restrict__ mmb,
                                                    const short* __restrict__ hb_in,
                                                    const short* __restrict__ Bw,
                                                    short* __restrict__ hn2b,
                                                    const float* __restrict__ bias4) {
    __shared__ short lds[2][32768];   // per buf: A[256][64] @0, B[256][64] @16384
    const int id = blockIdx.x;
    const int rb = 16 * (id & 7) + (id >> 5);
    const int cb = (id >> 3) & 3;
    const int tid = threadIdx.x;
    const int wave = tid >> 6, lane = tid & 63;
    const int wm = wave >> 2, wn = wave & 3;
    const int q = lane >> 4, t16 = lane & 15;
    const size_t arow0 = (size_t)rb * 256;
    const short* Bb = Bw + (size_t)cb * 256 * 512;
    // rotation: position i handles K-tile tt = (5+cb+i)&7; position 7 = tile 4+cb
    // = hb cols [cb*64, cb*64+64) -> ends in lds[1] for the epilogue h_prev read.
    const int ord0 = (5 + cb) & 7;

    floatx4 acc[4][8];   // [nf][mf]
#pragma unroll
    for (int i = 0; i < 4; i++)
#pragma unroll
        for (int jj = 0; jj < 8; jj++) acc[i][jj] = (floatx4)0.f;

    auto stageA = [&](int i, int Hh) {
        int tt = (ord0 + i) & 7;
        const short* Asrc = (tt < 4) ? (mmb + tt * 64) : (hb_in + (tt - 4) * 64);
        short* bufA = lds[i & 1];
#pragma unroll
        for (int u = 0; u < 2; ++u) {
            int unit = u * 512 + tid;              // 0..1023
            int row = Hh * 128 + (unit >> 3);
            int cs = (unit & 7) ^ (row & 7);
            gl_lds16(Asrc + (arow0 + (size_t)row) * 256 + cs * 8,
                     bufA + Hh * 8192 + unit * 8);
        }
    };
    auto stageB = [&](int i, int Hh) {
        int tt = (ord0 + i) & 7;
        short* bufB = lds[i & 1] + 16384;
#pragma unroll
        for (int u = 0; u < 2; ++u) {
            int unit = u * 512 + tid;
            int row = Hh * 128 + (unit >> 3);
            int cs = (unit & 7) ^ (row & 7);
            gl_lds16(Bb + (size_t)row * 512 + tt * 64 + cs * 8,
                     bufB + Hh * 8192 + unit * 8);
        }
    };

    // prologue: tiles 0 and 1 fully issued (16 loads/wave);
    // vmcnt(8): tile 0 complete, tile 1's 8 loads stay in flight
    stageA(0, 0); stageA(0, 1); stageB(0, 0); stageB(0, 1);
    stageA(1, 0); stageA(1, 1); stageB(1, 0); stageB(1, 1);
    asm volatile("s_waitcnt vmcnt(8)" ::: "memory");
    CF(); __builtin_amdgcn_s_barrier(); CF();

    short8 af[4][2], b0[2][2], b1[2][2];

#pragma unroll 2
    for (int t = 0; t < 8; ++t) {
        const short* bufA = lds[t & 1];
        const short* bufB = lds[t & 1] + 16384;

        // ---- P0: quadrant (0,0) ----
        ld_af<0>(bufA, wm, q, t16, af);
        ld_bf<0>(bufB, wn, q, t16, b0);
        CF(); __builtin_amdgcn_s_barrier();
        asm volatile("s_waitcnt lgkmcnt(0)" ::: "memory");
        mfma_q<0, 0>(af, b0, acc);
        CF(); __builtin_amdgcn_s_barrier(); CF();

        // ---- P1: quadrant (0,1) ----
        ld_bf<1>(bufB, wn, q, t16, b1);
        CF(); __builtin_amdgcn_s_barrier();
        asm volatile("s_waitcnt lgkmcnt(0)" ::: "memory");
        mfma_q<0, 1>(af, b1, acc);
        CF(); __builtin_amdgcn_s_barrier(); CF();

        // ---- P2: quadrant (1,1) ----  (bufB[t&1] free after P1's end barrier)
        ld_af<1>(bufA, wm, q, t16, af);
        if (t < 6) { stageB(t + 2, 0); stageB(t + 2, 1); }
        CF(); __builtin_amdgcn_s_barrier();
        asm volatile("s_waitcnt lgkmcnt(0)" ::: "memory");
        mfma_q<1, 1>(af, b1, acc);
        CF(); __builtin_amdgcn_s_barrier(); CF();

        // ---- P3: quadrant (1,0) ----  (bufA[t&1] free after P2's end barrier)
        if (t < 6) { stageA(t + 2, 0); stageA(t + 2, 1); }
        CF(); __builtin_amdgcn_s_barrier();
        mfma_q<1, 0>(af, b0, acc);
        // tile boundary: su(t+1) (oldest 8) complete; su(t+2) (8) stay in flight
        if (t < 6)       asm volatile("s_waitcnt vmcnt(8)" ::: "memory");
        else if (t == 6) asm volatile("s_waitcnt vmcnt(0)" ::: "memory");
        CF(); __builtin_amdgcn_s_barrier(); CF();
    }

    // epilogue: h_prev from LDS (lds[1] holds A-tile of tt=4+cb = hb cols cb*64..),
    // compute gates, stage hn2 tile in LDS, coalesced bf16 write.
    const short* hpt = lds[1];
    short* sO = (short*)lds;                   // [256][72] bf16 within lds[0]
#pragma unroll
    for (int nf = 0; nf < 4; nf++) {
        int chl = wn * 16 + nf * 4 + q;        // 0..63 within block
        int col0 = cb * 256 + wn * 64 + nf * 16 + q * 4;
        float4 bv4 = *(const float4*)&bias4[col0];
#pragma unroll
        for (int mf = 0; mf < 8; mf++) {
            int rowl = wm * 128 + mf * 16 + t16;
            float hp = bf2f(hpt[rowl * 64 + (((chl >> 3) ^ (rowl & 7)) << 3) + (chl & 7)]);
            float r = sig_(acc[nf][mf][0] + bv4.x);
            float z = sig_(acc[nf][mf][1] + bv4.y);
            float nv = tanh_((acc[nf][mf][2] + bv4.z) + r * (acc[nf][mf][3] + bv4.w));
            sO[rowl * 72 + chl] = f2bf((1.f - z) * nv + z * hp);
        }
    }
    __syncthreads();
#pragma unroll
    for (int it = 0; it < 4; ++it) {
        int unit = it * 512 + tid;
        int rowl = unit >> 3, ck = unit & 7;
        *(short8*)&hn2b[(arow0 + rowl) * 256 + cb * 64 + ck * 8] =
            *(const short8*)&sO[rowl * 72 + ck * 8];
    }
}

// ---------------- msg GEMM, 256x128 tile, deep pipeline ----------
// C = relu(mb[32768,512] @ msgWb[256,512]^T + bias) -> bf16 mmb [32768,256].
// Grid 256 = 128 rb x 2 cb, exactly 1 block/CU (one round). 8 waves 2Mx4N:
// wave output 128 rows x 32 cols, acc[2][8]. BK=64, 8 K-tiles, dbuf 96 KiB LDS.
// Schedule per tile (2 phases):
//  P0: ld_af<0>(8)+ld_bf32(4); stageA(t+1) [buf (t+1)&1 free since (t-1)-end];
//      bar; lgkm0; MFMA MH0; bar.
//  P1: ld_af<1>(8); stageB(t+2) [bufB[t&1] free after P0-end]; bar; lgkm0;
//      MFMA MH1; vmcnt(2) [B(t+1),A(t+1) complete; B(t+2) in flight]; bar.
// XCD: id&7 = XCD -> 16 contiguous rb x both cb per XCD.
__global__ __launch_bounds__(512, 2) void msg_bgemm(const short* __restrict__ A0,
                                                    const short* __restrict__ Bw,
                                                    short* __restrict__ Cout,
                                                    const float* __restrict__ bias) {
    __shared__ short lds[2][24576];   // per buf: A[256][64] @0, B[128][64] @16384
    const int id = blockIdx.x;
    const int j = id >> 3;                       // 0..31
    const int rb = (id & 7) * 16 + (j & 15);     // 0..127
    const int cb = j >> 4;                       // 0..1
    const int tid = threadIdx.x;
    const int wave = tid >> 6, lane = tid & 63;
    const int wm = wave >> 2, wn = wave & 3;
    const int q = lane >> 4, t16 = lane & 15;
    const size_t arow0 = (size_t)rb * 256;
    const short* Bb = Bw + (size_t)cb * 128 * 512;

    floatx4 acc[2][8];
#pragma unroll
    for (int i = 0; i < 2; i++)
#pragma unroll
        for (int jj = 0; jj < 8; jj++) acc[i][jj] = (floatx4)0.f;

    auto stageA = [&](int t, int Hh) {
        short* bufA = lds[t & 1];
#pragma unroll
        for (int u = 0; u < 2; ++u) {
            int unit = u * 512 + tid;
            int row = Hh * 128 + (unit >> 3);
            int cs = (unit & 7) ^ (row & 7);
            gl_lds16(A0 + (arow0 + (size_t)row) * 512 + t * 64 + cs * 8,
                     bufA + Hh * 8192 + unit * 8);
        }
    };
    auto stageB = [&](int t) {
        short* bufB = lds[t & 1] + 16384;
#pragma unroll
        for (int u = 0; u < 2; ++u) {
            int unit = u * 512 + tid;
            int row = unit >> 3;                 // 0..127
            int cs = (unit & 7) ^ (row & 7);
            gl_lds16(Bb + (size_t)row * 512 + t * 64 + cs * 8, bufB + unit * 8);
        }
    };

    // prologue: A(0)+B(0)+B(1); vmcnt(2): tile0 complete, B(1) in flight
    stageA(0, 0); stageA(0, 1); stageB(0); stageB(1);
    asm volatile("s_waitcnt vmcnt(2)" ::: "memory");
    CF(); __builtin_amdgcn_s_barrier(); CF();

    short8 af[4][2], bfr[2][2];

#pragma unroll 2
    for (int t = 0; t < 8; ++t) {
        const short* bufA = lds[t & 1];
        const short* bufB = lds[t & 1] + 16384;

        // ---- P0 ----
        ld_af<0>(bufA, wm, q, t16, af);
        ld_bf32(bufB, wn, q, t16, bfr);
        if (t < 7) { stageA(t + 1, 0); stageA(t + 1, 1); }
        CF(); __builtin_amdgcn_s_barrier();
        asm volatile("s_waitcnt lgkmcnt(0)" ::: "memory");
        mfma_m<0>(af, bfr, acc);
        CF(); __builtin_amdgcn_s_barrier(); CF();

        // ---- P1 ----  (bufB[t&1] free after P0's end barrier)
        ld_af<1>(bufA, wm, q, t16, af);
        if (t < 6) stageB(t + 2);
        CF(); __builtin_amdgcn_s_barrier();
        asm volatile("s_waitcnt lgkmcnt(0)" ::: "memory");
        mfma_m<1>(af, bfr, acc);
        if (t < 6)       asm volatile("s_waitcnt vmcnt(2)" ::: "memory");
        else if (t == 6) asm volatile("s_waitcnt vmcnt(0)" ::: "memory");
        CF(); __builtin_amdgcn_s_barrier(); CF();
    }

    // epilogue: bias + relu + bf16, LDS-staged coalesced write
    short* sO = (short*)lds;                     // [256][132]
#pragma unroll
    for (int nf = 0; nf < 2; nf++) {
        int chl = wn * 32 + nf * 16 + q * 4;     // 0..127 within block
        int col0 = cb * 128 + chl;
        float4 bv4 = *(const float4*)&bias[col0];
#pragma unroll
        for (int mf = 0; mf < 8; mf++) {
            int rowl = wm * 128 + mf * 16 + t16;
            short4v pk;
            pk.x = f2bf(fmaxf(acc[nf][mf][0] + bv4.x, 0.f));
            pk.y = f2bf(fmaxf(acc[nf][mf][1] + bv4.y, 0.f));
            pk.z = f2bf(fmaxf(acc[nf][mf][2] + bv4.z, 0.f));
            pk.w = f2bf(fmaxf(acc[nf][mf][3] + bv4.w, 0.f));
            *(short4v*)&sO[rowl * 132 + chl] = pk;
        }
    }
    __syncthreads();
    // coalesced write: 256 rows x 128 ch, short8 chunks (4096 units / 512 thr)
#pragma unroll
    for (int it = 0; it < 8; ++it) {
        int unit = it * 512 + tid;
        int rowl = unit >> 4, ck = unit & 15;
        *(short8*)&Cout[(arow0 + rowl) * 256 + cb * 128 + ck * 8] =
            *(const short8*)&sO[rowl * 132 + ck * 8];
    }
}

// ---------------- LayerNorm over hn2 (bf16) + mask -> hb ----------------
__global__ __launch_bounds__(256) void ln_kernel(
    const short* __restrict__ hn2b, short* __restrict__ hb,
    const int* __restrict__ mask,
    const float* __restrict__ lng, const float* __restrict__ lnb) {
    int t = threadIdx.x;
    int bl = tok_swizzle(blockIdx.x) + (t >> 6);
    int lane = t & 63;
    short4v v4 = *(const short4v*)&hn2b[(size_t)bl * C_ + lane * 4];
    float v[4] = {bf2f(v4.x), bf2f(v4.y), bf2f(v4.z), bf2f(v4.w)};
    float s = (v[0] + v[1]) + (v[2] + v[3]);
    float ss = (v[0] * v[0] + v[1] * v[1]) + (v[2] * v[2] + v[3] * v[3]);
#pragma unroll
    for (int off = 32; off; off >>= 1) {
        s += __shfl_xor(s, off);
        ss += __shfl_xor(ss, off);
    }
    float mu = s * (1.f / 256.f);
    float var = ss * (1.f / 256.f) - mu * mu;
    float rstd = rsqrtf(fmaxf(var, 0.f) + 1e-5f);
    float4 lg = *(const float4*)&lng[lane * 4];
    float4 lb = *(const float4*)&lnb[lane * 4];
    float mfv = mask[bl] ? 1.f : 0.f;
    short4v yb;
    yb.x = f2bf(((v[0] - mu) * rstd * lg.x + lb.x) * mfv);
    yb.y = f2bf(((v[1] - mu) * rstd * lg.y + lb.y) * mfv);
    yb.z = f2bf(((v[2] - mu) * rstd * lg.z + lb.z) * mfv);
    yb.w = f2bf(((v[3] - mu) * rstd * lg.w + lb.w) * mfv);
    *(short4v*)&hb[(size_t)bl * C_ + lane * 4] = yb;
}

// ---------------- sparse GAT aggregation, vectorized short8, both dirs ----------------
__global__ __launch_bounds__(256) void agg_fused(
    const short* __restrict__ hpb2, const float* __restrict__ S,
    const int* __restrict__ mask, const int* __restrict__ logical,
    const int* __restrict__ pol, const int* __restrict__ nvalid,
    short* __restrict__ m, int dil) {
    int t = threadIdx.x;
    int bl = tok_swizzle(blockIdx.x) + (t >> 6);
    int sub = t & 63;
    int dir = sub >> 5;
    int slot = sub & 31;
    int cb = slot * 8;
    int head = slot >> 3;
    int b = bl >> 9;

    int mi = mask[bl];
    int li = logical[bl];
    int nv = nvalid[b];
    int js[3]; int nn = 0;
    if (mi) {
#pragma unroll
        for (int k = 1; k <= 3; k++) {
            int lj = dir ? (li - k * dil) : (li + k * dil);
            if (lj >= 0 && lj < nv) js[nn++] = pol[b * L_ + lj];
        }
    }
    int sn = dir * 4 + head, dn = 8 + sn;
    float si = S[(size_t)bl * 16 + sn];
    float di = S[(size_t)bl * 16 + dn];
    float e0 = si + di; e0 = e0 > 0.f ? e0 : 0.2f * e0;
    float emax = e0, ev[3];
    for (int k = 0; k < nn; k++) {
        float djv = S[((size_t)(b * L_ + js[k])) * 16 + dn];
        float e = si + djv; e = e > 0.f ? e : 0.2f * e;
        ev[k] = e; emax = fmaxf(emax, e);
    }
    float w0 = __expf(e0 - emax), den = w0;
    float wv[3];
    for (int k = 0; k < nn; k++) { wv[k] = __expf(ev[k] - emax); den += wv[k]; }
    float rden = rcp_(den);

    size_t base = (size_t)bl * 512 + dir * 256 + cb;
    short8 vself = *(const short8*)&hpb2[base];
    float o[8];
#pragma unroll
    for (int j = 0; j < 8; j++) o[j] = w0 * bf2f(vself[j]);
    for (int k = 0; k < nn; k++) {
        short8 vn = *(const short8*)&hpb2[((size_t)(b * L_ + js[k])) * 512 + dir * 256 + cb];
#pragma unroll
        for (int j = 0; j < 8; j++) o[j] = fmaf(wv[k], bf2f(vn[j]), o[j]);
    }
    short8 ov;
#pragma unroll
    for (int j = 0; j < 8; j++) ov[j] = f2bf(o[j] * rden);
    *(short8*)&m[base] = ov;
}

// ---------------- masked softmax pooling + both heads (bf16 h) ----------------
__global__ __launch_bounds__(1024) void pool_head_kernel(
    const short* __restrict__ hb, const int* __restrict__ mask,
    const float* __restrict__ pw, const float* __restrict__ pb,
    const float* __restrict__ h0W, const float* __restrict__ h0b,
    const float* __restrict__ h1W, const float* __restrict__ h1b,
    float* __restrict__ out) {
    int b = blockIdx.x;
    int t = threadIdx.x;
    int lane = t & 63, wave = t >> 6;
    __shared__ float sc[L_];
    __shared__ float red[20];
    __shared__ float part[4][C_];
    __shared__ float pooled[C_];

    float4 wv = *(const float4*)&pw[lane * 4];
    for (int l = wave; l < L_; l += 16) {
        short4v hv = *(const short4v*)&hb[((size_t)b * L_ + l) * C_ + lane * 4];
        float p = bf2f(hv.x) * wv.x + bf2f(hv.y) * wv.y
                + bf2f(hv.z) * wv.z + bf2f(hv.w) * wv.w;
#pragma unroll
        for (int off = 32; off; off >>= 1) p += __shfl_down(p, off);
        if (lane == 0) sc[l] = mask[b * L_ + l] ? (p + pb[0]) : NEGV;
    }
    __syncthreads();

    float v = (t < L_) ? sc[t] : NEGV;
    float mx = v;
#pragma unroll
    for (int off = 32; off; off >>= 1) mx = fmaxf(mx, __shfl_down(mx, off));
    if (lane == 0) red[wave] = mx;
    __syncthreads();
    if (t == 0) {
        float g = red[0];
        for (int i = 1; i < 16; i++) g = fmaxf(g, red[i]);
        red[16] = g;
    }
    __syncthreads();
    float gmax = red[16];
    float e = (t < L_) ? __expf(v - gmax) : 0.f;
    float ssum = e;
#pragma unroll
    for (int off = 32; off; off >>= 1) ssum += __shfl_down(ssum, off);
    if (lane == 0) red[wave] = ssum;
    __syncthreads();
    if (t == 0) {
        float g = 0.f;
        for (int i = 0; i < 16; i++) g += red[i];
        red[17] = 1.f / g;
    }
    __syncthreads();
    if (t < L_) sc[t] = e * red[17];
    __syncthreads();

    int g = t >> 8, c = t & 255;
    const short* hrow = &hb[((size_t)b * L_ + g * 128) * C_ + c];
    const float* scg = &sc[g * 128];
    float a0 = 0.f, a1 = 0.f, a2 = 0.f, a3 = 0.f;
    for (int l = 0; l < 128; l += 4) {
        a0 = fmaf(scg[l + 0], bf2f(hrow[(size_t)(l + 0) * C_]), a0);
        a1 = fmaf(scg[l + 1], bf2f(hrow[(size_t)(l + 1) * C_]), a1);
        a2 = fmaf(scg[l + 2], bf2f(hrow[(size_t)(l + 2) * C_]), a2);
        a3 = fmaf(scg[l + 3], bf2f(hrow[(size_t)(l + 3) * C_]), a3);
    }
    part[g][c] = (a0 + a1) + (a2 + a3);
    __syncthreads();
    if (t < C_) pooled[t] = (part[0][t] + part[1][t]) + (part[2][t] + part[3][t]);
    __syncthreads();

    for (int o = wave; o < 70; o += 16) {
        const float* W = (o < 50) ? (h0W + (size_t)o * C_) : (h1W + (size_t)(o - 50) * C_);
        float bb = (o < 50) ? h0b[o] : h1b[o - 50];
        float4 w4 = *(const float4*)&W[lane * 4];
        float4 p4 = *(const float4*)&pooled[lane * 4];
        float s = p4.x * w4.x + p4.y * w4.y + p4.z * w4.z + p4.w * w4.w;
#pragma unroll
        for (int off = 32; off; off >>= 1) s += __shfl_down(s, off);
        if (lane == 0) out[b * 70 + o] = s + bb;
    }
}

extern "C" void kernel_launch(void* const* d_in, const int* in_sizes, int n_in,
                              void* d_out, int out_size, void* d_ws, size_t ws_size,
                              hipStream_t stream) {
    const int*   x    = (const int*)d_in[0];
    const float* emb  = (const float*)d_in[1];
    const float* pos  = (const float*)d_in[2];
    const float* gpW  = (const float*)d_in[3];
    const float* gpas = (const float*)d_in[4];
    const float* gpad = (const float*)d_in[5];
    const float* gfW  = (const float*)d_in[6];
    const float* gfas = (const float*)d_in[7];
    const float* gfad = (const float*)d_in[8];
    const float* msgW = (const float*)d_in[9];
    const float* msgb = (const float*)d_in[10];
    const float* Wih  = (const float*)d_in[11];
    const float* bih  = (const float*)d_in[12];
    const float* Whh  = (const float*)d_in[13];
    const float* bhh  = (const float*)d_in[14];
    const float* lng  = (const float*)d_in[15];
    const float* lnb  = (const float*)d_in[16];
    const float* pw   = (const float*)d_in[17];
    const float* pb   = (const float*)d_in[18];
    const float* h0W  = (const float*)d_in[19];
    const float* h0b  = (const float*)d_in[20];
    const float* h1W  = (const float*)d_in[21];
    const float* h1b  = (const float*)d_in[22];
    float* out = (float*)d_out;

    // Workspace layout, units MW = 1Mi floats = 4 MiB:
    //   hn2b bf16 [32768, 256] =  4 MW   -> [ 0,  4)
    //   hb   bf16 [32768, 256] =  4 MW   -> [ 8, 12)
    //   mmb  bf16 [32768, 256] =  4 MW   -> [12, 16)   (also Ssd fp32 [32768,16])
    //   hpb2 bf16 [32768, 512] =  8 MW   -> [16, 24)
    //   mb   bf16 [32768, 512] =  8 MW   -> [24, 32)
    //   weights/bias/masks               -> [32, ~33.3)
    const size_t MW = 1024 * 1024;
    float* ws = (float*)d_ws;
    short* hn2b = (short*)ws;
    short* hb   = (short*)(ws + 8 * MW);
    short* mmb  = (short*)(ws + 12 * MW);
    float* Ssd  = ws + 12 * MW;                          // aliases mmb (timeshared)
    short* hpb2 = (short*)(ws + 16 * MW);
    short* mb   = (short*)(ws + 24 * MW);
    short* Wcomb = (short*)(ws + 32 * MW);               // 3*640*256 shorts
    short* msgWb = Wcomb + 3 * 640 * 256;                // 3*256*512 shorts
    short* Bcat  = msgWb + 3 * 256 * 512;                // 3*1024*512 shorts (interleaved)
    float* bias4 = (float*)(Bcat + 3 * 1024 * 512);      // 3*1024 floats
    int* mask    = (int*)(bias4 + 3 * 1024);
    int* logical = mask + B_ * L_;
    int* pol     = logical + B_ * L_;
    int* nvalid  = pol + B_ * L_;

    // weight prep
    prep_wcomb<<<(3 * 640 * 256 + 255) / 256, 256, 0, stream>>>(gpW, gfW, gpas, gpad,
                                                                gfas, gfad, Wcomb);
    f2bf_kernel<<<(3 * 256 * 512 + 255) / 256, 256, 0, stream>>>(msgW, msgWb, 3 * 256 * 512);
    prep_gru_i<<<(3 * 1024 * 512 + 255) / 256, 256, 0, stream>>>(Wih, Whh, Bcat);
    prep_bias4<<<12, 256, 0, stream>>>(bih, bhh, bias4);

    scan_kernel<<<B_, L_, 0, stream>>>(x, mask, logical, pol, nvalid);
    embed_kernel<<<B_ * L_ / 4, 256, 0, stream>>>(x, emb, pos, hb);

    const int DILS[LAY] = {1, 2, 4};

    for (int l = 0; l < LAY; l++) {
        int dil = DILS[l];
        // hpb2 (N=512 bf16) + Ssd (16 fp32 cols) in one dispatch
        projssd_bgemm<<<256 * 5, 256, 0, stream>>>(hb, Wcomb + (size_t)l * 640 * 256,
                                                   hpb2, Ssd);
        // sparse GAT aggregation, both dirs in one wave, short8-vectorized
        agg_fused<<<8192, 256, 0, stream>>>(hpb2, Ssd, mask, logical, pol, nvalid, mb, dil);
        // mm = relu(m @ msgW^T + msgb) -> bf16, deep 256x128 pipeline (256 blocks)
        msg_bgemm<<<256, 512, 0, stream>>>(mb, msgWb + (size_t)l * 256 * 512,
                                           mmb, msgb + l * C_);
        // 256x256-tile 8-phase deep-vmcnt GRU GEMM + gate epilogue -> hn2b
        gru_bgemm<<<512, 512, 0, stream>>>(mmb, hb, Bcat + (size_t)l * 1024 * 512,
                                           hn2b, bias4 + l * 1024);
        // LayerNorm + mask -> hb
        ln_kernel<<<8192, 256, 0, stream>>>(hn2b, hb, mask, lng + l * C_, lnb + l * C_);
    }

    pool_head_kernel<<<B_, 1024, 0, stream>>>(hb, mask, pw, pb, h0W, h0b, h1W, h1b, out);
}

// Round 5
// 491.951 us; speedup vs baseline: 1.1496x; 1.0174x over previous
//
#include <hip/hip_runtime.h>
#include <math.h>

#define B_ 64
#define L_ 512
#define C_ 256
#define H_ 4
#define LAY 3
#define NEGV -1e9f

typedef __attribute__((ext_vector_type(8))) short short8;
typedef __attribute__((ext_vector_type(4))) short short4v;
typedef __attribute__((ext_vector_type(4))) float floatx4;

static __device__ __forceinline__ float rcp_(float x) { return __builtin_amdgcn_rcpf(x); }
static __device__ __forceinline__ float sig_(float x) { return rcp_(1.f + __expf(-x)); }
static __device__ __forceinline__ float tanh_(float x) {
    float e = __expf(2.f * x);
    return 1.f - 2.f * rcp_(e + 1.f);
}

static __device__ __forceinline__ short f2bf(float f) {
    unsigned x = __float_as_uint(f);
    x += 0x7fffu + ((x >> 16) & 1u);       // round-to-nearest-even to bf16
    return (short)(x >> 16);
}
static __device__ __forceinline__ float bf2f(short s) {
    return __uint_as_float(((unsigned)(unsigned short)s) << 16);
}

// XCD-aligned token swizzle for elementwise consumers (matches GEMM rb%8 = XCD).
static __device__ __forceinline__ int tok_swizzle(int blk) {
    int c8 = blk & 7, i = blk >> 3;
    return (c8 + 8 * (i >> 5)) * 128 + (i & 31) * 4;
}

static __device__ __forceinline__ void gl_lds16(const short* g, short* l) {
    __builtin_amdgcn_global_load_lds(
        (const __attribute__((address_space(1))) unsigned int*)g,
        (__attribute__((address_space(3))) unsigned int*)l, 16, 0, 0);
}

#define CF() asm volatile("" ::: "memory")

// ---------------- mask / logical-position scan + pos_of_logical ----------------
__global__ void scan_kernel(const int* __restrict__ x, int* __restrict__ mask,
                            int* __restrict__ logical, int* __restrict__ pol,
                            int* __restrict__ nvalid) {
    int b = blockIdx.x, t = threadIdx.x;
    __shared__ int s[L_];
    int m = (x[b * L_ + t] != 0) ? 1 : 0;
    s[t] = m;
    __syncthreads();
    for (int off = 1; off < L_; off <<= 1) {
        int v = (t >= off) ? s[t - off] : 0;
        __syncthreads();
        s[t] += v;
        __syncthreads();
    }
    int cum = s[t];
    int lg = cum - 1; if (lg < 0) lg = 0;
    mask[b * L_ + t] = m;
    logical[b * L_ + t] = lg;
    if (m) pol[b * L_ + lg] = t;
    if (t == L_ - 1) nvalid[b] = cum;
}

// ---------------- hb = bf16((emb[x] + pos*mf)*mf) ----------------
__global__ void embed_kernel(const int* __restrict__ x, const float* __restrict__ emb,
                             const float* __restrict__ pos, short* __restrict__ hb) {
    int t = threadIdx.x;
    int bl = tok_swizzle(blockIdx.x) + (t >> 6);
    int lane = t & 63;
    int xv = x[bl];
    float mf = (xv != 0) ? 1.f : 0.f;
    int l = bl & (L_ - 1);
    float4 e = *(const float4*)&emb[(size_t)xv * C_ + lane * 4];
    float4 p = *(const float4*)&pos[(size_t)l * C_ + lane * 4];
    short4v hv4;
    hv4.x = f2bf((e.x + p.x * mf) * mf);
    hv4.y = f2bf((e.y + p.y * mf) * mf);
    hv4.z = f2bf((e.z + p.z * mf) * mf);
    hv4.w = f2bf((e.w + p.w * mf) * mf);
    *(short4v*)&hb[(size_t)bl * C_ + lane * 4] = hv4;
}

// ---------------- weight prep ----------------
__global__ void f2bf_kernel(const float* __restrict__ s, short* __restrict__ d, int n) {
    int i = blockIdx.x * 256 + threadIdx.x;
    if (i < n) d[i] = f2bf(s[i]);
}

// Wcomb[l][640][256]: rows 0..255 = gpW[l], 256..511 = gfW[l],
// rows 512..527 = AsdW (n = type*8+dir*4+head -> a_vec @ W_dir), rest 0.
__global__ void prep_wcomb(const float* __restrict__ gpW, const float* __restrict__ gfW,
                           const float* __restrict__ gpas, const float* __restrict__ gpad,
                           const float* __restrict__ gfas, const float* __restrict__ gfad,
                           short* __restrict__ Wc) {
    int i = blockIdx.x * 256 + threadIdx.x;
    if (i >= 3 * 640 * 256) return;
    int k = i & 255;
    int r = (i >> 8) % 640;
    int l = i / (640 * 256);
    float v = 0.f;
    if (r < 256) {
        v = gpW[((size_t)l * 256 + r) * 256 + k];
    } else if (r < 512) {
        v = gfW[((size_t)l * 256 + (r - 256)) * 256 + k];
    } else {
        int n = r - 512;
        if (n < 16) {
            int type = n >> 3, dir = (n >> 2) & 1, hh = n & 3;
            const float* a = type ? (dir ? gfad : gpad) : (dir ? gfas : gpas);
            const float* W = dir ? gfW : gpW;
            for (int j = 0; j < 64; j++) {
                float av = a[l * 256 + hh * 64 + j];
                float wv = W[((size_t)l * 256 + hh * 64 + j) * 256 + k];
                v = fmaf(av, wv, v);
            }
        }
    }
    Wc[i] = f2bf(v);
}

// Interleaved GRU weights: Bc[l][n'][512], n' = 4*ch + g, g in {0:r,1:z,2:i,3:n}.
__global__ void prep_gru_i(const float* __restrict__ Wih, const float* __restrict__ Whh,
                           short* __restrict__ Bc) {
    int i = blockIdx.x * 256 + threadIdx.x;
    if (i >= 3 * 1024 * 512) return;
    int k = i & 511, np = (i >> 9) & 1023, l = i >> 19;
    int ch = np >> 2, g = np & 3;
    float v = 0.f;
    if (g < 2) {
        v = (k < 256) ? Wih[((size_t)l * 768 + g * 256 + ch) * 256 + k]
                      : Whh[((size_t)l * 768 + g * 256 + ch) * 256 + (k - 256)];
    } else if (g == 2) {
        if (k < 256) v = Wih[((size_t)l * 768 + 512 + ch) * 256 + k];
    } else {
        if (k >= 256) v = Whh[((size_t)l * 768 + 512 + ch) * 256 + (k - 256)];
    }
    Bc[i] = f2bf(v);
}

// bias4[l][4*ch+g]
__global__ void prep_bias4(const float* __restrict__ bih, const float* __restrict__ bhh,
                           float* __restrict__ bc) {
    int i = blockIdx.x * 256 + threadIdx.x;
    if (i >= 3 * 1024) return;
    int np = i & 1023, l = i >> 10;
    int ch = np >> 2, g = np & 3;
    float v;
    if (g < 2)       v = bih[l * 768 + g * 256 + ch] + bhh[l * 768 + g * 256 + ch];
    else if (g == 2) v = bih[l * 768 + 512 + ch];
    else             v = bhh[l * 768 + 512 + ch];
    bc[i] = v;
}

// ---------------- deep-GEMM fragment helpers (shared) ----------
static __device__ __forceinline__ short8 lds_rd8(const short* p) {
    return *(const short8*)p;
}

template <int MH>
static __device__ __forceinline__ void ld_af(const short* bufA, int wm, int q, int t16,
                                             short8 af[4][2]) {
#pragma unroll
    for (int mfl = 0; mfl < 4; ++mfl) {
        int row = wm * 128 + (MH * 4 + mfl) * 16 + t16;
#pragma unroll
        for (int ks = 0; ks < 2; ++ks) {
            int cg = (ks * 4 + q) ^ (row & 7);
            af[mfl][ks] = lds_rd8(&bufA[row * 64 + cg * 8]);
        }
    }
}

template <int NH>
static __device__ __forceinline__ void ld_bf(const short* bufB, int wn, int q, int t16,
                                             short8 bf[2][2]) {
#pragma unroll
    for (int nfl = 0; nfl < 2; ++nfl) {
        int row = wn * 64 + (NH * 2 + nfl) * 16 + t16;
#pragma unroll
        for (int ks = 0; ks < 2; ++ks) {
            int cg = (ks * 4 + q) ^ (row & 7);
            bf[nfl][ks] = lds_rd8(&bufB[row * 64 + cg * 8]);
        }
    }
}

// B fragment read for BN=128 (wave covers 32 cols): rows wn*32 + nfl*16 + t16
static __device__ __forceinline__ void ld_bf32(const short* bufB, int wn, int q, int t16,
                                               short8 bf[2][2]) {
#pragma unroll
    for (int nfl = 0; nfl < 2; ++nfl) {
        int row = wn * 32 + nfl * 16 + t16;
#pragma unroll
        for (int ks = 0; ks < 2; ++ks) {
            int cg = (ks * 4 + q) ^ (row & 7);
            bf[nfl][ks] = lds_rd8(&bufB[row * 64 + cg * 8]);
        }
    }
}

template <int MH, int NH>
static __device__ __forceinline__ void mfma_q(const short8 af[4][2], const short8 bf[2][2],
                                              floatx4 acc[4][8]) {
    __builtin_amdgcn_s_setprio(1);
#pragma unroll
    for (int ks = 0; ks < 2; ++ks)
#pragma unroll
        for (int mfl = 0; mfl < 4; ++mfl)
#pragma unroll
            for (int nfl = 0; nfl < 2; ++nfl)
                acc[NH * 2 + nfl][MH * 4 + mfl] = __builtin_amdgcn_mfma_f32_16x16x32_bf16(
                    bf[nfl][ks], af[mfl][ks], acc[NH * 2 + nfl][MH * 4 + mfl], 0, 0, 0);
    __builtin_amdgcn_s_setprio(0);
}

template <int MH>
static __device__ __forceinline__ void mfma_m(const short8 af[4][2], const short8 bf[2][2],
                                              floatx4 acc[2][8]) {
    __builtin_amdgcn_s_setprio(1);
#pragma unroll
    for (int ks = 0; ks < 2; ++ks)
#pragma unroll
        for (int mfl = 0; mfl < 4; ++mfl)
#pragma unroll
            for (int nfl = 0; nfl < 2; ++nfl)
                acc[nfl][MH * 4 + mfl] = __builtin_amdgcn_mfma_f32_16x16x32_bf16(
                    bf[nfl][ks], af[mfl][ks], acc[nfl][MH * 4 + mfl], 0, 0, 0);
    __builtin_amdgcn_s_setprio(0);
}

// ---------------- projection + Ssd GEMM, deep 256x128 pipeline ----------
// A = hb [32768,256] K=256 (4 K-tiles), B = Wcomb [640,256] as 5 cb of 128 rows.
// cb 0..3 -> hpb2 bf16 (ldc 512); cb 4 -> Ssd fp32 (16 real cols).
// Grid 640 = 8 XCD x 16 rb x 5 cb (XCD-coherent: one A-panel range per XCD).
// Same schedule as msg_bgemm: P0 stageA(t+1), P1 stageB(t+2), vmcnt(2) boundary.
__global__ __launch_bounds__(512, 2) void projssd_deep(const short* __restrict__ A0,
                                                       const short* __restrict__ Bw,
                                                       short* __restrict__ hpb2,
                                                       float* __restrict__ Ssd) {
    __shared__ short lds[2][24576];   // per buf: A[256][64] @0, B[128][64] @16384
    const int id = blockIdx.x;
    const int j = id >> 3;                       // 0..79
    const int cb = j >> 4;                       // 0..4
    const int rb = (id & 7) * 16 + (j & 15);     // 0..127
    const int tid = threadIdx.x;
    const int wave = tid >> 6, lane = tid & 63;
    const int wm = wave >> 2, wn = wave & 3;
    const int q = lane >> 4, t16 = lane & 15;
    const size_t arow0 = (size_t)rb * 256;
    const short* Bb = Bw + (size_t)cb * 128 * 256;

    floatx4 acc[2][8];
#pragma unroll
    for (int i = 0; i < 2; i++)
#pragma unroll
        for (int jj = 0; jj < 8; jj++) acc[i][jj] = (floatx4)0.f;

    auto stageA = [&](int t, int Hh) {
        short* bufA = lds[t & 1];
#pragma unroll
        for (int u = 0; u < 2; ++u) {
            int unit = u * 512 + tid;
            int row = Hh * 128 + (unit >> 3);
            int cs = (unit & 7) ^ (row & 7);
            gl_lds16(A0 + (arow0 + (size_t)row) * 256 + t * 64 + cs * 8,
                     bufA + Hh * 8192 + unit * 8);
        }
    };
    auto stageB = [&](int t) {
        short* bufB = lds[t & 1] + 16384;
#pragma unroll
        for (int u = 0; u < 2; ++u) {
            int unit = u * 512 + tid;
            int row = unit >> 3;                 // 0..127
            int cs = (unit & 7) ^ (row & 7);
            gl_lds16(Bb + (size_t)row * 256 + t * 64 + cs * 8, bufB + unit * 8);
        }
    };

    // prologue: A(0)+B(0)+B(1); vmcnt(2): tile0 complete, B(1) in flight
    stageA(0, 0); stageA(0, 1); stageB(0); stageB(1);
    asm volatile("s_waitcnt vmcnt(2)" ::: "memory");
    CF(); __builtin_amdgcn_s_barrier(); CF();

    short8 af[4][2], bfr[2][2];

#pragma unroll
    for (int t = 0; t < 4; ++t) {
        const short* bufA = lds[t & 1];
        const short* bufB = lds[t & 1] + 16384;

        // ---- P0 ----
        ld_af<0>(bufA, wm, q, t16, af);
        ld_bf32(bufB, wn, q, t16, bfr);
        if (t < 3) { stageA(t + 1, 0); stageA(t + 1, 1); }
        CF(); __builtin_amdgcn_s_barrier();
        asm volatile("s_waitcnt lgkmcnt(0)" ::: "memory");
        __builtin_amdgcn_sched_barrier(0);
        mfma_m<0>(af, bfr, acc);
        CF(); __builtin_amdgcn_s_barrier(); CF();

        // ---- P1 ----  (bufB[t&1] free after P0's end barrier)
        ld_af<1>(bufA, wm, q, t16, af);
        if (t < 2) stageB(t + 2);
        CF(); __builtin_amdgcn_s_barrier();
        asm volatile("s_waitcnt lgkmcnt(0)" ::: "memory");
        __builtin_amdgcn_sched_barrier(0);
        mfma_m<1>(af, bfr, acc);
        if (t < 2)       asm volatile("s_waitcnt vmcnt(2)" ::: "memory");
        else if (t == 2) asm volatile("s_waitcnt vmcnt(0)" ::: "memory");
        CF(); __builtin_amdgcn_s_barrier(); CF();
    }

    if (cb < 4) {
        // bf16 -> hpb2 (ldc 512), LDS-staged coalesced write
        short* sO = (short*)lds;                 // [256][132]
#pragma unroll
        for (int nf = 0; nf < 2; nf++) {
            int chl = wn * 32 + nf * 16 + q * 4; // 0..127 within block
#pragma unroll
            for (int mf = 0; mf < 8; mf++) {
                int rowl = wm * 128 + mf * 16 + t16;
                short4v pk;
                pk.x = f2bf(acc[nf][mf][0]);
                pk.y = f2bf(acc[nf][mf][1]);
                pk.z = f2bf(acc[nf][mf][2]);
                pk.w = f2bf(acc[nf][mf][3]);
                *(short4v*)&sO[rowl * 132 + chl] = pk;
            }
        }
        __syncthreads();
#pragma unroll
        for (int it = 0; it < 8; ++it) {
            int unit = it * 512 + tid;
            int rowl = unit >> 4, ck = unit & 15;
            *(short8*)&hpb2[(arow0 + rowl) * 512 + cb * 128 + ck * 8] =
                *(const short8*)&sO[rowl * 132 + ck * 8];
        }
    } else {
        // Ssd fp32: only cols 0..15 real (wn==0, nf==0)
        if (wn == 0) {
            int chl = q * 4;
            if (chl < 16) {
#pragma unroll
                for (int mf = 0; mf < 8; mf++) {
                    int rowl = wm * 128 + mf * 16 + t16;
                    float4 pk = make_float4(acc[0][mf][0], acc[0][mf][1],
                                            acc[0][mf][2], acc[0][mf][3]);
                    *(float4*)&Ssd[(arow0 + rowl) * 16 + chl] = pk;
                }
            }
        }
    }
}

// ---------------- dedicated GRU GEMM, 256x256 tile, 8-phase deep-vmcnt ----------
// (round-3 schedule, measured 44.1 us: full unroll + sched_barrier(0) after lgkm)
// A = [mmb | hb] K=512, B = Bcat interleaved (N=1024, n'=4ch+g).
// 8 waves (2M x 4N), BK=64, dbuf 128 KiB LDS, XOR-swizzle (src-perm + read-perm).
// Deep staging: su(t+2).B at t.P2, su(t+2).A at t.P3; one vmcnt(8) per boundary.
// K-tile order rotated so the hb-slice covering this block's cb channels is
// staged LAST -> epilogue reads h_prev from LDS. XCD: rb=16*(id&7)+(id>>5).
__global__ __launch_bounds__(512, 2) void gru_bgemm(const short* __restrict__ mmb,
                                                    const short* __restrict__ hb_in,
                                                    const short* __restrict__ Bw,
                                                    short* __restrict__ hn2b,
                                                    const float* __restrict__ bias4) {
    __shared__ short lds[2][32768];   // per buf: A[256][64] @0, B[256][64] @16384
    const int id = blockIdx.x;
    const int rb = 16 * (id & 7) + (id >> 5);
    const int cb = (id >> 3) & 3;
    const int tid = threadIdx.x;
    const int wave = tid >> 6, lane = tid & 63;
    const int wm = wave >> 2, wn = wave & 3;
    const int q = lane >> 4, t16 = lane & 15;
    const size_t arow0 = (size_t)rb * 256;
    const short* Bb = Bw + (size_t)cb * 256 * 512;
    const int ord0 = (5 + cb) & 7;

    floatx4 acc[4][8];   // [nf][mf]
#pragma unroll
    for (int i = 0; i < 4; i++)
#pragma unroll
        for (int jj = 0; jj < 8; jj++) acc[i][jj] = (floatx4)0.f;

    auto stageA = [&](int i, int Hh) {
        int tt = (ord0 + i) & 7;
        const short* Asrc = (tt < 4) ? (mmb + tt * 64) : (hb_in + (tt - 4) * 64);
        short* bufA = lds[i & 1];
#pragma unroll
        for (int u = 0; u < 2; ++u) {
            int unit = u * 512 + tid;              // 0..1023
            int row = Hh * 128 + (unit >> 3);
            int cs = (unit & 7) ^ (row & 7);
            gl_lds16(Asrc + (arow0 + (size_t)row) * 256 + cs * 8,
                     bufA + Hh * 8192 + unit * 8);
        }
    };
    auto stageB = [&](int i, int Hh) {
        int tt = (ord0 + i) & 7;
        short* bufB = lds[i & 1] + 16384;
#pragma unroll
        for (int u = 0; u < 2; ++u) {
            int unit = u * 512 + tid;
            int row = Hh * 128 + (unit >> 3);
            int cs = (unit & 7) ^ (row & 7);
            gl_lds16(Bb + (size_t)row * 512 + tt * 64 + cs * 8,
                     bufB + Hh * 8192 + unit * 8);
        }
    };

    // prologue: tiles 0 and 1 fully issued (16 loads/wave);
    // vmcnt(8): tile 0 complete, tile 1's 8 loads stay in flight
    stageA(0, 0); stageA(0, 1); stageB(0, 0); stageB(0, 1);
    stageA(1, 0); stageA(1, 1); stageB(1, 0); stageB(1, 1);
    asm volatile("s_waitcnt vmcnt(8)" ::: "memory");
    CF(); __builtin_amdgcn_s_barrier(); CF();

    short8 af[4][2], b0[2][2], b1[2][2];

#pragma unroll
    for (int t = 0; t < 8; ++t) {
        const short* bufA = lds[t & 1];
        const short* bufB = lds[t & 1] + 16384;

        // ---- P0: quadrant (0,0) ----
        ld_af<0>(bufA, wm, q, t16, af);
        ld_bf<0>(bufB, wn, q, t16, b0);
        CF(); __builtin_amdgcn_s_barrier();
        asm volatile("s_waitcnt lgkmcnt(0)" ::: "memory");
        __builtin_amdgcn_sched_barrier(0);
        mfma_q<0, 0>(af, b0, acc);
        CF(); __builtin_amdgcn_s_barrier(); CF();

        // ---- P1: quadrant (0,1) ----
        ld_bf<1>(bufB, wn, q, t16, b1);
        CF(); __builtin_amdgcn_s_barrier();
        asm volatile("s_waitcnt lgkmcnt(0)" ::: "memory");
        __builtin_amdgcn_sched_barrier(0);
        mfma_q<0, 1>(af, b1, acc);
        CF(); __builtin_amdgcn_s_barrier(); CF();

        // ---- P2: quadrant (1,1) ----  (bufB[t&1] free after P1's end barrier)
        ld_af<1>(bufA, wm, q, t16, af);
        if (t < 6) { stageB(t + 2, 0); stageB(t + 2, 1); }
        CF(); __builtin_amdgcn_s_barrier();
        asm volatile("s_waitcnt lgkmcnt(0)" ::: "memory");
        __builtin_amdgcn_sched_barrier(0);
        mfma_q<1, 1>(af, b1, acc);
        CF(); __builtin_amdgcn_s_barrier(); CF();

        // ---- P3: quadrant (1,0) ----  (bufA[t&1] free after P2's end barrier)
        if (t < 6) { stageA(t + 2, 0); stageA(t + 2, 1); }
        CF(); __builtin_amdgcn_s_barrier();
        mfma_q<1, 0>(af, b0, acc);
        // tile boundary: su(t+1) (oldest 8) complete; su(t+2) (8) stay in flight
        if (t < 6)       asm volatile("s_waitcnt vmcnt(8)" ::: "memory");
        else if (t == 6) asm volatile("s_waitcnt vmcnt(0)" ::: "memory");
        CF(); __builtin_amdgcn_s_barrier(); CF();
    }

    // epilogue: h_prev from LDS (lds[1] holds A-tile of tt=4+cb = hb cols cb*64..),
    // compute gates, stage hn2 tile in LDS, coalesced bf16 write.
    const short* hpt = lds[1];
    short* sO = (short*)lds;                   // [256][72] bf16 within lds[0]
#pragma unroll
    for (int nf = 0; nf < 4; nf++) {
        int chl = wn * 16 + nf * 4 + q;        // 0..63 within block
        int col0 = cb * 256 + wn * 64 + nf * 16 + q * 4;
        float4 bv4 = *(const float4*)&bias4[col0];
#pragma unroll
        for (int mf = 0; mf < 8; mf++) {
            int rowl = wm * 128 + mf * 16 + t16;
            float hp = bf2f(hpt[rowl * 64 + (((chl >> 3) ^ (rowl & 7)) << 3) + (chl & 7)]);
            float r = sig_(acc[nf][mf][0] + bv4.x);
            float z = sig_(acc[nf][mf][1] + bv4.y);
            float nv = tanh_((acc[nf][mf][2] + bv4.z) + r * (acc[nf][mf][3] + bv4.w));
            sO[rowl * 72 + chl] = f2bf((1.f - z) * nv + z * hp);
        }
    }
    __syncthreads();
#pragma unroll
    for (int it = 0; it < 4; ++it) {
        int unit = it * 512 + tid;
        int rowl = unit >> 3, ck = unit & 7;
        *(short8*)&hn2b[(arow0 + rowl) * 256 + cb * 64 + ck * 8] =
            *(const short8*)&sO[rowl * 72 + ck * 8];
    }
}

// ---------------- msg GEMM, 256x128 tile, deep pipeline ----------
// C = relu(mb[32768,512] @ msgWb[256,512]^T + bias) -> bf16 mmb [32768,256].
// Grid 256 = 128 rb x 2 cb, 1 block/CU. 8 waves 2Mx4N, BK=64, 8 K-tiles.
__global__ __launch_bounds__(512, 2) void msg_bgemm(const short* __restrict__ A0,
                                                    const short* __restrict__ Bw,
                                                    short* __restrict__ Cout,
                                                    const float* __restrict__ bias) {
    __shared__ short lds[2][24576];   // per buf: A[256][64] @0, B[128][64] @16384
    const int id = blockIdx.x;
    const int j = id >> 3;                       // 0..31
    const int rb = (id & 7) * 16 + (j & 15);     // 0..127
    const int cb = j >> 4;                       // 0..1
    const int tid = threadIdx.x;
    const int wave = tid >> 6, lane = tid & 63;
    const int wm = wave >> 2, wn = wave & 3;
    const int q = lane >> 4, t16 = lane & 15;
    const size_t arow0 = (size_t)rb * 256;
    const short* Bb = Bw + (size_t)cb * 128 * 512;

    floatx4 acc[2][8];
#pragma unroll
    for (int i = 0; i < 2; i++)
#pragma unroll
        for (int jj = 0; jj < 8; jj++) acc[i][jj] = (floatx4)0.f;

    auto stageA = [&](int t, int Hh) {
        short* bufA = lds[t & 1];
#pragma unroll
        for (int u = 0; u < 2; ++u) {
            int unit = u * 512 + tid;
            int row = Hh * 128 + (unit >> 3);
            int cs = (unit & 7) ^ (row & 7);
            gl_lds16(A0 + (arow0 + (size_t)row) * 512 + t * 64 + cs * 8,
                     bufA + Hh * 8192 + unit * 8);
        }
    };
    auto stageB = [&](int t) {
        short* bufB = lds[t & 1] + 16384;
#pragma unroll
        for (int u = 0; u < 2; ++u) {
            int unit = u * 512 + tid;
            int row = unit >> 3;                 // 0..127
            int cs = (unit & 7) ^ (row & 7);
            gl_lds16(Bb + (size_t)row * 512 + t * 64 + cs * 8, bufB + unit * 8);
        }
    };

    // prologue: A(0)+B(0)+B(1); vmcnt(2): tile0 complete, B(1) in flight
    stageA(0, 0); stageA(0, 1); stageB(0); stageB(1);
    asm volatile("s_waitcnt vmcnt(2)" ::: "memory");
    CF(); __builtin_amdgcn_s_barrier(); CF();

    short8 af[4][2], bfr[2][2];

#pragma unroll 2
    for (int t = 0; t < 8; ++t) {
        const short* bufA = lds[t & 1];
        const short* bufB = lds[t & 1] + 16384;

        // ---- P0 ----
        ld_af<0>(bufA, wm, q, t16, af);
        ld_bf32(bufB, wn, q, t16, bfr);
        if (t < 7) { stageA(t + 1, 0); stageA(t + 1, 1); }
        CF(); __builtin_amdgcn_s_barrier();
        asm volatile("s_waitcnt lgkmcnt(0)" ::: "memory");
        mfma_m<0>(af, bfr, acc);
        CF(); __builtin_amdgcn_s_barrier(); CF();

        // ---- P1 ----  (bufB[t&1] free after P0's end barrier)
        ld_af<1>(bufA, wm, q, t16, af);
        if (t < 6) stageB(t + 2);
        CF(); __builtin_amdgcn_s_barrier();
        asm volatile("s_waitcnt lgkmcnt(0)" ::: "memory");
        mfma_m<1>(af, bfr, acc);
        if (t < 6)       asm volatile("s_waitcnt vmcnt(2)" ::: "memory");
        else if (t == 6) asm volatile("s_waitcnt vmcnt(0)" ::: "memory");
        CF(); __builtin_amdgcn_s_barrier(); CF();
    }

    // epilogue: bias + relu + bf16, LDS-staged coalesced write
    short* sO = (short*)lds;                     // [256][132]
#pragma unroll
    for (int nf = 0; nf < 2; nf++) {
        int chl = wn * 32 + nf * 16 + q * 4;     // 0..127 within block
        int col0 = cb * 128 + chl;
        float4 bv4 = *(const float4*)&bias[col0];
#pragma unroll
        for (int mf = 0; mf < 8; mf++) {
            int rowl = wm * 128 + mf * 16 + t16;
            short4v pk;
            pk.x = f2bf(fmaxf(acc[nf][mf][0] + bv4.x, 0.f));
            pk.y = f2bf(fmaxf(acc[nf][mf][1] + bv4.y, 0.f));
            pk.z = f2bf(fmaxf(acc[nf][mf][2] + bv4.z, 0.f));
            pk.w = f2bf(fmaxf(acc[nf][mf][3] + bv4.w, 0.f));
            *(short4v*)&sO[rowl * 132 + chl] = pk;
        }
    }
    __syncthreads();
#pragma unroll
    for (int it = 0; it < 8; ++it) {
        int unit = it * 512 + tid;
        int rowl = unit >> 4, ck = unit & 15;
        *(short8*)&Cout[(arow0 + rowl) * 256 + cb * 128 + ck * 8] =
            *(const short8*)&sO[rowl * 132 + ck * 8];
    }
}

// ---------------- LayerNorm over hn2 (bf16) + mask -> hb ----------------
__global__ __launch_bounds__(256) void ln_kernel(
    const short* __restrict__ hn2b, short* __restrict__ hb,
    const int* __restrict__ mask,
    const float* __restrict__ lng, const float* __restrict__ lnb) {
    int t = threadIdx.x;
    int bl = tok_swizzle(blockIdx.x) + (t >> 6);
    int lane = t & 63;
    short4v v4 = *(const short4v*)&hn2b[(size_t)bl * C_ + lane * 4];
    float v[4] = {bf2f(v4.x), bf2f(v4.y), bf2f(v4.z), bf2f(v4.w)};
    float s = (v[0] + v[1]) + (v[2] + v[3]);
    float ss = (v[0] * v[0] + v[1] * v[1]) + (v[2] * v[2] + v[3] * v[3]);
#pragma unroll
    for (int off = 32; off; off >>= 1) {
        s += __shfl_xor(s, off);
        ss += __shfl_xor(ss, off);
    }
    float mu = s * (1.f / 256.f);
    float var = ss * (1.f / 256.f) - mu * mu;
    float rstd = rsqrtf(fmaxf(var, 0.f) + 1e-5f);
    float4 lg = *(const float4*)&lng[lane * 4];
    float4 lb = *(const float4*)&lnb[lane * 4];
    float mfv = mask[bl] ? 1.f : 0.f;
    short4v yb;
    yb.x = f2bf(((v[0] - mu) * rstd * lg.x + lb.x) * mfv);
    yb.y = f2bf(((v[1] - mu) * rstd * lg.y + lb.y) * mfv);
    yb.z = f2bf(((v[2] - mu) * rstd * lg.z + lb.z) * mfv);
    yb.w = f2bf(((v[3] - mu) * rstd * lg.w + lb.w) * mfv);
    *(short4v*)&hb[(size_t)bl * C_ + lane * 4] = yb;
}

// ---------------- sparse GAT aggregation, vectorized short8, both dirs ----------------
__global__ __launch_bounds__(256) void agg_fused(
    const short* __restrict__ hpb2, const float* __restrict__ S,
    const int* __restrict__ mask, const int* __restrict__ logical,
    const int* __restrict__ pol, const int* __restrict__ nvalid,
    short* __restrict__ m, int dil) {
    int t = threadIdx.x;
    int bl = tok_swizzle(blockIdx.x) + (t >> 6);
    int sub = t & 63;
    int dir = sub >> 5;
    int slot = sub & 31;
    int cb = slot * 8;
    int head = slot >> 3;
    int b = bl >> 9;

    int mi = mask[bl];
    int li = logical[bl];
    int nv = nvalid[b];
    int js[3]; int nn = 0;
    if (mi) {
#pragma unroll
        for (int k = 1; k <= 3; k++) {
            int lj = dir ? (li - k * dil) : (li + k * dil);
            if (lj >= 0 && lj < nv) js[nn++] = pol[b * L_ + lj];
        }
    }
    int sn = dir * 4 + head, dn = 8 + sn;
    float si = S[(size_t)bl * 16 + sn];
    float di = S[(size_t)bl * 16 + dn];
    float e0 = si + di; e0 = e0 > 0.f ? e0 : 0.2f * e0;
    float emax = e0, ev[3];
    for (int k = 0; k < nn; k++) {
        float djv = S[((size_t)(b * L_ + js[k])) * 16 + dn];
        float e = si + djv; e = e > 0.f ? e : 0.2f * e;
        ev[k] = e; emax = fmaxf(emax, e);
    }
    float w0 = __expf(e0 - emax), den = w0;
    float wv[3];
    for (int k = 0; k < nn; k++) { wv[k] = __expf(ev[k] - emax); den += wv[k]; }
    float rden = rcp_(den);

    size_t base = (size_t)bl * 512 + dir * 256 + cb;
    short8 vself = *(const short8*)&hpb2[base];
    float o[8];
#pragma unroll
    for (int j = 0; j < 8; j++) o[j] = w0 * bf2f(vself[j]);
    for (int k = 0; k < nn; k++) {
        short8 vn = *(const short8*)&hpb2[((size_t)(b * L_ + js[k])) * 512 + dir * 256 + cb];
#pragma unroll
        for (int j = 0; j < 8; j++) o[j] = fmaf(wv[k], bf2f(vn[j]), o[j]);
    }
    short8 ov;
#pragma unroll
    for (int j = 0; j < 8; j++) ov[j] = f2bf(o[j] * rden);
    *(short8*)&m[base] = ov;
}

// ---------------- masked softmax pooling + both heads (bf16 h) ----------------
__global__ __launch_bounds__(1024) void pool_head_kernel(
    const short* __restrict__ hb, const int* __restrict__ mask,
    const float* __restrict__ pw, const float* __restrict__ pb,
    const float* __restrict__ h0W, const float* __restrict__ h0b,
    const float* __restrict__ h1W, const float* __restrict__ h1b,
    float* __restrict__ out) {
    int b = blockIdx.x;
    int t = threadIdx.x;
    int lane = t & 63, wave = t >> 6;
    __shared__ float sc[L_];
    __shared__ float red[20];
    __shared__ float part[4][C_];
    __shared__ float pooled[C_];

    float4 wv = *(const float4*)&pw[lane * 4];
    for (int l = wave; l < L_; l += 16) {
        short4v hv = *(const short4v*)&hb[((size_t)b * L_ + l) * C_ + lane * 4];
        float p = bf2f(hv.x) * wv.x + bf2f(hv.y) * wv.y
                + bf2f(hv.z) * wv.z + bf2f(hv.w) * wv.w;
#pragma unroll
        for (int off = 32; off; off >>= 1) p += __shfl_down(p, off);
        if (lane == 0) sc[l] = mask[b * L_ + l] ? (p + pb[0]) : NEGV;
    }
    __syncthreads();

    float v = (t < L_) ? sc[t] : NEGV;
    float mx = v;
#pragma unroll
    for (int off = 32; off; off >>= 1) mx = fmaxf(mx, __shfl_down(mx, off));
    if (lane == 0) red[wave] = mx;
    __syncthreads();
    if (t == 0) {
        float g = red[0];
        for (int i = 1; i < 16; i++) g = fmaxf(g, red[i]);
        red[16] = g;
    }
    __syncthreads();
    float gmax = red[16];
    float e = (t < L_) ? __expf(v - gmax) : 0.f;
    float ssum = e;
#pragma unroll
    for (int off = 32; off; off >>= 1) ssum += __shfl_down(ssum, off);
    if (lane == 0) red[wave] = ssum;
    __syncthreads();
    if (t == 0) {
        float g = 0.f;
        for (int i = 0; i < 16; i++) g += red[i];
        red[17] = 1.f / g;
    }
    __syncthreads();
    if (t < L_) sc[t] = e * red[17];
    __syncthreads();

    int g = t >> 8, c = t & 255;
    const short* hrow = &hb[((size_t)b * L_ + g * 128) * C_ + c];
    const float* scg = &sc[g * 128];
    float a0 = 0.f, a1 = 0.f, a2 = 0.f, a3 = 0.f;
    for (int l = 0; l < 128; l += 4) {
        a0 = fmaf(scg[l + 0], bf2f(hrow[(size_t)(l + 0) * C_]), a0);
        a1 = fmaf(scg[l + 1], bf2f(hrow[(size_t)(l + 1) * C_]), a1);
        a2 = fmaf(scg[l + 2], bf2f(hrow[(size_t)(l + 2) * C_]), a2);
        a3 = fmaf(scg[l + 3], bf2f(hrow[(size_t)(l + 3) * C_]), a3);
    }
    part[g][c] = (a0 + a1) + (a2 + a3);
    __syncthreads();
    if (t < C_) pooled[t] = (part[0][t] + part[1][t]) + (part[2][t] + part[3][t]);
    __syncthreads();

    for (int o = wave; o < 70; o += 16) {
        const float* W = (o < 50) ? (h0W + (size_t)o * C_) : (h1W + (size_t)(o - 50) * C_);
        float bb = (o < 50) ? h0b[o] : h1b[o - 50];
        float4 w4 = *(const float4*)&W[lane * 4];
        float4 p4 = *(const float4*)&pooled[lane * 4];
        float s = p4.x * w4.x + p4.y * w4.y + p4.z * w4.z + p4.w * w4.w;
#pragma unroll
        for (int off = 32; off; off >>= 1) s += __shfl_down(s, off);
        if (lane == 0) out[b * 70 + o] = s + bb;
    }
}

extern "C" void kernel_launch(void* const* d_in, const int* in_sizes, int n_in,
                              void* d_out, int out_size, void* d_ws, size_t ws_size,
                              hipStream_t stream) {
    const int*   x    = (const int*)d_in[0];
    const float* emb  = (const float*)d_in[1];
    const float* pos  = (const float*)d_in[2];
    const float* gpW  = (const float*)d_in[3];
    const float* gpas = (const float*)d_in[4];
    const float* gpad = (const float*)d_in[5];
    const float* gfW  = (const float*)d_in[6];
    const float* gfas = (const float*)d_in[7];
    const float* gfad = (const float*)d_in[8];
    const float* msgW = (const float*)d_in[9];
    const float* msgb = (const float*)d_in[10];
    const float* Wih  = (const float*)d_in[11];
    const float* bih  = (const float*)d_in[12];
    const float* Whh  = (const float*)d_in[13];
    const float* bhh  = (const float*)d_in[14];
    const float* lng  = (const float*)d_in[15];
    const float* lnb  = (const float*)d_in[16];
    const float* pw   = (const float*)d_in[17];
    const float* pb   = (const float*)d_in[18];
    const float* h0W  = (const float*)d_in[19];
    const float* h0b  = (const float*)d_in[20];
    const float* h1W  = (const float*)d_in[21];
    const float* h1b  = (const float*)d_in[22];
    float* out = (float*)d_out;

    // Workspace layout, units MW = 1Mi floats = 4 MiB:
    //   hn2b bf16 [32768, 256] =  4 MW   -> [ 0,  4)
    //   hb   bf16 [32768, 256] =  4 MW   -> [ 8, 12)
    //   mmb  bf16 [32768, 256] =  4 MW   -> [12, 16)   (also Ssd fp32 [32768,16])
    //   hpb2 bf16 [32768, 512] =  8 MW   -> [16, 24)
    //   mb   bf16 [32768, 512] =  8 MW   -> [24, 32)
    //   weights/bias/masks               -> [32, ~33.3)
    const size_t MW = 1024 * 1024;
    float* ws = (float*)d_ws;
    short* hn2b = (short*)ws;
    short* hb   = (short*)(ws + 8 * MW);
    short* mmb  = (short*)(ws + 12 * MW);
    float* Ssd  = ws + 12 * MW;                          // aliases mmb (timeshared)
    short* hpb2 = (short*)(ws + 16 * MW);
    short* mb   = (short*)(ws + 24 * MW);
    short* Wcomb = (short*)(ws + 32 * MW);               // 3*640*256 shorts
    short* msgWb = Wcomb + 3 * 640 * 256;                // 3*256*512 shorts
    short* Bcat  = msgWb + 3 * 256 * 512;                // 3*1024*512 shorts (interleaved)
    float* bias4 = (float*)(Bcat + 3 * 1024 * 512);      // 3*1024 floats
    int* mask    = (int*)(bias4 + 3 * 1024);
    int* logical = mask + B_ * L_;
    int* pol     = logical + B_ * L_;
    int* nvalid  = pol + B_ * L_;

    // weight prep
    prep_wcomb<<<(3 * 640 * 256 + 255) / 256, 256, 0, stream>>>(gpW, gfW, gpas, gpad,
                                                                gfas, gfad, Wcomb);
    f2bf_kernel<<<(3 * 256 * 512 + 255) / 256, 256, 0, stream>>>(msgW, msgWb, 3 * 256 * 512);
    prep_gru_i<<<(3 * 1024 * 512 + 255) / 256, 256, 0, stream>>>(Wih, Whh, Bcat);
    prep_bias4<<<12, 256, 0, stream>>>(bih, bhh, bias4);

    scan_kernel<<<B_, L_, 0, stream>>>(x, mask, logical, pol, nvalid);
    embed_kernel<<<B_ * L_ / 4, 256, 0, stream>>>(x, emb, pos, hb);

    const int DILS[LAY] = {1, 2, 4};

    for (int l = 0; l < LAY; l++) {
        int dil = DILS[l];
        // hpb2 (N=512 bf16) + Ssd (16 fp32 cols), deep 256x128 pipeline (640 blocks)
        projssd_deep<<<640, 512, 0, stream>>>(hb, Wcomb + (size_t)l * 640 * 256,
                                              hpb2, Ssd);
        // sparse GAT aggregation, both dirs in one wave, short8-vectorized
        agg_fused<<<8192, 256, 0, stream>>>(hpb2, Ssd, mask, logical, pol, nvalid, mb, dil);
        // mm = relu(m @ msgW^T + msgb) -> bf16, deep 256x128 pipeline (256 blocks)
        msg_bgemm<<<256, 512, 0, stream>>>(mb, msgWb + (size_t)l * 256 * 512,
                                           mmb, msgb + l * C_);
        // 256x256-tile 8-phase deep-vmcnt GRU GEMM + gate epilogue -> hn2b
        gru_bgemm<<<512, 512, 0, stream>>>(mmb, hb, Bcat + (size_t)l * 1024 * 512,
                                           hn2b, bias4 + l * 1024);
        // LayerNorm + mask -> hb
        ln_kernel<<<8192, 256, 0, stream>>>(hn2b, hb, mask, lng + l * C_, lnb + l * C_);
    }

    pool_head_kernel<<<B_, 1024, 0, stream>>>(hb, mask, pw, pb, h0W, h0b, h1W, h1b, out);
}

// Round 6
// 483.387 us; speedup vs baseline: 1.1700x; 1.0177x over previous
//
#include <hip/hip_runtime.h>
#include <math.h>

#define B_ 64
#define L_ 512
#define C_ 256
#define H_ 4
#define LAY 3
#define NEGV -1e9f

typedef __attribute__((ext_vector_type(8))) short short8;
typedef __attribute__((ext_vector_type(4))) short short4v;
typedef __attribute__((ext_vector_type(4))) float floatx4;

static __device__ __forceinline__ float rcp_(float x) { return __builtin_amdgcn_rcpf(x); }
static __device__ __forceinline__ float sig_(float x) { return rcp_(1.f + __expf(-x)); }
static __device__ __forceinline__ float tanh_(float x) {
    float e = __expf(2.f * x);
    return 1.f - 2.f * rcp_(e + 1.f);
}

static __device__ __forceinline__ short f2bf(float f) {
    unsigned x = __float_as_uint(f);
    x += 0x7fffu + ((x >> 16) & 1u);       // round-to-nearest-even to bf16
    return (short)(x >> 16);
}
static __device__ __forceinline__ float bf2f(short s) {
    return __uint_as_float(((unsigned)(unsigned short)s) << 16);
}

// XCD-aligned token swizzle for elementwise consumers (matches GEMM rb%8 = XCD).
static __device__ __forceinline__ int tok_swizzle(int blk) {
    int c8 = blk & 7, i = blk >> 3;
    return (c8 + 8 * (i >> 5)) * 128 + (i & 31) * 4;
}

static __device__ __forceinline__ void gl_lds16(const short* g, short* l) {
    __builtin_amdgcn_global_load_lds(
        (const __attribute__((address_space(1))) unsigned int*)g,
        (__attribute__((address_space(3))) unsigned int*)l, 16, 0, 0);
}

#define CF() asm volatile("" ::: "memory")

// ---------------- merged weight prep + output zeroing (1 dispatch) ----------------
// Ranges: [0,n0) Wcomb; [n0,n0+n1) msgWb; [..+n2) Bcat; [..+n3) bias4; [..+n4) out=0.
#define PR_N0 (3 * 640 * 256)
#define PR_N1 (3 * 256 * 512)
#define PR_N2 (3 * 1024 * 512)
#define PR_N3 (3 * 1024)
#define PR_N4 (B_ * 70)
#define PR_TOT (PR_N0 + PR_N1 + PR_N2 + PR_N3 + PR_N4)

__global__ void prep_all(const float* __restrict__ gpW, const float* __restrict__ gfW,
                         const float* __restrict__ gpas, const float* __restrict__ gpad,
                         const float* __restrict__ gfas, const float* __restrict__ gfad,
                         const float* __restrict__ msgW,
                         const float* __restrict__ Wih, const float* __restrict__ Whh,
                         const float* __restrict__ bih, const float* __restrict__ bhh,
                         short* __restrict__ Wc, short* __restrict__ msgWb,
                         short* __restrict__ Bc, float* __restrict__ bias4,
                         float* __restrict__ outz) {
    int i = blockIdx.x * 256 + threadIdx.x;
    if (i < PR_N0) {
        // Wcomb[l][640][256]: rows 0..255 gpW, 256..511 gfW, 512..527 a@W, rest 0
        int k = i & 255;
        int r = (i >> 8) % 640;
        int l = i / (640 * 256);
        float v = 0.f;
        if (r < 256) {
            v = gpW[((size_t)l * 256 + r) * 256 + k];
        } else if (r < 512) {
            v = gfW[((size_t)l * 256 + (r - 256)) * 256 + k];
        } else {
            int n = r - 512;
            if (n < 16) {
                int type = n >> 3, dir = (n >> 2) & 1, hh = n & 3;
                const float* a = type ? (dir ? gfad : gpad) : (dir ? gfas : gpas);
                const float* W = dir ? gfW : gpW;
                for (int j = 0; j < 64; j++) {
                    float av = a[l * 256 + hh * 64 + j];
                    float wv = W[((size_t)l * 256 + hh * 64 + j) * 256 + k];
                    v = fmaf(av, wv, v);
                }
            }
        }
        Wc[i] = f2bf(v);
        return;
    }
    i -= PR_N0;
    if (i < PR_N1) { msgWb[i] = f2bf(msgW[i]); return; }
    i -= PR_N1;
    if (i < PR_N2) {
        // Bcat interleaved: Bc[l][n'][512], n' = 4*ch+g, g in {0:r,1:z,2:i,3:n}
        int k = i & 511, np = (i >> 9) & 1023, l = i >> 19;
        int ch = np >> 2, g = np & 3;
        float v = 0.f;
        if (g < 2) {
            v = (k < 256) ? Wih[((size_t)l * 768 + g * 256 + ch) * 256 + k]
                          : Whh[((size_t)l * 768 + g * 256 + ch) * 256 + (k - 256)];
        } else if (g == 2) {
            if (k < 256) v = Wih[((size_t)l * 768 + 512 + ch) * 256 + k];
        } else {
            if (k >= 256) v = Whh[((size_t)l * 768 + 512 + ch) * 256 + (k - 256)];
        }
        Bc[i] = f2bf(v);
        return;
    }
    i -= PR_N2;
    if (i < PR_N3) {
        int np = i & 1023, l = i >> 10;
        int ch = np >> 2, g = np & 3;
        float v;
        if (g < 2)       v = bih[l * 768 + g * 256 + ch] + bhh[l * 768 + g * 256 + ch];
        else if (g == 2) v = bih[l * 768 + 512 + ch];
        else             v = bhh[l * 768 + 512 + ch];
        bias4[i] = v;
        return;
    }
    i -= PR_N3;
    if (i < PR_N4) outz[i] = 0.f;
}

// ---------------- fused scan (64 blocks) + embed (4096 blocks x 8 tokens) ----------
__global__ __launch_bounds__(512) void scan_embed(
    const int* __restrict__ x, const float* __restrict__ emb,
    const float* __restrict__ pos, short* __restrict__ hb,
    int* __restrict__ mask, int* __restrict__ logical,
    int* __restrict__ pol, int* __restrict__ nvalid) {
    if (blockIdx.x < 64) {
        // mask / logical-position scan + pos_of_logical
        int b = blockIdx.x, t = threadIdx.x;
        __shared__ int s[L_];
        int m = (x[b * L_ + t] != 0) ? 1 : 0;
        s[t] = m;
        __syncthreads();
        for (int off = 1; off < L_; off <<= 1) {
            int v = (t >= off) ? s[t - off] : 0;
            __syncthreads();
            s[t] += v;
            __syncthreads();
        }
        int cum = s[t];
        int lg = cum - 1; if (lg < 0) lg = 0;
        mask[b * L_ + t] = m;
        logical[b * L_ + t] = lg;
        if (m) pol[b * L_ + lg] = t;
        if (t == L_ - 1) nvalid[b] = cum;
    } else {
        // hb = bf16((emb[x] + pos*mf)*mf), 8 tokens per block (2 virtual sub-blocks)
        int t = threadIdx.x & 255, sub = threadIdx.x >> 8;
        int blk2 = (blockIdx.x - 64) * 2 + sub;
        int bl = tok_swizzle(blk2) + (t >> 6);
        int lane = t & 63;
        int xv = x[bl];
        float mf = (xv != 0) ? 1.f : 0.f;
        int l = bl & (L_ - 1);
        float4 e = *(const float4*)&emb[(size_t)xv * C_ + lane * 4];
        float4 p = *(const float4*)&pos[(size_t)l * C_ + lane * 4];
        short4v hv4;
        hv4.x = f2bf((e.x + p.x * mf) * mf);
        hv4.y = f2bf((e.y + p.y * mf) * mf);
        hv4.z = f2bf((e.z + p.z * mf) * mf);
        hv4.w = f2bf((e.w + p.w * mf) * mf);
        *(short4v*)&hb[(size_t)bl * C_ + lane * 4] = hv4;
    }
}

// ---------------- deep-GEMM fragment helpers (shared) ----------
static __device__ __forceinline__ short8 lds_rd8(const short* p) {
    return *(const short8*)p;
}

template <int MH>
static __device__ __forceinline__ void ld_af(const short* bufA, int wm, int q, int t16,
                                             short8 af[4][2]) {
#pragma unroll
    for (int mfl = 0; mfl < 4; ++mfl) {
        int row = wm * 128 + (MH * 4 + mfl) * 16 + t16;
#pragma unroll
        for (int ks = 0; ks < 2; ++ks) {
            int cg = (ks * 4 + q) ^ (row & 7);
            af[mfl][ks] = lds_rd8(&bufA[row * 64 + cg * 8]);
        }
    }
}

template <int NH>
static __device__ __forceinline__ void ld_bf(const short* bufB, int wn, int q, int t16,
                                             short8 bf[2][2]) {
#pragma unroll
    for (int nfl = 0; nfl < 2; ++nfl) {
        int row = wn * 64 + (NH * 2 + nfl) * 16 + t16;
#pragma unroll
        for (int ks = 0; ks < 2; ++ks) {
            int cg = (ks * 4 + q) ^ (row & 7);
            bf[nfl][ks] = lds_rd8(&bufB[row * 64 + cg * 8]);
        }
    }
}

// B fragment read for BN=128 (wave covers 32 cols): rows wn*32 + nfl*16 + t16
static __device__ __forceinline__ void ld_bf32(const short* bufB, int wn, int q, int t16,
                                               short8 bf[2][2]) {
#pragma unroll
    for (int nfl = 0; nfl < 2; ++nfl) {
        int row = wn * 32 + nfl * 16 + t16;
#pragma unroll
        for (int ks = 0; ks < 2; ++ks) {
            int cg = (ks * 4 + q) ^ (row & 7);
            bf[nfl][ks] = lds_rd8(&bufB[row * 64 + cg * 8]);
        }
    }
}

template <int MH, int NH>
static __device__ __forceinline__ void mfma_q(const short8 af[4][2], const short8 bf[2][2],
                                              floatx4 acc[4][8]) {
    __builtin_amdgcn_s_setprio(1);
#pragma unroll
    for (int ks = 0; ks < 2; ++ks)
#pragma unroll
        for (int mfl = 0; mfl < 4; ++mfl)
#pragma unroll
            for (int nfl = 0; nfl < 2; ++nfl)
                acc[NH * 2 + nfl][MH * 4 + mfl] = __builtin_amdgcn_mfma_f32_16x16x32_bf16(
                    bf[nfl][ks], af[mfl][ks], acc[NH * 2 + nfl][MH * 4 + mfl], 0, 0, 0);
    __builtin_amdgcn_s_setprio(0);
}

template <int MH>
static __device__ __forceinline__ void mfma_m(const short8 af[4][2], const short8 bf[2][2],
                                              floatx4 acc[2][8]) {
    __builtin_amdgcn_s_setprio(1);
#pragma unroll
    for (int ks = 0; ks < 2; ++ks)
#pragma unroll
        for (int mfl = 0; mfl < 4; ++mfl)
#pragma unroll
            for (int nfl = 0; nfl < 2; ++nfl)
                acc[nfl][MH * 4 + mfl] = __builtin_amdgcn_mfma_f32_16x16x32_bf16(
                    bf[nfl][ks], af[mfl][ks], acc[nfl][MH * 4 + mfl], 0, 0, 0);
    __builtin_amdgcn_s_setprio(0);
}

// ---------------- projection + Ssd GEMM, deep 256x128 pipeline ----------
// A = hb [32768,256] K=256 (4 K-tiles), B = Wcomb [640,256] as 5 cb of 128 rows.
// cb 0..3 -> hpb2 bf16 (ldc 512); cb 4 -> Ssd fp32 (16 real cols).
// Grid 640 = 8 XCD x 16 rb x 5 cb (XCD-coherent: one A-panel range per XCD).
__global__ __launch_bounds__(512, 2) void projssd_deep(const short* __restrict__ A0,
                                                       const short* __restrict__ Bw,
                                                       short* __restrict__ hpb2,
                                                       float* __restrict__ Ssd) {
    __shared__ short lds[2][24576];   // per buf: A[256][64] @0, B[128][64] @16384
    const int id = blockIdx.x;
    const int j = id >> 3;                       // 0..79
    const int cb = j >> 4;                       // 0..4
    const int rb = (id & 7) * 16 + (j & 15);     // 0..127
    const int tid = threadIdx.x;
    const int wave = tid >> 6, lane = tid & 63;
    const int wm = wave >> 2, wn = wave & 3;
    const int q = lane >> 4, t16 = lane & 15;
    const size_t arow0 = (size_t)rb * 256;
    const short* Bb = Bw + (size_t)cb * 128 * 256;

    floatx4 acc[2][8];
#pragma unroll
    for (int i = 0; i < 2; i++)
#pragma unroll
        for (int jj = 0; jj < 8; jj++) acc[i][jj] = (floatx4)0.f;

    auto stageA = [&](int t, int Hh) {
        short* bufA = lds[t & 1];
#pragma unroll
        for (int u = 0; u < 2; ++u) {
            int unit = u * 512 + tid;
            int row = Hh * 128 + (unit >> 3);
            int cs = (unit & 7) ^ (row & 7);
            gl_lds16(A0 + (arow0 + (size_t)row) * 256 + t * 64 + cs * 8,
                     bufA + Hh * 8192 + unit * 8);
        }
    };
    auto stageB = [&](int t) {
        short* bufB = lds[t & 1] + 16384;
#pragma unroll
        for (int u = 0; u < 2; ++u) {
            int unit = u * 512 + tid;
            int row = unit >> 3;                 // 0..127
            int cs = (unit & 7) ^ (row & 7);
            gl_lds16(Bb + (size_t)row * 256 + t * 64 + cs * 8, bufB + unit * 8);
        }
    };

    // prologue: A(0)+B(0)+B(1); vmcnt(2): tile0 complete, B(1) in flight
    stageA(0, 0); stageA(0, 1); stageB(0); stageB(1);
    asm volatile("s_waitcnt vmcnt(2)" ::: "memory");
    CF(); __builtin_amdgcn_s_barrier(); CF();

    short8 af[4][2], bfr[2][2];

#pragma unroll
    for (int t = 0; t < 4; ++t) {
        const short* bufA = lds[t & 1];
        const short* bufB = lds[t & 1] + 16384;

        // ---- P0 ----
        ld_af<0>(bufA, wm, q, t16, af);
        ld_bf32(bufB, wn, q, t16, bfr);
        if (t < 3) { stageA(t + 1, 0); stageA(t + 1, 1); }
        CF(); __builtin_amdgcn_s_barrier();
        asm volatile("s_waitcnt lgkmcnt(0)" ::: "memory");
        __builtin_amdgcn_sched_barrier(0);
        mfma_m<0>(af, bfr, acc);
        CF(); __builtin_amdgcn_s_barrier(); CF();

        // ---- P1 ----  (bufB[t&1] free after P0's end barrier)
        ld_af<1>(bufA, wm, q, t16, af);
        if (t < 2) stageB(t + 2);
        CF(); __builtin_amdgcn_s_barrier();
        asm volatile("s_waitcnt lgkmcnt(0)" ::: "memory");
        __builtin_amdgcn_sched_barrier(0);
        mfma_m<1>(af, bfr, acc);
        if (t < 2)       asm volatile("s_waitcnt vmcnt(2)" ::: "memory");
        else if (t == 2) asm volatile("s_waitcnt vmcnt(0)" ::: "memory");
        CF(); __builtin_amdgcn_s_barrier(); CF();
    }

    if (cb < 4) {
        // bf16 -> hpb2 (ldc 512), LDS-staged coalesced write
        short* sO = (short*)lds;                 // [256][132]
#pragma unroll
        for (int nf = 0; nf < 2; nf++) {
            int chl = wn * 32 + nf * 16 + q * 4; // 0..127 within block
#pragma unroll
            for (int mf = 0; mf < 8; mf++) {
                int rowl = wm * 128 + mf * 16 + t16;
                short4v pk;
                pk.x = f2bf(acc[nf][mf][0]);
                pk.y = f2bf(acc[nf][mf][1]);
                pk.z = f2bf(acc[nf][mf][2]);
                pk.w = f2bf(acc[nf][mf][3]);
                *(short4v*)&sO[rowl * 132 + chl] = pk;
            }
        }
        __syncthreads();
#pragma unroll
        for (int it = 0; it < 8; ++it) {
            int unit = it * 512 + tid;
            int rowl = unit >> 4, ck = unit & 15;
            *(short8*)&hpb2[(arow0 + rowl) * 512 + cb * 128 + ck * 8] =
                *(const short8*)&sO[rowl * 132 + ck * 8];
        }
    } else {
        // Ssd fp32: only cols 0..15 real (wn==0, nf==0)
        if (wn == 0) {
            int chl = q * 4;
            if (chl < 16) {
#pragma unroll
                for (int mf = 0; mf < 8; mf++) {
                    int rowl = wm * 128 + mf * 16 + t16;
                    float4 pk = make_float4(acc[0][mf][0], acc[0][mf][1],
                                            acc[0][mf][2], acc[0][mf][3]);
                    *(float4*)&Ssd[(arow0 + rowl) * 16 + chl] = pk;
                }
            }
        }
    }
}

// ---------------- dedicated GRU GEMM, 256x256 tile, 8-phase deep-vmcnt ----------
// (round-3 schedule: full unroll + sched_barrier(0) after lgkm)
__global__ __launch_bounds__(512, 2) void gru_bgemm(const short* __restrict__ mmb,
                                                    const short* __restrict__ hb_in,
                                                    const short* __restrict__ Bw,
                                                    short* __restrict__ hn2b,
                                                    const float* __restrict__ bias4) {
    __shared__ short lds[2][32768];   // per buf: A[256][64] @0, B[256][64] @16384
    const int id = blockIdx.x;
    const int rb = 16 * (id & 7) + (id >> 5);
    const int cb = (id >> 3) & 3;
    const int tid = threadIdx.x;
    const int wave = tid >> 6, lane = tid & 63;
    const int wm = wave >> 2, wn = wave & 3;
    const int q = lane >> 4, t16 = lane & 15;
    const size_t arow0 = (size_t)rb * 256;
    const short* Bb = Bw + (size_t)cb * 256 * 512;
    const int ord0 = (5 + cb) & 7;

    floatx4 acc[4][8];   // [nf][mf]
#pragma unroll
    for (int i = 0; i < 4; i++)
#pragma unroll
        for (int jj = 0; jj < 8; jj++) acc[i][jj] = (floatx4)0.f;

    auto stageA = [&](int i, int Hh) {
        int tt = (ord0 + i) & 7;
        const short* Asrc = (tt < 4) ? (mmb + tt * 64) : (hb_in + (tt - 4) * 64);
        short* bufA = lds[i & 1];
#pragma unroll
        for (int u = 0; u < 2; ++u) {
            int unit = u * 512 + tid;              // 0..1023
            int row = Hh * 128 + (unit >> 3);
            int cs = (unit & 7) ^ (row & 7);
            gl_lds16(Asrc + (arow0 + (size_t)row) * 256 + cs * 8,
                     bufA + Hh * 8192 + unit * 8);
        }
    };
    auto stageB = [&](int i, int Hh) {
        int tt = (ord0 + i) & 7;
        short* bufB = lds[i & 1] + 16384;
#pragma unroll
        for (int u = 0; u < 2; ++u) {
            int unit = u * 512 + tid;
            int row = Hh * 128 + (unit >> 3);
            int cs = (unit & 7) ^ (row & 7);
            gl_lds16(Bb + (size_t)row * 512 + tt * 64 + cs * 8,
                     bufB + Hh * 8192 + unit * 8);
        }
    };

    // prologue: tiles 0 and 1 fully issued (16 loads/wave);
    // vmcnt(8): tile 0 complete, tile 1's 8 loads stay in flight
    stageA(0, 0); stageA(0, 1); stageB(0, 0); stageB(0, 1);
    stageA(1, 0); stageA(1, 1); stageB(1, 0); stageB(1, 1);
    asm volatile("s_waitcnt vmcnt(8)" ::: "memory");
    CF(); __builtin_amdgcn_s_barrier(); CF();

    short8 af[4][2], b0[2][2], b1[2][2];

#pragma unroll
    for (int t = 0; t < 8; ++t) {
        const short* bufA = lds[t & 1];
        const short* bufB = lds[t & 1] + 16384;

        // ---- P0: quadrant (0,0) ----
        ld_af<0>(bufA, wm, q, t16, af);
        ld_bf<0>(bufB, wn, q, t16, b0);
        CF(); __builtin_amdgcn_s_barrier();
        asm volatile("s_waitcnt lgkmcnt(0)" ::: "memory");
        __builtin_amdgcn_sched_barrier(0);
        mfma_q<0, 0>(af, b0, acc);
        CF(); __builtin_amdgcn_s_barrier(); CF();

        // ---- P1: quadrant (0,1) ----
        ld_bf<1>(bufB, wn, q, t16, b1);
        CF(); __builtin_amdgcn_s_barrier();
        asm volatile("s_waitcnt lgkmcnt(0)" ::: "memory");
        __builtin_amdgcn_sched_barrier(0);
        mfma_q<0, 1>(af, b1, acc);
        CF(); __builtin_amdgcn_s_barrier(); CF();

        // ---- P2: quadrant (1,1) ----  (bufB[t&1] free after P1's end barrier)
        ld_af<1>(bufA, wm, q, t16, af);
        if (t < 6) { stageB(t + 2, 0); stageB(t + 2, 1); }
        CF(); __builtin_amdgcn_s_barrier();
        asm volatile("s_waitcnt lgkmcnt(0)" ::: "memory");
        __builtin_amdgcn_sched_barrier(0);
        mfma_q<1, 1>(af, b1, acc);
        CF(); __builtin_amdgcn_s_barrier(); CF();

        // ---- P3: quadrant (1,0) ----  (bufA[t&1] free after P2's end barrier)
        if (t < 6) { stageA(t + 2, 0); stageA(t + 2, 1); }
        CF(); __builtin_amdgcn_s_barrier();
        mfma_q<1, 0>(af, b0, acc);
        // tile boundary: su(t+1) (oldest 8) complete; su(t+2) (8) stay in flight
        if (t < 6)       asm volatile("s_waitcnt vmcnt(8)" ::: "memory");
        else if (t == 6) asm volatile("s_waitcnt vmcnt(0)" ::: "memory");
        CF(); __builtin_amdgcn_s_barrier(); CF();
    }

    // epilogue: h_prev from LDS (lds[1] holds A-tile of tt=4+cb = hb cols cb*64..),
    // compute gates, stage hn2 tile in LDS, coalesced bf16 write.
    const short* hpt = lds[1];
    short* sO = (short*)lds;                   // [256][72] bf16 within lds[0]
#pragma unroll
    for (int nf = 0; nf < 4; nf++) {
        int chl = wn * 16 + nf * 4 + q;        // 0..63 within block
        int col0 = cb * 256 + wn * 64 + nf * 16 + q * 4;
        float4 bv4 = *(const float4*)&bias4[col0];
#pragma unroll
        for (int mf = 0; mf < 8; mf++) {
            int rowl = wm * 128 + mf * 16 + t16;
            float hp = bf2f(hpt[rowl * 64 + (((chl >> 3) ^ (rowl & 7)) << 3) + (chl & 7)]);
            float r = sig_(acc[nf][mf][0] + bv4.x);
            float z = sig_(acc[nf][mf][1] + bv4.y);
            float nv = tanh_((acc[nf][mf][2] + bv4.z) + r * (acc[nf][mf][3] + bv4.w));
            sO[rowl * 72 + chl] = f2bf((1.f - z) * nv + z * hp);
        }
    }
    __syncthreads();
#pragma unroll
    for (int it = 0; it < 4; ++it) {
        int unit = it * 512 + tid;
        int rowl = unit >> 3, ck = unit & 7;
        *(short8*)&hn2b[(arow0 + rowl) * 256 + cb * 64 + ck * 8] =
            *(const short8*)&sO[rowl * 72 + ck * 8];
    }
}

// ---------------- msg GEMM, 256x128 tile, deep pipeline ----------
__global__ __launch_bounds__(512, 2) void msg_bgemm(const short* __restrict__ A0,
                                                    const short* __restrict__ Bw,
                                                    short* __restrict__ Cout,
                                                    const float* __restrict__ bias) {
    __shared__ short lds[2][24576];   // per buf: A[256][64] @0, B[128][64] @16384
    const int id = blockIdx.x;
    const int j = id >> 3;                       // 0..31
    const int rb = (id & 7) * 16 + (j & 15);     // 0..127
    const int cb = j >> 4;                       // 0..1
    const int tid = threadIdx.x;
    const int wave = tid >> 6, lane = tid & 63;
    const int wm = wave >> 2, wn = wave & 3;
    const int q = lane >> 4, t16 = lane & 15;
    const size_t arow0 = (size_t)rb * 256;
    const short* Bb = Bw + (size_t)cb * 128 * 512;

    floatx4 acc[2][8];
#pragma unroll
    for (int i = 0; i < 2; i++)
#pragma unroll
        for (int jj = 0; jj < 8; jj++) acc[i][jj] = (floatx4)0.f;

    auto stageA = [&](int t, int Hh) {
        short* bufA = lds[t & 1];
#pragma unroll
        for (int u = 0; u < 2; ++u) {
            int unit = u * 512 + tid;
            int row = Hh * 128 + (unit >> 3);
            int cs = (unit & 7) ^ (row & 7);
            gl_lds16(A0 + (arow0 + (size_t)row) * 512 + t * 64 + cs * 8,
                     bufA + Hh * 8192 + unit * 8);
        }
    };
    auto stageB = [&](int t) {
        short* bufB = lds[t & 1] + 16384;
#pragma unroll
        for (int u = 0; u < 2; ++u) {
            int unit = u * 512 + tid;
            int row = unit >> 3;                 // 0..127
            int cs = (unit & 7) ^ (row & 7);
            gl_lds16(Bb + (size_t)row * 512 + t * 64 + cs * 8, bufB + unit * 8);
        }
    };

    // prologue: A(0)+B(0)+B(1); vmcnt(2): tile0 complete, B(1) in flight
    stageA(0, 0); stageA(0, 1); stageB(0); stageB(1);
    asm volatile("s_waitcnt vmcnt(2)" ::: "memory");
    CF(); __builtin_amdgcn_s_barrier(); CF();

    short8 af[4][2], bfr[2][2];

#pragma unroll 2
    for (int t = 0; t < 8; ++t) {
        const short* bufA = lds[t & 1];
        const short* bufB = lds[t & 1] + 16384;

        // ---- P0 ----
        ld_af<0>(bufA, wm, q, t16, af);
        ld_bf32(bufB, wn, q, t16, bfr);
        if (t < 7) { stageA(t + 1, 0); stageA(t + 1, 1); }
        CF(); __builtin_amdgcn_s_barrier();
        asm volatile("s_waitcnt lgkmcnt(0)" ::: "memory");
        mfma_m<0>(af, bfr, acc);
        CF(); __builtin_amdgcn_s_barrier(); CF();

        // ---- P1 ----  (bufB[t&1] free after P0's end barrier)
        ld_af<1>(bufA, wm, q, t16, af);
        if (t < 6) stageB(t + 2);
        CF(); __builtin_amdgcn_s_barrier();
        asm volatile("s_waitcnt lgkmcnt(0)" ::: "memory");
        mfma_m<1>(af, bfr, acc);
        if (t < 6)       asm volatile("s_waitcnt vmcnt(2)" ::: "memory");
        else if (t == 6) asm volatile("s_waitcnt vmcnt(0)" ::: "memory");
        CF(); __builtin_amdgcn_s_barrier(); CF();
    }

    // epilogue: bias + relu + bf16, LDS-staged coalesced write
    short* sO = (short*)lds;                     // [256][132]
#pragma unroll
    for (int nf = 0; nf < 2; nf++) {
        int chl = wn * 32 + nf * 16 + q * 4;     // 0..127 within block
        int col0 = cb * 128 + chl;
        float4 bv4 = *(const float4*)&bias[col0];
#pragma unroll
        for (int mf = 0; mf < 8; mf++) {
            int rowl = wm * 128 + mf * 16 + t16;
            short4v pk;
            pk.x = f2bf(fmaxf(acc[nf][mf][0] + bv4.x, 0.f));
            pk.y = f2bf(fmaxf(acc[nf][mf][1] + bv4.y, 0.f));
            pk.z = f2bf(fmaxf(acc[nf][mf][2] + bv4.z, 0.f));
            pk.w = f2bf(fmaxf(acc[nf][mf][3] + bv4.w, 0.f));
            *(short4v*)&sO[rowl * 132 + chl] = pk;
        }
    }
    __syncthreads();
#pragma unroll
    for (int it = 0; it < 8; ++it) {
        int unit = it * 512 + tid;
        int rowl = unit >> 4, ck = unit & 15;
        *(short8*)&Cout[(arow0 + rowl) * 256 + cb * 128 + ck * 8] =
            *(const short8*)&sO[rowl * 132 + ck * 8];
    }
}

// ---------------- LayerNorm over hn2 (bf16) + mask -> hb ----------------
__global__ __launch_bounds__(256) void ln_kernel(
    const short* __restrict__ hn2b, short* __restrict__ hb,
    const int* __restrict__ mask,
    const float* __restrict__ lng, const float* __restrict__ lnb) {
    int t = threadIdx.x;
    int bl = tok_swizzle(blockIdx.x) + (t >> 6);
    int lane = t & 63;
    short4v v4 = *(const short4v*)&hn2b[(size_t)bl * C_ + lane * 4];
    float v[4] = {bf2f(v4.x), bf2f(v4.y), bf2f(v4.z), bf2f(v4.w)};
    float s = (v[0] + v[1]) + (v[2] + v[3]);
    float ss = (v[0] * v[0] + v[1] * v[1]) + (v[2] * v[2] + v[3] * v[3]);
#pragma unroll
    for (int off = 32; off; off >>= 1) {
        s += __shfl_xor(s, off);
        ss += __shfl_xor(ss, off);
    }
    float mu = s * (1.f / 256.f);
    float var = ss * (1.f / 256.f) - mu * mu;
    float rstd = rsqrtf(fmaxf(var, 0.f) + 1e-5f);
    float4 lg = *(const float4*)&lng[lane * 4];
    float4 lb = *(const float4*)&lnb[lane * 4];
    float mfv = mask[bl] ? 1.f : 0.f;
    short4v yb;
    yb.x = f2bf(((v[0] - mu) * rstd * lg.x + lb.x) * mfv);
    yb.y = f2bf(((v[1] - mu) * rstd * lg.y + lb.y) * mfv);
    yb.z = f2bf(((v[2] - mu) * rstd * lg.z + lb.z) * mfv);
    yb.w = f2bf(((v[3] - mu) * rstd * lg.w + lb.w) * mfv);
    *(short4v*)&hb[(size_t)bl * C_ + lane * 4] = yb;
}

// ---------------- sparse GAT aggregation, vectorized short8, both dirs ----------------
__global__ __launch_bounds__(256) void agg_fused(
    const short* __restrict__ hpb2, const float* __restrict__ S,
    const int* __restrict__ mask, const int* __restrict__ logical,
    const int* __restrict__ pol, const int* __restrict__ nvalid,
    short* __restrict__ m, int dil) {
    int t = threadIdx.x;
    int bl = tok_swizzle(blockIdx.x) + (t >> 6);
    int sub = t & 63;
    int dir = sub >> 5;
    int slot = sub & 31;
    int cb = slot * 8;
    int head = slot >> 3;
    int b = bl >> 9;

    int mi = mask[bl];
    int li = logical[bl];
    int nv = nvalid[b];
    int js[3]; int nn = 0;
    if (mi) {
#pragma unroll
        for (int k = 1; k <= 3; k++) {
            int lj = dir ? (li - k * dil) : (li + k * dil);
            if (lj >= 0 && lj < nv) js[nn++] = pol[b * L_ + lj];
        }
    }
    int sn = dir * 4 + head, dn = 8 + sn;
    float si = S[(size_t)bl * 16 + sn];
    float di = S[(size_t)bl * 16 + dn];
    float e0 = si + di; e0 = e0 > 0.f ? e0 : 0.2f * e0;
    float emax = e0, ev[3];
    for (int k = 0; k < nn; k++) {
        float djv = S[((size_t)(b * L_ + js[k])) * 16 + dn];
        float e = si + djv; e = e > 0.f ? e : 0.2f * e;
        ev[k] = e; emax = fmaxf(emax, e);
    }
    float w0 = __expf(e0 - emax), den = w0;
    float wv[3];
    for (int k = 0; k < nn; k++) { wv[k] = __expf(ev[k] - emax); den += wv[k]; }
    float rden = rcp_(den);

    size_t base = (size_t)bl * 512 + dir * 256 + cb;
    short8 vself = *(const short8*)&hpb2[base];
    float o[8];
#pragma unroll
    for (int j = 0; j < 8; j++) o[j] = w0 * bf2f(vself[j]);
    for (int k = 0; k < nn; k++) {
        short8 vn = *(const short8*)&hpb2[((size_t)(b * L_ + js[k])) * 512 + dir * 256 + cb];
#pragma unroll
        for (int j = 0; j < 8; j++) o[j] = fmaf(wv[k], bf2f(vn[j]), o[j]);
    }
    short8 ov;
#pragma unroll
    for (int j = 0; j < 8; j++) ov[j] = f2bf(o[j] * rden);
    *(short8*)&m[base] = ov;
}

// ---------------- masked softmax pooling + heads, 4 slices per batch ----------------
// Grid 256 = b*4 + s. Each block: full score pass (L2-hot after slice 0),
// softmax (redundant, cheap), weighted sum over its 64-ch slice, head partials
// via device-scope atomicAdd (out zeroed by prep_all each iteration).
__global__ __launch_bounds__(1024) void pool_head2(
    const short* __restrict__ hb, const int* __restrict__ mask,
    const float* __restrict__ pw, const float* __restrict__ pb,
    const float* __restrict__ h0W, const float* __restrict__ h0b,
    const float* __restrict__ h1W, const float* __restrict__ h1b,
    float* __restrict__ out) {
    int b = blockIdx.x >> 2, s = blockIdx.x & 3;
    int t = threadIdx.x;
    int lane = t & 63, wave = t >> 6;
    __shared__ float sc[L_];
    __shared__ float red[20];
    __shared__ float part[16][64];
    __shared__ float pooled[64];

    // pass 1: scores
    float4 wv = *(const float4*)&pw[lane * 4];
    for (int l = wave; l < L_; l += 16) {
        short4v hv = *(const short4v*)&hb[((size_t)b * L_ + l) * C_ + lane * 4];
        float p = bf2f(hv.x) * wv.x + bf2f(hv.y) * wv.y
                + bf2f(hv.z) * wv.z + bf2f(hv.w) * wv.w;
#pragma unroll
        for (int off = 32; off; off >>= 1) p += __shfl_down(p, off);
        if (lane == 0) sc[l] = mask[b * L_ + l] ? (p + pb[0]) : NEGV;
    }
    __syncthreads();

    // softmax over 512
    float v = (t < L_) ? sc[t] : NEGV;
    float mx = v;
#pragma unroll
    for (int off = 32; off; off >>= 1) mx = fmaxf(mx, __shfl_down(mx, off));
    if (lane == 0) red[wave] = mx;
    __syncthreads();
    if (t == 0) {
        float g = red[0];
        for (int i = 1; i < 16; i++) g = fmaxf(g, red[i]);
        red[16] = g;
    }
    __syncthreads();
    float gmax = red[16];
    float e = (t < L_) ? __expf(v - gmax) : 0.f;
    float ssum = e;
#pragma unroll
    for (int off = 32; off; off >>= 1) ssum += __shfl_down(ssum, off);
    if (lane == 0) red[wave] = ssum;
    __syncthreads();
    if (t == 0) {
        float g = 0.f;
        for (int i = 0; i < 16; i++) g += red[i];
        red[17] = 1.f / g;
    }
    __syncthreads();
    if (t < L_) sc[t] = e * red[17];
    __syncthreads();

    // pass 2: weighted sum over channels [s*64, s*64+64); 16 l-groups x 64 ch
    {
        int c0 = t & 63, lw = t >> 6;
        const short* hcol = &hb[((size_t)b * L_ + lw * 32) * C_ + s * 64 + c0];
        const float* scg = &sc[lw * 32];
        float a0 = 0.f, a1 = 0.f;
        for (int l = 0; l < 32; l += 2) {
            a0 = fmaf(scg[l + 0], bf2f(hcol[(size_t)(l + 0) * C_]), a0);
            a1 = fmaf(scg[l + 1], bf2f(hcol[(size_t)(l + 1) * C_]), a1);
        }
        part[lw][c0] = a0 + a1;
    }
    __syncthreads();
    if (t < 64) {
        float p = 0.f;
        for (int i = 0; i < 16; i++) p += part[i][t];
        pooled[t] = p;
    }
    __syncthreads();

    // pass 3: head partials over this 64-ch slice, atomicAdd to out
    for (int o = wave; o < 70; o += 16) {
        const float* W = (o < 50) ? (h0W + (size_t)o * C_) : (h1W + (size_t)(o - 50) * C_);
        float sv = pooled[lane] * W[s * 64 + lane];
#pragma unroll
        for (int off = 32; off; off >>= 1) sv += __shfl_down(sv, off);
        if (lane == 0) {
            float add = sv + ((s == 0) ? ((o < 50) ? h0b[o] : h1b[o - 50]) : 0.f);
            atomicAdd(&out[b * 70 + o], add);
        }
    }
}

extern "C" void kernel_launch(void* const* d_in, const int* in_sizes, int n_in,
                              void* d_out, int out_size, void* d_ws, size_t ws_size,
                              hipStream_t stream) {
    const int*   x    = (const int*)d_in[0];
    const float* emb  = (const float*)d_in[1];
    const float* pos  = (const float*)d_in[2];
    const float* gpW  = (const float*)d_in[3];
    const float* gpas = (const float*)d_in[4];
    const float* gpad = (const float*)d_in[5];
    const float* gfW  = (const float*)d_in[6];
    const float* gfas = (const float*)d_in[7];
    const float* gfad = (const float*)d_in[8];
    const float* msgW = (const float*)d_in[9];
    const float* msgb = (const float*)d_in[10];
    const float* Wih  = (const float*)d_in[11];
    const float* bih  = (const float*)d_in[12];
    const float* Whh  = (const float*)d_in[13];
    const float* bhh  = (const float*)d_in[14];
    const float* lng  = (const float*)d_in[15];
    const float* lnb  = (const float*)d_in[16];
    const float* pw   = (const float*)d_in[17];
    const float* pb   = (const float*)d_in[18];
    const float* h0W  = (const float*)d_in[19];
    const float* h0b  = (const float*)d_in[20];
    const float* h1W  = (const float*)d_in[21];
    const float* h1b  = (const float*)d_in[22];
    float* out = (float*)d_out;

    // Workspace layout, units MW = 1Mi floats = 4 MiB:
    //   hn2b bf16 [32768, 256] =  4 MW   -> [ 0,  4)
    //   hb   bf16 [32768, 256] =  4 MW   -> [ 8, 12)
    //   mmb  bf16 [32768, 256] =  4 MW   -> [12, 16)   (also Ssd fp32 [32768,16])
    //   hpb2 bf16 [32768, 512] =  8 MW   -> [16, 24)
    //   mb   bf16 [32768, 512] =  8 MW   -> [24, 32)
    //   weights/bias/masks               -> [32, ~33.3)
    const size_t MW = 1024 * 1024;
    float* ws = (float*)d_ws;
    short* hn2b = (short*)ws;
    short* hb   = (short*)(ws + 8 * MW);
    short* mmb  = (short*)(ws + 12 * MW);
    float* Ssd  = ws + 12 * MW;                          // aliases mmb (timeshared)
    short* hpb2 = (short*)(ws + 16 * MW);
    short* mb   = (short*)(ws + 24 * MW);
    short* Wcomb = (short*)(ws + 32 * MW);               // 3*640*256 shorts
    short* msgWb = Wcomb + 3 * 640 * 256;                // 3*256*512 shorts
    short* Bcat  = msgWb + 3 * 256 * 512;                // 3*1024*512 shorts (interleaved)
    float* bias4 = (float*)(Bcat + 3 * 1024 * 512);      // 3*1024 floats
    int* mask    = (int*)(bias4 + 3 * 1024);
    int* logical = mask + B_ * L_;
    int* pol     = logical + B_ * L_;
    int* nvalid  = pol + B_ * L_;

    // merged weight prep + out zeroing (1 dispatch)
    prep_all<<<(PR_TOT + 255) / 256, 256, 0, stream>>>(
        gpW, gfW, gpas, gpad, gfas, gfad, msgW, Wih, Whh, bih, bhh,
        Wcomb, msgWb, Bcat, bias4, out);

    // fused scan (64 blocks) + embed (4096 blocks of 8 tokens)
    scan_embed<<<64 + 4096, 512, 0, stream>>>(x, emb, pos, hb, mask, logical, pol, nvalid);

    const int DILS[LAY] = {1, 2, 4};

    for (int l = 0; l < LAY; l++) {
        int dil = DILS[l];
        // hpb2 (N=512 bf16) + Ssd (16 fp32 cols), deep 256x128 pipeline (640 blocks)
        projssd_deep<<<640, 512, 0, stream>>>(hb, Wcomb + (size_t)l * 640 * 256,
                                              hpb2, Ssd);
        // sparse GAT aggregation, both dirs in one wave, short8-vectorized
        agg_fused<<<8192, 256, 0, stream>>>(hpb2, Ssd, mask, logical, pol, nvalid, mb, dil);
        // mm = relu(m @ msgW^T + msgb) -> bf16, deep 256x128 pipeline (256 blocks)
        msg_bgemm<<<256, 512, 0, stream>>>(mb, msgWb + (size_t)l * 256 * 512,
                                           mmb, msgb + l * C_);
        // 256x256-tile 8-phase deep-vmcnt GRU GEMM + gate epilogue -> hn2b
        gru_bgemm<<<512, 512, 0, stream>>>(mmb, hb, Bcat + (size_t)l * 1024 * 512,
                                           hn2b, bias4 + l * 1024);
        // LayerNorm + mask -> hb
        ln_kernel<<<8192, 256, 0, stream>>>(hn2b, hb, mask, lng + l * C_, lnb + l * C_);
    }

    // 4-slice parallel pooling + heads (256 blocks, atomicAdd into zeroed out)
    pool_head2<<<B_ * 4, 1024, 0, stream>>>(hb, mask, pw, pb, h0W, h0b, h1W, h1b, out);
}